// Round 3
// baseline (4134.550 us; speedup 1.0000x reference)
//
#include <hip/hip_runtime.h>
#include <hip/hip_bf16.h>

// Problem constants
#define N_NODES 10000
#define N_EDGES 64000
#define IN_F    1247
#define NH      4
#define D0      256
#define D1      8
#define HD0     1024   // NH*D0
#define HD1     32     // NH*D1
#define OUTF    6
#define INV_N   (1.0f / 10000.0f)

// ---------------- workspace layout (float-slot offsets), total ~92.3 MB ----------------
constexpr size_t OFF_FLAG   = 0;                         // 16 (dtype flag int)
constexpr size_t OFF_COLSUM = 16;                        // 1280
constexpr size_t OFF_MASKM  = 1296;                      // 1280
constexpr size_t OFF_RSCALE = 2576;                      // 10016
constexpr size_t OFF_Z      = 12592;                     // N*32
constexpr size_t OFF_ES     = OFF_Z    + 320000;         // N*4
constexpr size_t OFF_ED     = OFF_ES   + 40000;          // N*4
constexpr size_t OFF_P2     = OFF_ED   + 40000;          // E*4
constexpr size_t OFF_DEN2   = OFF_P2   + 256000;         // N*4
constexpr size_t OFF_H3     = OFF_DEN2 + 40000;          // N*32
constexpr size_t OFF_OUT0   = OFF_H3   + 320000;         // N*1024 f32
constexpr size_t OFF_P0     = OFF_OUT0 + 10240000;       // E*4
constexpr size_t OFF_DEN0   = OFF_P0   + 256000;         // N*4
constexpr size_t OFF_FS1    = OFF_DEN0 + 40000;          // N*32
constexpr size_t OFF_FD1    = OFF_FS1  + 320000;         // N*32
constexpr size_t OFF_OUT1   = OFF_FD1  + 320000;         // N*32
constexpr size_t OFF_P1     = OFF_OUT1 + 320000;         // E*4
constexpr size_t OFF_DEN1   = OFF_P1   + 256000;         // N*4
constexpr size_t OFF_W2T    = OFF_DEN1 + 40000;          // bf16 IN*32 (19952 -> 19968 slots)
constexpr size_t OFF_FS0B   = OFF_W2T  + 19968;          // bf16 N*1024 -> 5,120,000 slots
constexpr size_t OFF_FD0B   = OFF_FS0B + 5120000;        // bf16 N*1024
constexpr size_t WS_FLOATS  = OFF_FD0B + 5120000;        // ~92.3 MB

// dual-dtype load: is_f32 ? float : bf16
__device__ __forceinline__ float ldin(const void* p, size_t i, int f32) {
    return f32 ? ((const float*)p)[i]
               : __bfloat162float(((const __hip_bfloat16*)p)[i]);
}

// ---------------- kernels ----------------

// dtype detection: scan feats as uint16; any exp==0xFF pattern => data is f32.
__global__ void detect_kernel(const unsigned short* __restrict__ w, int n,
                              int* __restrict__ flag) {
    int i = blockIdx.x * 256 + threadIdx.x;
    int stride = gridDim.x * 256;
    int found = 0;
    for (; i < n; i += stride) {
        if (((w[i] >> 7) & 0xFF) == 0xFF) found = 1;
    }
    if (found) atomicOr(flag, 1);
}

// column sums of (dual-dtype) features. grid (5,40), block 256
__global__ void colsum_kernel(const void* __restrict__ feats,
                              float* __restrict__ colsum, const int* __restrict__ dflag) {
    int f32 = *dflag;
    int c = blockIdx.x * blockDim.x + threadIdx.x;
    if (c >= IN_F) return;
    int r0 = blockIdx.y * 250;
    float s = 0.f;
    for (int r = r0; r < r0 + 250; ++r)
        s += ldin(feats, (size_t)r * IN_F + c, f32);
    atomicAdd(&colsum[c], s);
}

// maskmul[c] = tm[c]+am[c]+vm[c]
__global__ void maskprep_kernel(const void* __restrict__ tm, const void* __restrict__ am,
                                const void* __restrict__ vm, float* __restrict__ maskmul,
                                const int* __restrict__ dflag) {
    int f32 = *dflag;
    int c = blockIdx.x * 256 + threadIdx.x;
    if (c >= IN_F) return;
    maskmul[c] = ldin(tm, c, f32) + ldin(am, c, f32) + ldin(vm, c, f32);
}

// per-row L1 scale of the imputed/blended features (pre-mask)
__global__ __launch_bounds__(256) void rowscale_kernel(
        const void* __restrict__ feats, const float* __restrict__ colsum,
        float* __restrict__ rowscale, const int* __restrict__ dflag) {
    int f32 = *dflag;
    int n = blockIdx.x;
    __shared__ float red[256];
    float s = 0.f;
    for (int c = threadIdx.x; c < IN_F; c += 256) {
        float f = ldin(feats, (size_t)n * IN_F + c, f32);
        float v = (f != 0.0f) ? f : 0.5f * colsum[c] * INV_N;   // 0.5*(h+h1)
        s += fabsf(v);
    }
    red[threadIdx.x] = s;
    __syncthreads();
    for (int st = 128; st > 0; st >>= 1) {
        if (threadIdx.x < st) red[threadIdx.x] += red[threadIdx.x + st];
        __syncthreads();
    }
    if (threadIdx.x == 0) rowscale[n] = 1.0f / fmaxf(red[0], 1e-12f);
}

// transpose W2 [H][IN][D1] -> w2t [IN][H*D1] (canonical bf16)
__global__ void w2t_kernel(const void* __restrict__ W2, __hip_bfloat16* __restrict__ w2t,
                           const int* __restrict__ dflag) {
    int f32 = *dflag;
    int idx = blockIdx.x * 256 + threadIdx.x;
    if (idx >= IN_F * HD1) return;
    int i = idx / HD1, j = idx % HD1;
    int hh = j / D1, o = j % D1;
    w2t[idx] = __float2bfloat16(ldin(W2, ((size_t)hh * IN_F + i) * D1 + o, f32));
}

// C[M,Nc] = A[M,K] @ B[K,Nc] (+ bias). a_mode: 0 = on-the-fly preprocessed feats
// (dual dtype), 1 = f32 ws buffer Af. b_fixed: 1 = B is canonical bf16 (w2t),
// 0 = B dual per flag. C -> f32 (Cf) or bf16 (Cb). 64x64 tile, BK=16.
__global__ __launch_bounds__(256) void gemm_kernel(
        const void* __restrict__ A, const float* __restrict__ Af,
        const float* __restrict__ colsum, const float* __restrict__ rowscale,
        const float* __restrict__ maskmul,
        const void* __restrict__ B, const void* __restrict__ bias,
        float* __restrict__ Cf, __hip_bfloat16* __restrict__ Cb,
        int M, int K, int Nc, const int* __restrict__ dflag, int a_mode, int b_fixed) {
    int f32 = *dflag;
    __shared__ float As[16][65];
    __shared__ float Bs[16][65];
    const int tid = threadIdx.x;
    const int tx = tid & 15;
    const int ty = tid >> 4;
    const int bm = blockIdx.y * 64;
    const int bn = blockIdx.x * 64;
    const int a_k = tid & 15;
    const int a_m = tid >> 4;
    const int b_n = tid & 63;
    const int b_k = tid >> 6;
    float acc[4][4] = {{0.f}};
    for (int k0 = 0; k0 < K; k0 += 16) {
#pragma unroll
        for (int s = 0; s < 4; ++s) {
            int m = a_m + s * 16;
            int gm = bm + m, gk = k0 + a_k;
            float v = 0.f;
            if (gm < M && gk < K) {
                if (a_mode == 0) {
                    float f = ldin(A, (size_t)gm * K + gk, f32);
                    float t = (f != 0.0f) ? f : 0.5f * colsum[gk] * INV_N;
                    v = t * rowscale[gm] * maskmul[gk];
                } else {
                    v = Af[(size_t)gm * K + gk];
                }
            }
            As[a_k][m] = v;
        }
#pragma unroll
        for (int s = 0; s < 4; ++s) {
            int kk = b_k + s * 4;
            int gk = k0 + kk, gn = bn + b_n;
            float v = 0.f;
            if (gk < K && gn < Nc) {
                size_t bi = (size_t)gk * Nc + gn;
                v = b_fixed ? __bfloat162float(((const __hip_bfloat16*)B)[bi])
                            : ldin(B, bi, f32);
            }
            Bs[kk][b_n] = v;
        }
        __syncthreads();
#pragma unroll
        for (int kk = 0; kk < 16; ++kk) {
            float a[4], b[4];
#pragma unroll
            for (int i = 0; i < 4; ++i) a[i] = As[kk][ty * 4 + i];
#pragma unroll
            for (int j = 0; j < 4; ++j) b[j] = Bs[kk][tx * 4 + j];
#pragma unroll
            for (int i = 0; i < 4; ++i)
#pragma unroll
                for (int j = 0; j < 4; ++j) acc[i][j] += a[i] * b[j];
        }
        __syncthreads();
    }
#pragma unroll
    for (int i = 0; i < 4; ++i) {
        int gm = bm + ty * 4 + i;
        if (gm >= M) continue;
#pragma unroll
        for (int j = 0; j < 4; ++j) {
            int gn = bn + tx * 4 + j;
            if (gn >= Nc) continue;
            float v = acc[i][j];
            if (bias) v += ldin(bias, gn, f32);
            if (Cb) Cb[(size_t)gm * Nc + gn] = __float2bfloat16(v);
            else    Cf[(size_t)gm * Nc + gn] = v;
        }
    }
}

// es/ed for gat_inner
__global__ void esed_kernel(const float* __restrict__ z, const void* __restrict__ a2,
                            float* __restrict__ es, float* __restrict__ ed,
                            const int* __restrict__ dflag) {
    int f32 = *dflag;
    int idx = blockIdx.x * 256 + threadIdx.x;   // n*NH + h
    if (idx >= N_NODES * NH) return;
    int hh = idx % NH;
    const float* zp = z + (size_t)idx * D1;
    float s1 = 0.f, s2 = 0.f;
    for (int o = 0; o < D1; ++o) {
        float zv = zp[o];
        s1 += zv * ldin(a2, hh * 2 * D1 + o, f32);
        s2 += zv * ldin(a2, hh * 2 * D1 + D1 + o, f32);
    }
    es[idx] = s1; ed[idx] = s2;
}

__global__ void edge2_kernel(const int* __restrict__ src, const int* __restrict__ dst,
                             const float* __restrict__ es, const float* __restrict__ ed,
                             float* __restrict__ p2, float* __restrict__ den2) {
    int idx = blockIdx.x * 256 + threadIdx.x;   // e*NH + h
    if (idx >= N_EDGES * NH) return;
    int e = idx / NH, hh = idx % NH;
    int s = src[e], d = dst[e];
    float x = es[s * NH + hh] + ed[d * NH + hh];
    x = x > 0.f ? x : 0.2f * x;
    float p = expf(x);
    p2[idx] = p;
    atomicAdd(&den2[d * NH + hh], p);
}

// GATv2 layer0 logits: one block per edge, one wave per head (bf16 fs/fd in ws)
__global__ __launch_bounds__(256) void edge0_kernel(
        const int* __restrict__ src, const int* __restrict__ dst,
        const __hip_bfloat16* __restrict__ fs, const __hip_bfloat16* __restrict__ fd,
        const void* __restrict__ a0,
        float* __restrict__ p0, float* __restrict__ den0,
        const int* __restrict__ dflag) {
    int f32 = *dflag;
    int e = blockIdx.x;
    int lane = threadIdx.x & 63, hh = threadIdx.x >> 6;
    int s = src[e], d = dst[e];
    const __hip_bfloat16* fsp = fs + (size_t)s * HD0 + hh * D0;
    const __hip_bfloat16* fdp = fd + (size_t)d * HD0 + hh * D0;
    float acc = 0.f;
    for (int k = lane; k < D0; k += 64) {
        float x = __bfloat162float(fsp[k]) + __bfloat162float(fdp[k]);
        x = x > 0.f ? x : 0.2f * x;
        acc += x * ldin(a0, hh * D0 + k, f32);
    }
    for (int off = 32; off > 0; off >>= 1) acc += __shfl_down(acc, off);
    if (lane == 0) {
        float p = expf(acc);
        p0[e * NH + hh] = p;
        atomicAdd(&den0[d * NH + hh], p);
    }
}

// GATv2 layer0 aggregate: atomic into out0 (holds res+bias from gemm)
__global__ __launch_bounds__(256) void agg0_kernel(
        const int* __restrict__ src, const int* __restrict__ dst,
        const __hip_bfloat16* __restrict__ fs, const float* __restrict__ p0,
        const float* __restrict__ den0, float* __restrict__ out0) {
    int e = blockIdx.x;
    int s = src[e], d = dst[e];
    for (int j = threadIdx.x; j < HD0; j += 256) {
        int hh = j >> 8;
        float alpha = p0[e * NH + hh] / fmaxf(den0[d * NH + hh], 1e-9f);
        atomicAdd(&out0[(size_t)d * HD0 + j],
                  __bfloat162float(fs[(size_t)s * HD0 + j]) * alpha);
    }
}

__global__ void edge1_kernel(const int* __restrict__ src, const int* __restrict__ dst,
                             const float* __restrict__ fs1, const float* __restrict__ fd1,
                             const void* __restrict__ a1,
                             float* __restrict__ p1, float* __restrict__ den1,
                             const int* __restrict__ dflag) {
    int f32 = *dflag;
    int idx = blockIdx.x * 256 + threadIdx.x;   // e*NH + h
    if (idx >= N_EDGES * NH) return;
    int e = idx / NH, hh = idx % NH;
    int s = src[e], d = dst[e];
    float acc = 0.f;
    for (int o = 0; o < D1; ++o) {
        float x = fs1[(size_t)s * HD1 + hh * D1 + o] + fd1[(size_t)d * HD1 + hh * D1 + o];
        x = x > 0.f ? x : 0.2f * x;
        acc += x * ldin(a1, hh * D1 + o, f32);
    }
    float p = expf(acc);
    p1[idx] = p;
    atomicAdd(&den1[d * NH + hh], p);
}

// small aggregate (32-wide rows): gat_inner (z->h3) and layer1 (fs1->out1)
__global__ void agg_small_kernel(const int* __restrict__ src, const int* __restrict__ dst,
                                 const float* __restrict__ feat, const float* __restrict__ p,
                                 const float* __restrict__ den, float* __restrict__ out) {
    int idx = blockIdx.x * 256 + threadIdx.x;   // e*32 + j
    if (idx >= N_EDGES * HD1) return;
    int e = idx >> 5, j = idx & 31;
    int hh = j >> 3;
    int d = dst[e];
    float alpha = p[e * NH + hh] / fmaxf(den[d * NH + hh], 1e-9f);
    atomicAdd(&out[(size_t)d * HD1 + j], feat[(size_t)src[e] * HD1 + j] * alpha);
}

__global__ void relu_kernel(float* __restrict__ x, int n) {
    int idx = blockIdx.x * 256 + threadIdx.x;
    if (idx < n) x[idx] = fmaxf(x[idx], 0.f);
}

// final: out[n,o] = [h3 | out1] @ Wlin + blin; dual-dtype store
__global__ void final_kernel(const float* __restrict__ h3, const float* __restrict__ out1,
                             const void* __restrict__ Wlin, const void* __restrict__ blin,
                             void* __restrict__ out, const int* __restrict__ dflag) {
    int f32 = *dflag;
    int idx = blockIdx.x * 256 + threadIdx.x;   // n*OUTF + o
    if (idx >= N_NODES * OUTF) return;
    int n = idx / OUTF, o = idx % OUTF;
    float acc = ldin(blin, o, f32);
    for (int j = 0; j < HD1; ++j)
        acc += h3[(size_t)n * HD1 + j] * ldin(Wlin, j * OUTF + o, f32);
    for (int j = 0; j < HD1; ++j)
        acc += out1[(size_t)n * HD1 + j] * ldin(Wlin, (HD1 + j) * OUTF + o, f32);
    if (f32) ((float*)out)[idx] = acc;
    else     ((__hip_bfloat16*)out)[idx] = __float2bfloat16(acc);
}

// ---------------- launch ----------------
extern "C" void kernel_launch(void* const* d_in, const int* in_sizes, int n_in,
                              void* d_out, int out_size, void* d_ws, size_t ws_size,
                              hipStream_t stream) {
    const void* feats = d_in[0];
    const int*  src   = (const int*)d_in[1];
    const int*  dst   = (const int*)d_in[2];
    const void* tm    = d_in[3];
    const void* am    = d_in[4];
    const void* vm    = d_in[5];
    const void* W2    = d_in[6];
    const void* a2    = d_in[7];
    const void* Wl0   = d_in[8];
    const void* Wr0   = d_in[9];
    const void* a0    = d_in[10];
    const void* Wres0 = d_in[11];
    const void* b0    = d_in[12];
    const void* Wl1   = d_in[13];
    const void* Wr1   = d_in[14];
    const void* a1    = d_in[15];
    const void* Wres1 = d_in[16];
    const void* b1    = d_in[17];
    const void* Wlin  = d_in[18];
    const void* blin  = d_in[19];

    float* ws = (float*)d_ws;
    int*   dflag  = (int*)(ws + OFF_FLAG);
    float* colsum = ws + OFF_COLSUM;
    float* maskm  = ws + OFF_MASKM;
    float* rscale = ws + OFF_RSCALE;
    float* z      = ws + OFF_Z;
    float* es     = ws + OFF_ES;
    float* ed     = ws + OFF_ED;
    float* p2     = ws + OFF_P2;
    float* den2   = ws + OFF_DEN2;
    float* h3     = ws + OFF_H3;
    float* out0   = ws + OFF_OUT0;
    float* p0     = ws + OFF_P0;
    float* den0   = ws + OFF_DEN0;
    float* fs1    = ws + OFF_FS1;
    float* fd1    = ws + OFF_FD1;
    float* out1   = ws + OFF_OUT1;
    float* p1     = ws + OFF_P1;
    float* den1   = ws + OFF_DEN1;
    __hip_bfloat16* w2t  = (__hip_bfloat16*)(ws + OFF_W2T);
    __hip_bfloat16* fs0b = (__hip_bfloat16*)(ws + OFF_FS0B);
    __hip_bfloat16* fd0b = (__hip_bfloat16*)(ws + OFF_FD0B);

    // zero accumulators (ws poisoned 0xAA before every call)
    hipMemsetAsync(dflag, 0, sizeof(int), stream);
    hipMemsetAsync(colsum, 0, 1280 * sizeof(float), stream);
    hipMemsetAsync(den2, 0, N_NODES * NH * sizeof(float), stream);
    hipMemsetAsync(den0, 0, N_NODES * NH * sizeof(float), stream);
    hipMemsetAsync(den1, 0, N_NODES * NH * sizeof(float), stream);
    hipMemsetAsync(h3, 0, N_NODES * HD1 * sizeof(float), stream);

    // dtype detection (scan feats as uint16 words)
    detect_kernel<<<4096, 256, 0, stream>>>((const unsigned short*)feats,
                                            N_NODES * IN_F, dflag);

    // preprocess scalars
    colsum_kernel<<<dim3(5, 40), 256, 0, stream>>>(feats, colsum, dflag);
    maskprep_kernel<<<5, 256, 0, stream>>>(tm, am, vm, maskm, dflag);
    rowscale_kernel<<<N_NODES, 256, 0, stream>>>(feats, colsum, rscale, dflag);
    w2t_kernel<<<(IN_F * HD1 + 255) / 256, 256, 0, stream>>>(W2, w2t, dflag);

    // projections (A = on-the-fly preprocessed features)
    gemm_kernel<<<dim3(1, 157), 256, 0, stream>>>(feats, nullptr, colsum, rscale, maskm,
                                                  w2t, nullptr, z, nullptr,
                                                  N_NODES, IN_F, HD1, dflag, 0, 1);
    gemm_kernel<<<dim3(16, 157), 256, 0, stream>>>(feats, nullptr, colsum, rscale, maskm,
                                                   Wl0, nullptr, nullptr, fs0b,
                                                   N_NODES, IN_F, HD0, dflag, 0, 0);
    gemm_kernel<<<dim3(16, 157), 256, 0, stream>>>(feats, nullptr, colsum, rscale, maskm,
                                                   Wr0, nullptr, nullptr, fd0b,
                                                   N_NODES, IN_F, HD0, dflag, 0, 0);
    gemm_kernel<<<dim3(16, 157), 256, 0, stream>>>(feats, nullptr, colsum, rscale, maskm,
                                                   Wres0, b0, out0, nullptr,
                                                   N_NODES, IN_F, HD0, dflag, 0, 0);

    // gat_inner (h3)
    esed_kernel<<<(N_NODES * NH + 255) / 256, 256, 0, stream>>>(z, a2, es, ed, dflag);
    edge2_kernel<<<(N_EDGES * NH + 255) / 256, 256, 0, stream>>>(src, dst, es, ed, p2, den2);
    agg_small_kernel<<<(N_EDGES * HD1 + 255) / 256, 256, 0, stream>>>(src, dst, z, p2, den2, h3);

    // GATv2 layer 0
    edge0_kernel<<<N_EDGES, 256, 0, stream>>>(src, dst, fs0b, fd0b, a0, p0, den0, dflag);
    agg0_kernel<<<N_EDGES, 256, 0, stream>>>(src, dst, fs0b, p0, den0, out0);
    relu_kernel<<<(N_NODES * HD0 + 255) / 256, 256, 0, stream>>>(out0, N_NODES * HD0);

    // GATv2 layer 1 (A = out0, plain f32)
    gemm_kernel<<<dim3(1, 157), 256, 0, stream>>>(nullptr, out0, nullptr, nullptr, nullptr,
                                                  Wl1, nullptr, fs1, nullptr,
                                                  N_NODES, HD0, HD1, dflag, 1, 0);
    gemm_kernel<<<dim3(1, 157), 256, 0, stream>>>(nullptr, out0, nullptr, nullptr, nullptr,
                                                  Wr1, nullptr, fd1, nullptr,
                                                  N_NODES, HD0, HD1, dflag, 1, 0);
    gemm_kernel<<<dim3(1, 157), 256, 0, stream>>>(nullptr, out0, nullptr, nullptr, nullptr,
                                                  Wres1, b1, out1, nullptr,
                                                  N_NODES, HD0, HD1, dflag, 1, 0);
    edge1_kernel<<<(N_EDGES * NH + 255) / 256, 256, 0, stream>>>(src, dst, fs1, fd1, a1,
                                                                 p1, den1, dflag);
    agg_small_kernel<<<(N_EDGES * HD1 + 255) / 256, 256, 0, stream>>>(src, dst, fs1, p1, den1, out1);
    relu_kernel<<<(N_NODES * HD1 + 255) / 256, 256, 0, stream>>>(out1, N_NODES * HD1);

    // final linear
    final_kernel<<<(N_NODES * OUTF + 255) / 256, 256, 0, stream>>>(h3, out1, Wlin, blin,
                                                                   out_size ? d_out : d_out, dflag);
}

// Round 5
// 1730.183 us; speedup vs baseline: 2.3897x; 2.3897x over previous
//
#include <hip/hip_runtime.h>
#include <hip/hip_bf16.h>

// Problem constants
#define N_NODES 10000
#define N_EDGES 64000
#define IN_F    1247
#define KPAD    1280   // IN_F padded to mult of 32
#define NH      4
#define D0      256
#define D1      8
#define HD0     1024   // NH*D0
#define HD1     32     // NH*D1
#define NBIG    3072   // Wl0 | Wr0 | Wres0 fused
#define OUTF    6
#define INV_N   (1.0f / 10000.0f)

typedef __attribute__((ext_vector_type(8))) short bf16x8;
typedef __attribute__((ext_vector_type(4))) float f32x4;

// ---------------- workspace layout (float-slot offsets), total ~125.8 MB ----------------
constexpr size_t OFF_FLAG   = 0;                         // 16 (dtype flag int)
constexpr size_t OFF_COLSUM = 16;                        // 1280
constexpr size_t OFF_MASKM  = 1296;                      // 1280
constexpr size_t OFF_RSCALE = 2576;                      // 10016
constexpr size_t OFF_Z      = 12592;                     // N*32
constexpr size_t OFF_ES     = OFF_Z    + 320000;         // N*4
constexpr size_t OFF_ED     = OFF_ES   + 40000;          // N*4
constexpr size_t OFF_P2     = OFF_ED   + 40000;          // E*4
constexpr size_t OFF_DEN2   = OFF_P2   + 256000;         // N*4
constexpr size_t OFF_H3     = OFF_DEN2 + 40000;          // N*32
constexpr size_t OFF_OUT0   = OFF_H3   + 320000;         // N*1024 f32
constexpr size_t OFF_P0     = OFF_OUT0 + 10240000;       // E*4
constexpr size_t OFF_DEN0   = OFF_P0   + 256000;         // N*4
constexpr size_t OFF_FS1    = OFF_DEN0 + 40000;          // N*32
constexpr size_t OFF_FD1    = OFF_FS1  + 320000;         // N*32
constexpr size_t OFF_OUT1   = OFF_FD1  + 320000;         // N*32
constexpr size_t OFF_P1     = OFF_OUT1 + 320000;         // E*4
constexpr size_t OFF_DEN1   = OFF_P1   + 256000;         // N*4
constexpr size_t OFF_W2T    = OFF_DEN1 + 40000;          // bf16 IN*32 -> 19968 slots
constexpr size_t OFF_FS0B   = OFF_W2T  + 19968;          // bf16 N*1024 -> 5,120,000 slots
constexpr size_t OFF_FD0B   = OFF_FS0B + 5120000;        // bf16 N*1024
constexpr size_t OFF_B0F    = OFF_FD0B + 5120000;        // f32 1024
constexpr size_t OFF_ABF    = OFF_B0F  + 1024;           // bf16 N*KPAD -> 6,400,000 slots
constexpr size_t OFF_BT     = OFF_ABF  + 6400000;        // bf16 NBIG*KPAD -> 1,966,080 slots
constexpr size_t WS_FLOATS  = OFF_BT   + 1966080;        // ~125.8 MB

// dual-dtype load: is_f32 ? float : bf16
__device__ __forceinline__ float ldin(const void* p, size_t i, int f32) {
    return f32 ? ((const float*)p)[i]
               : __bfloat162float(((const __hip_bfloat16*)p)[i]);
}

// ---------------- kernels ----------------

// dtype detection: scan feats as uint16; any exp==0xFF pattern => data is f32.
__global__ void detect_kernel(const unsigned short* __restrict__ w, int n,
                              int* __restrict__ flag) {
    int i = blockIdx.x * 256 + threadIdx.x;
    int stride = gridDim.x * 256;
    int found = 0;
    for (; i < n; i += stride) {
        if (((w[i] >> 7) & 0xFF) == 0xFF) found = 1;
    }
    if (found) atomicOr(flag, 1);
}

// column sums of (dual-dtype) features. grid (5,40), block 256
__global__ void colsum_kernel(const void* __restrict__ feats,
                              float* __restrict__ colsum, const int* __restrict__ dflag) {
    int f32 = *dflag;
    int c = blockIdx.x * blockDim.x + threadIdx.x;
    if (c >= IN_F) return;
    int r0 = blockIdx.y * 250;
    float s = 0.f;
    for (int r = r0; r < r0 + 250; ++r)
        s += ldin(feats, (size_t)r * IN_F + c, f32);
    atomicAdd(&colsum[c], s);
}

// maskmul[c] = tm[c]+am[c]+vm[c]
__global__ void maskprep_kernel(const void* __restrict__ tm, const void* __restrict__ am,
                                const void* __restrict__ vm, float* __restrict__ maskmul,
                                const int* __restrict__ dflag) {
    int f32 = *dflag;
    int c = blockIdx.x * 256 + threadIdx.x;
    if (c >= IN_F) return;
    maskmul[c] = ldin(tm, c, f32) + ldin(am, c, f32) + ldin(vm, c, f32);
}

// b0 -> f32
__global__ void b0f_kernel(const void* __restrict__ b0, float* __restrict__ b0f,
                           const int* __restrict__ dflag) {
    int f32 = *dflag;
    int c = blockIdx.x * 256 + threadIdx.x;
    if (c < HD0) b0f[c] = ldin(b0, c, f32);
}

// per-row L1 scale of the imputed/blended features (pre-mask)
__global__ __launch_bounds__(256) void rowscale_kernel(
        const void* __restrict__ feats, const float* __restrict__ colsum,
        float* __restrict__ rowscale, const int* __restrict__ dflag) {
    int f32 = *dflag;
    int n = blockIdx.x;
    __shared__ float red[256];
    float s = 0.f;
    for (int c = threadIdx.x; c < IN_F; c += 256) {
        float f = ldin(feats, (size_t)n * IN_F + c, f32);
        float v = (f != 0.0f) ? f : 0.5f * colsum[c] * INV_N;   // 0.5*(h+h1)
        s += fabsf(v);
    }
    red[threadIdx.x] = s;
    __syncthreads();
    for (int st = 128; st > 0; st >>= 1) {
        if (threadIdx.x < st) red[threadIdx.x] += red[threadIdx.x + st];
        __syncthreads();
    }
    if (threadIdx.x == 0) rowscale[n] = 1.0f / fmaxf(red[0], 1e-12f);
}

// transpose W2 [H][IN][D1] -> w2t [IN][H*D1] (canonical bf16)
__global__ void w2t_kernel(const void* __restrict__ W2, __hip_bfloat16* __restrict__ w2t,
                           const int* __restrict__ dflag) {
    int f32 = *dflag;
    int idx = blockIdx.x * 256 + threadIdx.x;
    if (idx >= IN_F * HD1) return;
    int i = idx / HD1, j = idx % HD1;
    int hh = j / D1, o = j % D1;
    w2t[idx] = __float2bfloat16(ldin(W2, ((size_t)hh * IN_F + i) * D1 + o, f32));
}

// preprocessed A as bf16 [N_NODES][KPAD]; one block per row
__global__ __launch_bounds__(256) void abf_kernel(
        const void* __restrict__ feats, const float* __restrict__ colsum,
        const float* __restrict__ rowscale, const float* __restrict__ maskmul,
        __hip_bfloat16* __restrict__ abf, const int* __restrict__ dflag) {
    int f32 = *dflag;
    int n = blockIdx.x;
    float rs = rowscale[n];
    for (int k = threadIdx.x; k < KPAD; k += 256) {
        float v = 0.f;
        if (k < IN_F) {
            float f = ldin(feats, (size_t)n * IN_F + k, f32);
            float t = (f != 0.0f) ? f : 0.5f * colsum[k] * INV_N;
            v = t * rs * maskmul[k];
        }
        abf[(size_t)n * KPAD + k] = __float2bfloat16(v);
    }
}

// fused transposed B: bt[n][k] = {Wl0|Wr0|Wres0}[k][n%1024], bf16, zero-pad k>=IN_F
__global__ void bt_kernel(const void* __restrict__ Wl0, const void* __restrict__ Wr0,
                          const void* __restrict__ Wres0, __hip_bfloat16* __restrict__ bt,
                          const int* __restrict__ dflag) {
    int f32 = *dflag;
    int idx = blockIdx.x * 256 + threadIdx.x;   // k*NBIG + n (reads coalesced)
    if (idx >= KPAD * NBIG) return;
    int k = idx / NBIG, n = idx % NBIG;
    float v = 0.f;
    if (k < IN_F) {
        int seg = n >> 10, col = n & 1023;
        const void* W = (seg == 0) ? Wl0 : (seg == 1) ? Wr0 : Wres0;
        v = ldin(W, (size_t)k * HD0 + col, f32);
    }
    bt[(size_t)n * KPAD + k] = __float2bfloat16(v);
}

// MFMA GEMM: C[10000 x 3072] = A_bf16[10000 x 1280] @ BT^T ; epilogue splits
// cols 0..1023 -> fs0b (bf16), 1024..2047 -> fd0b (bf16), 2048..3071 -> out0 (f32, +b0).
// 128x128 tile, BK=32, 256 threads (4 waves, 2x2 of 64x64), 16x16x32 bf16 MFMA.
#define LDSTR 40   // padded row stride in ushorts (2-way bank conflicts only)
__global__ __launch_bounds__(256) void mfma_gemm(
        const unsigned short* __restrict__ A, const unsigned short* __restrict__ BT,
        const float* __restrict__ b0f, __hip_bfloat16* __restrict__ fs0b,
        __hip_bfloat16* __restrict__ fd0b, float* __restrict__ out0) {
    __shared__ unsigned short As[128 * LDSTR];
    __shared__ unsigned short Bs[128 * LDSTR];
    const int tid = threadIdx.x;
    const int wave = tid >> 6, lane = tid & 63;
    const int quad = lane >> 4, l16 = lane & 15;
    const int wm = (wave & 1) * 64, wn = (wave >> 1) * 64;
    const int bm = blockIdx.y * 128, bn = blockIdx.x * 128;

    f32x4 acc[4][4];
#pragma unroll
    for (int i = 0; i < 4; ++i)
#pragma unroll
        for (int j = 0; j < 4; ++j) acc[i][j] = (f32x4){0.f, 0.f, 0.f, 0.f};

    for (int k0 = 0; k0 < KPAD; k0 += 32) {
        // stage A tile: 128 rows x 32 k; 16B chunks; 512 chunks over 256 threads
#pragma unroll
        for (int cc = 0; cc < 2; ++cc) {
            int c = tid + cc * 256;
            int r = c >> 2, kc = (c & 3) << 3;     // kc in ushorts
            int gm = bm + r;
            uint4 v = {0u, 0u, 0u, 0u};
            if (gm < N_NODES)
                v = *(const uint4*)(A + (size_t)gm * KPAD + k0 + kc);
            *(uint4*)(&As[r * LDSTR + kc]) = v;
            // B tile (no row guard: grid covers exactly 3072 cols)
            uint4 w = *(const uint4*)(BT + (size_t)(bn + r) * KPAD + k0 + kc);
            *(uint4*)(&Bs[r * LDSTR + kc]) = w;
        }
        __syncthreads();
        bf16x8 af[4], bfr[4];
#pragma unroll
        for (int i = 0; i < 4; ++i)
            af[i] = *(const bf16x8*)(&As[(wm + i * 16 + l16) * LDSTR + quad * 8]);
#pragma unroll
        for (int j = 0; j < 4; ++j)
            bfr[j] = *(const bf16x8*)(&Bs[(wn + j * 16 + l16) * LDSTR + quad * 8]);
#pragma unroll
        for (int i = 0; i < 4; ++i)
#pragma unroll
            for (int j = 0; j < 4; ++j)
                acc[i][j] = __builtin_amdgcn_mfma_f32_16x16x32_bf16(
                    af[i], bfr[j], acc[i][j], 0, 0, 0);
        __syncthreads();
    }

    // epilogue: D row = quad*4 + reg, col = l16 (within 16x16 tile)
    const int seg = bn >> 10;                 // block-uniform
#pragma unroll
    for (int i = 0; i < 4; ++i) {
#pragma unroll
        for (int r = 0; r < 4; ++r) {
            int gm = bm + wm + i * 16 + quad * 4 + r;
            if (gm >= N_NODES) continue;
#pragma unroll
            for (int j = 0; j < 4; ++j) {
                int gnl = (bn & 1023) + wn + j * 16 + l16;   // col within segment
                float v = acc[i][j][r];
                if (seg == 0)      fs0b[(size_t)gm * HD0 + gnl] = __float2bfloat16(v);
                else if (seg == 1) fd0b[(size_t)gm * HD0 + gnl] = __float2bfloat16(v);
                else               out0[(size_t)gm * HD0 + gnl] = v + b0f[gnl];
            }
        }
    }
}

// C[M,Nc] = A[M,K] @ B[K,Nc] (+ bias). a_mode: 0 = on-the-fly preprocessed feats
// (dual dtype), 1 = f32 ws buffer Af. b_fixed: 1 = B canonical bf16, 0 = dual.
__global__ __launch_bounds__(256) void gemm_kernel(
        const void* __restrict__ A, const float* __restrict__ Af,
        const float* __restrict__ colsum, const float* __restrict__ rowscale,
        const float* __restrict__ maskmul,
        const void* __restrict__ B, const void* __restrict__ bias,
        float* __restrict__ Cf, __hip_bfloat16* __restrict__ Cb,
        int M, int K, int Nc, const int* __restrict__ dflag, int a_mode, int b_fixed) {
    int f32 = *dflag;
    __shared__ float As[16][65];
    __shared__ float Bs[16][65];
    const int tid = threadIdx.x;
    const int tx = tid & 15;
    const int ty = tid >> 4;
    const int bm = blockIdx.y * 64;
    const int bn = blockIdx.x * 64;
    const int a_k = tid & 15;
    const int a_m = tid >> 4;
    const int b_n = tid & 63;
    const int b_k = tid >> 6;
    float acc[4][4] = {{0.f}};
    for (int k0 = 0; k0 < K; k0 += 16) {
#pragma unroll
        for (int s = 0; s < 4; ++s) {
            int m = a_m + s * 16;
            int gm = bm + m, gk = k0 + a_k;
            float v = 0.f;
            if (gm < M && gk < K) {
                if (a_mode == 0) {
                    float f = ldin(A, (size_t)gm * K + gk, f32);
                    float t = (f != 0.0f) ? f : 0.5f * colsum[gk] * INV_N;
                    v = t * rowscale[gm] * maskmul[gk];
                } else {
                    v = Af[(size_t)gm * K + gk];
                }
            }
            As[a_k][m] = v;
        }
#pragma unroll
        for (int s = 0; s < 4; ++s) {
            int kk = b_k + s * 4;
            int gk = k0 + kk, gn = bn + b_n;
            float v = 0.f;
            if (gk < K && gn < Nc) {
                size_t bi = (size_t)gk * Nc + gn;
                v = b_fixed ? __bfloat162float(((const __hip_bfloat16*)B)[bi])
                            : ldin(B, bi, f32);
            }
            Bs[kk][b_n] = v;
        }
        __syncthreads();
#pragma unroll
        for (int kk = 0; kk < 16; ++kk) {
            float a[4], b[4];
#pragma unroll
            for (int i = 0; i < 4; ++i) a[i] = As[kk][ty * 4 + i];
#pragma unroll
            for (int j = 0; j < 4; ++j) b[j] = Bs[kk][tx * 4 + j];
#pragma unroll
            for (int i = 0; i < 4; ++i)
#pragma unroll
                for (int j = 0; j < 4; ++j) acc[i][j] += a[i] * b[j];
        }
        __syncthreads();
    }
#pragma unroll
    for (int i = 0; i < 4; ++i) {
        int gm = bm + ty * 4 + i;
        if (gm >= M) continue;
#pragma unroll
        for (int j = 0; j < 4; ++j) {
            int gn = bn + tx * 4 + j;
            if (gn >= Nc) continue;
            float v = acc[i][j];
            if (bias) v += ldin(bias, gn, f32);
            if (Cb) Cb[(size_t)gm * Nc + gn] = __float2bfloat16(v);
            else    Cf[(size_t)gm * Nc + gn] = v;
        }
    }
}

// es/ed for gat_inner
__global__ void esed_kernel(const float* __restrict__ z, const void* __restrict__ a2,
                            float* __restrict__ es, float* __restrict__ ed,
                            const int* __restrict__ dflag) {
    int f32 = *dflag;
    int idx = blockIdx.x * 256 + threadIdx.x;   // n*NH + h
    if (idx >= N_NODES * NH) return;
    int hh = idx % NH;
    const float* zp = z + (size_t)idx * D1;
    float s1 = 0.f, s2 = 0.f;
    for (int o = 0; o < D1; ++o) {
        float zv = zp[o];
        s1 += zv * ldin(a2, hh * 2 * D1 + o, f32);
        s2 += zv * ldin(a2, hh * 2 * D1 + D1 + o, f32);
    }
    es[idx] = s1; ed[idx] = s2;
}

__global__ void edge2_kernel(const int* __restrict__ src, const int* __restrict__ dst,
                             const float* __restrict__ es, const float* __restrict__ ed,
                             float* __restrict__ p2, float* __restrict__ den2) {
    int idx = blockIdx.x * 256 + threadIdx.x;   // e*NH + h
    if (idx >= N_EDGES * NH) return;
    int e = idx / NH, hh = idx % NH;
    int s = src[e], d = dst[e];
    float x = es[s * NH + hh] + ed[d * NH + hh];
    x = x > 0.f ? x : 0.2f * x;
    float p = expf(x);
    p2[idx] = p;
    atomicAdd(&den2[d * NH + hh], p);
}

// GATv2 layer0 logits: one block per edge, one wave per head (bf16 fs/fd in ws)
__global__ __launch_bounds__(256) void edge0_kernel(
        const int* __restrict__ src, const int* __restrict__ dst,
        const __hip_bfloat16* __restrict__ fs, const __hip_bfloat16* __restrict__ fd,
        const void* __restrict__ a0,
        float* __restrict__ p0, float* __restrict__ den0,
        const int* __restrict__ dflag) {
    int f32 = *dflag;
    int e = blockIdx.x;
    int lane = threadIdx.x & 63, hh = threadIdx.x >> 6;
    int s = src[e], d = dst[e];
    const __hip_bfloat16* fsp = fs + (size_t)s * HD0 + hh * D0;
    const __hip_bfloat16* fdp = fd + (size_t)d * HD0 + hh * D0;
    float acc = 0.f;
    for (int k = lane; k < D0; k += 64) {
        float x = __bfloat162float(fsp[k]) + __bfloat162float(fdp[k]);
        x = x > 0.f ? x : 0.2f * x;
        acc += x * ldin(a0, hh * D0 + k, f32);
    }
    for (int off = 32; off > 0; off >>= 1) acc += __shfl_down(acc, off);
    if (lane == 0) {
        float p = expf(acc);
        p0[e * NH + hh] = p;
        atomicAdd(&den0[d * NH + hh], p);
    }
}

// GATv2 layer0 aggregate: atomic into out0 (holds res+bias)
__global__ __launch_bounds__(256) void agg0_kernel(
        const int* __restrict__ src, const int* __restrict__ dst,
        const __hip_bfloat16* __restrict__ fs, const float* __restrict__ p0,
        const float* __restrict__ den0, float* __restrict__ out0) {
    int e = blockIdx.x;
    int s = src[e], d = dst[e];
    for (int j = threadIdx.x; j < HD0; j += 256) {
        int hh = j >> 8;
        float alpha = p0[e * NH + hh] / fmaxf(den0[d * NH + hh], 1e-9f);
        atomicAdd(&out0[(size_t)d * HD0 + j],
                  __bfloat162float(fs[(size_t)s * HD0 + j]) * alpha);
    }
}

__global__ void edge1_kernel(const int* __restrict__ src, const int* __restrict__ dst,
                             const float* __restrict__ fs1, const float* __restrict__ fd1,
                             const void* __restrict__ a1,
                             float* __restrict__ p1, float* __restrict__ den1,
                             const int* __restrict__ dflag) {
    int f32 = *dflag;
    int idx = blockIdx.x * 256 + threadIdx.x;   // e*NH + h
    if (idx >= N_EDGES * NH) return;
    int e = idx / NH, hh = idx % NH;
    int s = src[e], d = dst[e];
    float acc = 0.f;
    for (int o = 0; o < D1; ++o) {
        float x = fs1[(size_t)s * HD1 + hh * D1 + o] + fd1[(size_t)d * HD1 + hh * D1 + o];
        x = x > 0.f ? x : 0.2f * x;
        acc += x * ldin(a1, hh * D1 + o, f32);
    }
    float p = expf(acc);
    p1[idx] = p;
    atomicAdd(&den1[d * NH + hh], p);
}

// small aggregate (32-wide rows): gat_inner (z->h3) and layer1 (fs1->out1)
__global__ void agg_small_kernel(const int* __restrict__ src, const int* __restrict__ dst,
                                 const float* __restrict__ feat, const float* __restrict__ p,
                                 const float* __restrict__ den, float* __restrict__ out) {
    int idx = blockIdx.x * 256 + threadIdx.x;   // e*32 + j
    if (idx >= N_EDGES * HD1) return;
    int e = idx >> 5, j = idx & 31;
    int hh = j >> 3;
    int d = dst[e];
    float alpha = p[e * NH + hh] / fmaxf(den[d * NH + hh], 1e-9f);
    atomicAdd(&out[(size_t)d * HD1 + j], feat[(size_t)src[e] * HD1 + j] * alpha);
}

__global__ void relu_kernel(float* __restrict__ x, int n) {
    int idx = blockIdx.x * 256 + threadIdx.x;
    if (idx < n) x[idx] = fmaxf(x[idx], 0.f);
}

// final: out[n,o] = [h3 | out1] @ Wlin + blin; dual-dtype store
__global__ void final_kernel(const float* __restrict__ h3, const float* __restrict__ out1,
                             const void* __restrict__ Wlin, const void* __restrict__ blin,
                             void* __restrict__ out, const int* __restrict__ dflag) {
    int f32 = *dflag;
    int idx = blockIdx.x * 256 + threadIdx.x;   // n*OUTF + o
    if (idx >= N_NODES * OUTF) return;
    int n = idx / OUTF, o = idx % OUTF;
    float acc = ldin(blin, o, f32);
    for (int j = 0; j < HD1; ++j)
        acc += h3[(size_t)n * HD1 + j] * ldin(Wlin, j * OUTF + o, f32);
    for (int j = 0; j < HD1; ++j)
        acc += out1[(size_t)n * HD1 + j] * ldin(Wlin, (HD1 + j) * OUTF + o, f32);
    if (f32) ((float*)out)[idx] = acc;
    else     ((__hip_bfloat16*)out)[idx] = __float2bfloat16(acc);
}

// ---------------- launch ----------------
extern "C" void kernel_launch(void* const* d_in, const int* in_sizes, int n_in,
                              void* d_out, int out_size, void* d_ws, size_t ws_size,
                              hipStream_t stream) {
    const void* feats = d_in[0];
    const int*  src   = (const int*)d_in[1];
    const int*  dst   = (const int*)d_in[2];
    const void* tm    = d_in[3];
    const void* am    = d_in[4];
    const void* vm    = d_in[5];
    const void* W2    = d_in[6];
    const void* a2    = d_in[7];
    const void* Wl0   = d_in[8];
    const void* Wr0   = d_in[9];
    const void* a0    = d_in[10];
    const void* Wres0 = d_in[11];
    const void* b0    = d_in[12];
    const void* Wl1   = d_in[13];
    const void* Wr1   = d_in[14];
    const void* a1    = d_in[15];
    const void* Wres1 = d_in[16];
    const void* b1    = d_in[17];
    const void* Wlin  = d_in[18];
    const void* blin  = d_in[19];

    float* ws = (float*)d_ws;
    int*   dflag  = (int*)(ws + OFF_FLAG);
    float* colsum = ws + OFF_COLSUM;
    float* maskm  = ws + OFF_MASKM;
    float* rscale = ws + OFF_RSCALE;
    float* z      = ws + OFF_Z;
    float* es     = ws + OFF_ES;
    float* ed     = ws + OFF_ED;
    float* p2     = ws + OFF_P2;
    float* den2   = ws + OFF_DEN2;
    float* h3     = ws + OFF_H3;
    float* out0   = ws + OFF_OUT0;
    float* p0     = ws + OFF_P0;
    float* den0   = ws + OFF_DEN0;
    float* fs1    = ws + OFF_FS1;
    float* fd1    = ws + OFF_FD1;
    float* out1   = ws + OFF_OUT1;
    float* p1     = ws + OFF_P1;
    float* den1   = ws + OFF_DEN1;
    float* b0f    = ws + OFF_B0F;
    __hip_bfloat16* w2t  = (__hip_bfloat16*)(ws + OFF_W2T);
    __hip_bfloat16* fs0b = (__hip_bfloat16*)(ws + OFF_FS0B);
    __hip_bfloat16* fd0b = (__hip_bfloat16*)(ws + OFF_FD0B);
    __hip_bfloat16* abf  = (__hip_bfloat16*)(ws + OFF_ABF);
    __hip_bfloat16* bt   = (__hip_bfloat16*)(ws + OFF_BT);

    // zero accumulators (ws poisoned 0xAA before every call)
    (void)hipMemsetAsync(dflag, 0, sizeof(int), stream);
    (void)hipMemsetAsync(colsum, 0, 1280 * sizeof(float), stream);
    (void)hipMemsetAsync(den2, 0, N_NODES * NH * sizeof(float), stream);
    (void)hipMemsetAsync(den0, 0, N_NODES * NH * sizeof(float), stream);
    (void)hipMemsetAsync(den1, 0, N_NODES * NH * sizeof(float), stream);
    (void)hipMemsetAsync(h3, 0, N_NODES * HD1 * sizeof(float), stream);

    // dtype detection
    detect_kernel<<<4096, 256, 0, stream>>>((const unsigned short*)feats,
                                            N_NODES * IN_F, dflag);

    // preprocess scalars
    colsum_kernel<<<dim3(5, 40), 256, 0, stream>>>(feats, colsum, dflag);
    maskprep_kernel<<<5, 256, 0, stream>>>(tm, am, vm, maskm, dflag);
    b0f_kernel<<<4, 256, 0, stream>>>(b0, b0f, dflag);
    rowscale_kernel<<<N_NODES, 256, 0, stream>>>(feats, colsum, rscale, dflag);
    w2t_kernel<<<(IN_F * HD1 + 255) / 256, 256, 0, stream>>>(W2, w2t, dflag);

    // MFMA inputs: preprocessed A (bf16) and fused transposed B (bf16)
    abf_kernel<<<N_NODES, 256, 0, stream>>>(feats, colsum, rscale, maskm, abf, dflag);
    bt_kernel<<<(KPAD * NBIG + 255) / 256, 256, 0, stream>>>(Wl0, Wr0, Wres0, bt, dflag);

    // big fused projection GEMM (Wl0 | Wr0 | Wres0)
    mfma_gemm<<<dim3(NBIG / 128, (N_NODES + 127) / 128), 256, 0, stream>>>(
        (const unsigned short*)abf, (const unsigned short*)bt, b0f, fs0b, fd0b, out0);

    // z projection (small) on the fp32 path
    gemm_kernel<<<dim3(1, 157), 256, 0, stream>>>(feats, nullptr, colsum, rscale, maskm,
                                                  w2t, nullptr, z, nullptr,
                                                  N_NODES, IN_F, HD1, dflag, 0, 1);

    // gat_inner (h3)
    esed_kernel<<<(N_NODES * NH + 255) / 256, 256, 0, stream>>>(z, a2, es, ed, dflag);
    edge2_kernel<<<(N_EDGES * NH + 255) / 256, 256, 0, stream>>>(src, dst, es, ed, p2, den2);
    agg_small_kernel<<<(N_EDGES * HD1 + 255) / 256, 256, 0, stream>>>(src, dst, z, p2, den2, h3);

    // GATv2 layer 0
    edge0_kernel<<<N_EDGES, 256, 0, stream>>>(src, dst, fs0b, fd0b, a0, p0, den0, dflag);
    agg0_kernel<<<N_EDGES, 256, 0, stream>>>(src, dst, fs0b, p0, den0, out0);
    relu_kernel<<<(N_NODES * HD0 + 255) / 256, 256, 0, stream>>>(out0, N_NODES * HD0);

    // GATv2 layer 1 (A = out0, plain f32)
    gemm_kernel<<<dim3(1, 157), 256, 0, stream>>>(nullptr, out0, nullptr, nullptr, nullptr,
                                                  Wl1, nullptr, fs1, nullptr,
                                                  N_NODES, HD0, HD1, dflag, 1, 0);
    gemm_kernel<<<dim3(1, 157), 256, 0, stream>>>(nullptr, out0, nullptr, nullptr, nullptr,
                                                  Wr1, nullptr, fd1, nullptr,
                                                  N_NODES, HD0, HD1, dflag, 1, 0);
    gemm_kernel<<<dim3(1, 157), 256, 0, stream>>>(nullptr, out0, nullptr, nullptr, nullptr,
                                                  Wres1, b1, out1, nullptr,
                                                  N_NODES, HD0, HD1, dflag, 1, 0);
    edge1_kernel<<<(N_EDGES * NH + 255) / 256, 256, 0, stream>>>(src, dst, fs1, fd1, a1,
                                                                 p1, den1, dflag);
    agg_small_kernel<<<(N_EDGES * HD1 + 255) / 256, 256, 0, stream>>>(src, dst, fs1, p1, den1, out1);
    relu_kernel<<<(N_NODES * HD1 + 255) / 256, 256, 0, stream>>>(out1, N_NODES * HD1);

    // final linear
    final_kernel<<<(N_NODES * OUTF + 255) / 256, 256, 0, stream>>>(h3, out1, Wlin, blin,
                                                                   d_out, dflag);
}

// Round 6
// 1055.008 us; speedup vs baseline: 3.9190x; 1.6400x over previous
//
#include <hip/hip_runtime.h>
#include <hip/hip_bf16.h>

// Problem constants
#define N_NODES 10000
#define N_EDGES 64000
#define IN_F    1247
#define KPAD    1280   // IN_F padded to mult of 32
#define NH      4
#define D0      256
#define D1      8
#define HD0     1024   // NH*D0
#define HD1     32     // NH*D1
#define NBIG    3072   // Wl0 | Wr0 | Wres0
#define NBIG2   3200   // + 32 z cols (from W2) + 96 pad
#define OUTF    6
#define INV_N   (1.0f / 10000.0f)

typedef __attribute__((ext_vector_type(8))) short bf16x8;
typedef __attribute__((ext_vector_type(4))) float f32x4;

// ---------------- workspace layout (float-slot offsets), ~126.2 MB ----------------
constexpr size_t OFF_FLAG   = 0;                          // 16
constexpr size_t OFF_COLSUM = 16;                         // 1280
constexpr size_t OFF_MASKM  = 1296;                       // 1280
constexpr size_t OFF_RSCALE = 2576;                       // 10016
constexpr size_t OFF_Z      = 12592;                      // N*32
constexpr size_t OFF_ES     = OFF_Z    + 320000;          // N*4
constexpr size_t OFF_ED     = OFF_ES   + 40000;           // N*4
constexpr size_t OFF_P2     = OFF_ED   + 40000;           // E*4
constexpr size_t OFF_DEN2   = OFF_P2   + 256000;          // N*4
constexpr size_t OFF_H3     = OFF_DEN2 + 40000;           // N*32
constexpr size_t OFF_OUT0   = OFF_H3   + 320000;          // N*1024 f32
constexpr size_t OFF_P0     = OFF_OUT0 + 10240000;        // E*4
constexpr size_t OFF_DEN0   = OFF_P0   + 256000;          // N*4
constexpr size_t OFF_FS1    = OFF_DEN0 + 40000;           // N*32
constexpr size_t OFF_FD1    = OFF_FS1  + 320000;          // N*32
constexpr size_t OFF_OUT1   = OFF_FD1  + 320000;          // N*32
constexpr size_t OFF_P1     = OFF_OUT1 + 320000;          // E*4
constexpr size_t OFF_DEN1   = OFF_P1   + 256000;          // N*4
constexpr size_t OFF_B0F    = OFF_DEN1 + 40000;           // 1024
constexpr size_t OFF_B1F    = OFF_B0F  + 1024;            // 64
constexpr size_t OFF_FS0B   = OFF_B1F  + 64;              // bf16 N*1024 (reused as out0b later)
constexpr size_t OFF_FD0B   = OFF_FS0B + 5120000;         // bf16 N*1024
constexpr size_t OFF_ABF    = OFF_FD0B + 5120000;         // bf16 N*KPAD
constexpr size_t OFF_BT     = OFF_ABF  + 6400000;         // bf16 NBIG2*KPAD = 4,096,000 ushort
constexpr size_t OFF_BT1    = OFF_BT   + 2048000;         // bf16 96*1024
constexpr size_t WS_FLOATS  = OFF_BT1  + 49152;           // ~31.56M f32 = 126.2 MB

// dual-dtype load: is_f32 ? float : bf16
__device__ __forceinline__ float ldin(const void* p, size_t i, int f32) {
    return f32 ? ((const float*)p)[i]
               : __bfloat162float(((const __hip_bfloat16*)p)[i]);
}

// ---------------- kernels ----------------

// dtype detection: scan feats as uint16; any exp==0xFF pattern => data is f32.
__global__ void detect_kernel(const unsigned short* __restrict__ w, int n,
                              int* __restrict__ flag) {
    int i = blockIdx.x * 256 + threadIdx.x;
    int stride = gridDim.x * 256;
    int found = 0;
    for (; i < n; i += stride) {
        if (((w[i] >> 7) & 0xFF) == 0xFF) found = 1;
    }
    if (found) atomicOr(flag, 1);
}

// column sums of (dual-dtype) features. grid (5,40), block 256
__global__ void colsum_kernel(const void* __restrict__ feats,
                              float* __restrict__ colsum, const int* __restrict__ dflag) {
    int f32 = *dflag;
    int c = blockIdx.x * blockDim.x + threadIdx.x;
    if (c >= IN_F) return;
    int r0 = blockIdx.y * 250;
    float s = 0.f;
    for (int r = r0; r < r0 + 250; ++r)
        s += ldin(feats, (size_t)r * IN_F + c, f32);
    atomicAdd(&colsum[c], s);
}

// maskmul[c] = tm[c]+am[c]+vm[c]
__global__ void maskprep_kernel(const void* __restrict__ tm, const void* __restrict__ am,
                                const void* __restrict__ vm, float* __restrict__ maskmul,
                                const int* __restrict__ dflag) {
    int f32 = *dflag;
    int c = blockIdx.x * 256 + threadIdx.x;
    if (c >= IN_F) return;
    maskmul[c] = ldin(tm, c, f32) + ldin(am, c, f32) + ldin(vm, c, f32);
}

// biases -> f32
__global__ void biasprep_kernel(const void* __restrict__ b0, const void* __restrict__ b1,
                                float* __restrict__ b0f, float* __restrict__ b1f,
                                const int* __restrict__ dflag) {
    int f32 = *dflag;
    int c = blockIdx.x * 256 + threadIdx.x;
    if (c < HD0) b0f[c] = ldin(b0, c, f32);
    if (c < HD1) b1f[c] = ldin(b1, c, f32);
}

// per-row L1 scale of the imputed/blended features (pre-mask)
__global__ __launch_bounds__(256) void rowscale_kernel(
        const void* __restrict__ feats, const float* __restrict__ colsum,
        float* __restrict__ rowscale, const int* __restrict__ dflag) {
    int f32 = *dflag;
    int n = blockIdx.x;
    __shared__ float red[256];
    float s = 0.f;
    for (int c = threadIdx.x; c < IN_F; c += 256) {
        float f = ldin(feats, (size_t)n * IN_F + c, f32);
        float v = (f != 0.0f) ? f : 0.5f * colsum[c] * INV_N;   // 0.5*(h+h1)
        s += fabsf(v);
    }
    red[threadIdx.x] = s;
    __syncthreads();
    for (int st = 128; st > 0; st >>= 1) {
        if (threadIdx.x < st) red[threadIdx.x] += red[threadIdx.x + st];
        __syncthreads();
    }
    if (threadIdx.x == 0) rowscale[n] = 1.0f / fmaxf(red[0], 1e-12f);
}

// preprocessed A as bf16 [N_NODES][KPAD]; one block per row
__global__ __launch_bounds__(256) void abf_kernel(
        const void* __restrict__ feats, const float* __restrict__ colsum,
        const float* __restrict__ rowscale, const float* __restrict__ maskmul,
        __hip_bfloat16* __restrict__ abf, const int* __restrict__ dflag) {
    int f32 = *dflag;
    int n = blockIdx.x;
    float rs = rowscale[n];
    for (int k = threadIdx.x; k < KPAD; k += 256) {
        float v = 0.f;
        if (k < IN_F) {
            float f = ldin(feats, (size_t)n * IN_F + k, f32);
            float t = (f != 0.0f) ? f : 0.5f * colsum[k] * INV_N;
            v = t * rs * maskmul[k];
        }
        abf[(size_t)n * KPAD + k] = __float2bfloat16(v);
    }
}

// fused transposed B [NBIG2][KPAD]: cols 0..3071 = {Wl0|Wr0|Wres0}, 3072..3103 = W2
// (z projection, col=h*8+o -> W2[h][k][o]), 3104..3199 = zero. zero-pad k>=IN_F.
__global__ void bt_kernel(const void* __restrict__ Wl0, const void* __restrict__ Wr0,
                          const void* __restrict__ Wres0, const void* __restrict__ W2,
                          __hip_bfloat16* __restrict__ bt, const int* __restrict__ dflag) {
    int f32 = *dflag;
    int idx = blockIdx.x * 256 + threadIdx.x;   // k*NBIG2 + n
    if (idx >= KPAD * NBIG2) return;
    int k = idx / NBIG2, n = idx % NBIG2;
    float v = 0.f;
    if (k < IN_F) {
        if (n < NBIG) {
            int seg = n >> 10, col = n & 1023;
            const void* W = (seg == 0) ? Wl0 : (seg == 1) ? Wr0 : Wres0;
            v = ldin(W, (size_t)k * HD0 + col, f32);
        } else if (n < NBIG + HD1) {
            int col = n - NBIG;                 // h*8+o
            int hh = col >> 3, o = col & 7;
            v = ldin(W2, ((size_t)hh * IN_F + k) * D1 + o, f32);
        }
    }
    bt[(size_t)n * KPAD + k] = __float2bfloat16(v);
}

// transposed layer-1 B [96][1024]: rows 0..31=Wl1, 32..63=Wr1, 64..95=Wres1
__global__ void bt1_kernel(const void* __restrict__ Wl1, const void* __restrict__ Wr1,
                           const void* __restrict__ Wres1, __hip_bfloat16* __restrict__ bt1,
                           const int* __restrict__ dflag) {
    int f32 = *dflag;
    int idx = blockIdx.x * 256 + threadIdx.x;   // k*96 + n
    if (idx >= HD0 * 96) return;
    int k = idx / 96, n = idx % 96;
    int seg = n >> 5, col = n & 31;
    const void* W = (seg == 0) ? Wl1 : (seg == 1) ? Wr1 : Wres1;
    bt1[(size_t)n * HD0 + k] = __float2bfloat16(ldin(W, (size_t)k * HD1 + col, f32));
}

// MFMA GEMM: C[10000 x 3200] = abf @ bt^T. Epilogue: cols 0..1023 -> fs0b (bf16),
// 1024..2047 -> fd0b (bf16), 2048..3071 -> out0 (f32, +b0), 3072..3103 -> z (f32).
// 128x128 tile, BK=32, 256 threads (4 waves, 2x2 of 64x64), 16x16x32 bf16 MFMA.
#define LDSTR 40   // padded row stride in ushorts (2-way bank conflicts only)
__global__ __launch_bounds__(256) void mfma_gemm(
        const unsigned short* __restrict__ A, const unsigned short* __restrict__ BT,
        const float* __restrict__ b0f, __hip_bfloat16* __restrict__ fs0b,
        __hip_bfloat16* __restrict__ fd0b, float* __restrict__ out0,
        float* __restrict__ z) {
    __shared__ unsigned short As[128 * LDSTR];
    __shared__ unsigned short Bs[128 * LDSTR];
    const int tid = threadIdx.x;
    const int wave = tid >> 6, lane = tid & 63;
    const int quad = lane >> 4, l16 = lane & 15;
    const int wm = (wave & 1) * 64, wn = (wave >> 1) * 64;
    const int bm = blockIdx.y * 128, bn = blockIdx.x * 128;

    f32x4 acc[4][4];
#pragma unroll
    for (int i = 0; i < 4; ++i)
#pragma unroll
        for (int j = 0; j < 4; ++j) acc[i][j] = (f32x4){0.f, 0.f, 0.f, 0.f};

    for (int k0 = 0; k0 < KPAD; k0 += 32) {
#pragma unroll
        for (int cc = 0; cc < 2; ++cc) {
            int c = tid + cc * 256;
            int r = c >> 2, kc = (c & 3) << 3;     // kc in ushorts
            int gm = bm + r;
            uint4 v = {0u, 0u, 0u, 0u};
            if (gm < N_NODES)
                v = *(const uint4*)(A + (size_t)gm * KPAD + k0 + kc);
            *(uint4*)(&As[r * LDSTR + kc]) = v;
            uint4 w = *(const uint4*)(BT + (size_t)(bn + r) * KPAD + k0 + kc);
            *(uint4*)(&Bs[r * LDSTR + kc]) = w;
        }
        __syncthreads();
        bf16x8 af[4], bfr[4];
#pragma unroll
        for (int i = 0; i < 4; ++i)
            af[i] = *(const bf16x8*)(&As[(wm + i * 16 + l16) * LDSTR + quad * 8]);
#pragma unroll
        for (int j = 0; j < 4; ++j)
            bfr[j] = *(const bf16x8*)(&Bs[(wn + j * 16 + l16) * LDSTR + quad * 8]);
#pragma unroll
        for (int i = 0; i < 4; ++i)
#pragma unroll
            for (int j = 0; j < 4; ++j)
                acc[i][j] = __builtin_amdgcn_mfma_f32_16x16x32_bf16(
                    af[i], bfr[j], acc[i][j], 0, 0, 0);
        __syncthreads();
    }

    // epilogue: D row = quad*4 + reg, col = l16
    const int seg = bn >> 10;                 // block-uniform: 0,1,2,3
#pragma unroll
    for (int i = 0; i < 4; ++i) {
#pragma unroll
        for (int r = 0; r < 4; ++r) {
            int gm = bm + wm + i * 16 + quad * 4 + r;
            if (gm >= N_NODES) continue;
#pragma unroll
            for (int j = 0; j < 4; ++j) {
                int gnl = (bn & 1023) + wn + j * 16 + l16;
                float v = acc[i][j][r];
                if (seg == 0)      fs0b[(size_t)gm * HD0 + gnl] = __float2bfloat16(v);
                else if (seg == 1) fd0b[(size_t)gm * HD0 + gnl] = __float2bfloat16(v);
                else if (seg == 2) out0[(size_t)gm * HD0 + gnl] = v + b0f[gnl];
                else if (gnl < HD1) z[(size_t)gm * HD1 + gnl] = v;
            }
        }
    }
}

// layer-1 fused MFMA GEMM: C[10000 x 96] = out0b @ bt1^T, K=1024.
// cols 0..31 -> fs1, 32..63 -> fd1, 64..95 -> out1(+b1). 128-row tile, 4 waves,
// wave w covers rows w*32..w*32+31 (2 row-tiles) x 6 col-tiles.
__global__ __launch_bounds__(256) void mfma_gemm96(
        const unsigned short* __restrict__ A, const unsigned short* __restrict__ BT1,
        const float* __restrict__ b1f, float* __restrict__ fs1,
        float* __restrict__ fd1, float* __restrict__ out1) {
    __shared__ unsigned short As[128 * LDSTR];
    __shared__ unsigned short Bs[96 * LDSTR];
    const int tid = threadIdx.x;
    const int wave = tid >> 6, lane = tid & 63;
    const int quad = lane >> 4, l16 = lane & 15;
    const int bm = blockIdx.x * 128;

    f32x4 acc[2][6];
#pragma unroll
    for (int i = 0; i < 2; ++i)
#pragma unroll
        for (int j = 0; j < 6; ++j) acc[i][j] = (f32x4){0.f, 0.f, 0.f, 0.f};

    for (int k0 = 0; k0 < HD0; k0 += 32) {
#pragma unroll
        for (int cc = 0; cc < 2; ++cc) {
            int c = tid + cc * 256;
            int r = c >> 2, kc = (c & 3) << 3;
            int gm = bm + r;
            uint4 v = {0u, 0u, 0u, 0u};
            if (gm < N_NODES)
                v = *(const uint4*)(A + (size_t)gm * HD0 + k0 + kc);
            *(uint4*)(&As[r * LDSTR + kc]) = v;
            if (c < 384) {
                uint4 w = *(const uint4*)(BT1 + (size_t)r * HD0 + k0 + kc);
                *(uint4*)(&Bs[r * LDSTR + kc]) = w;
            }
        }
        __syncthreads();
        bf16x8 af[2], bfr[6];
#pragma unroll
        for (int i = 0; i < 2; ++i)
            af[i] = *(const bf16x8*)(&As[(wave * 32 + i * 16 + l16) * LDSTR + quad * 8]);
#pragma unroll
        for (int j = 0; j < 6; ++j)
            bfr[j] = *(const bf16x8*)(&Bs[(j * 16 + l16) * LDSTR + quad * 8]);
#pragma unroll
        for (int i = 0; i < 2; ++i)
#pragma unroll
            for (int j = 0; j < 6; ++j)
                acc[i][j] = __builtin_amdgcn_mfma_f32_16x16x32_bf16(
                    af[i], bfr[j], acc[i][j], 0, 0, 0);
        __syncthreads();
    }

#pragma unroll
    for (int i = 0; i < 2; ++i) {
#pragma unroll
        for (int r = 0; r < 4; ++r) {
            int gm = bm + wave * 32 + i * 16 + quad * 4 + r;
            if (gm >= N_NODES) continue;
#pragma unroll
            for (int j = 0; j < 6; ++j) {
                int col = j * 16 + l16;
                int seg = col >> 5, cl = col & 31;
                float v = acc[i][j][r];
                if (seg == 0)      fs1[(size_t)gm * HD1 + cl] = v;
                else if (seg == 1) fd1[(size_t)gm * HD1 + cl] = v;
                else               out1[(size_t)gm * HD1 + cl] = v + b1f[cl];
            }
        }
    }
}

// es/ed for gat_inner
__global__ void esed_kernel(const float* __restrict__ z, const void* __restrict__ a2,
                            float* __restrict__ es, float* __restrict__ ed,
                            const int* __restrict__ dflag) {
    int f32 = *dflag;
    int idx = blockIdx.x * 256 + threadIdx.x;   // n*NH + h
    if (idx >= N_NODES * NH) return;
    int hh = idx % NH;
    const float* zp = z + (size_t)idx * D1;
    float s1 = 0.f, s2 = 0.f;
    for (int o = 0; o < D1; ++o) {
        float zv = zp[o];
        s1 += zv * ldin(a2, hh * 2 * D1 + o, f32);
        s2 += zv * ldin(a2, hh * 2 * D1 + D1 + o, f32);
    }
    es[idx] = s1; ed[idx] = s2;
}

__global__ void edge2_kernel(const int* __restrict__ src, const int* __restrict__ dst,
                             const float* __restrict__ es, const float* __restrict__ ed,
                             float* __restrict__ p2, float* __restrict__ den2) {
    int idx = blockIdx.x * 256 + threadIdx.x;   // e*NH + h
    if (idx >= N_EDGES * NH) return;
    int e = idx / NH, hh = idx % NH;
    int s = src[e], d = dst[e];
    float x = es[s * NH + hh] + ed[d * NH + hh];
    x = x > 0.f ? x : 0.2f * x;
    float p = expf(x);
    p2[idx] = p;
    atomicAdd(&den2[d * NH + hh], p);
}

// GATv2 layer0 logits: one block per edge, one wave per head (bf16 fs/fd in ws)
__global__ __launch_bounds__(256) void edge0_kernel(
        const int* __restrict__ src, const int* __restrict__ dst,
        const __hip_bfloat16* __restrict__ fs, const __hip_bfloat16* __restrict__ fd,
        const void* __restrict__ a0,
        float* __restrict__ p0, float* __restrict__ den0,
        const int* __restrict__ dflag) {
    int f32 = *dflag;
    int e = blockIdx.x;
    int lane = threadIdx.x & 63, hh = threadIdx.x >> 6;
    int s = src[e], d = dst[e];
    const __hip_bfloat16* fsp = fs + (size_t)s * HD0 + hh * D0;
    const __hip_bfloat16* fdp = fd + (size_t)d * HD0 + hh * D0;
    float acc = 0.f;
    for (int k = lane; k < D0; k += 64) {
        float x = __bfloat162float(fsp[k]) + __bfloat162float(fdp[k]);
        x = x > 0.f ? x : 0.2f * x;
        acc += x * ldin(a0, hh * D0 + k, f32);
    }
    for (int off = 32; off > 0; off >>= 1) acc += __shfl_down(acc, off);
    if (lane == 0) {
        float p = expf(acc);
        p0[e * NH + hh] = p;
        atomicAdd(&den0[d * NH + hh], p);
    }
}

// GATv2 layer0 aggregate: atomic into out0 (holds res+bias)
__global__ __launch_bounds__(256) void agg0_kernel(
        const int* __restrict__ src, const int* __restrict__ dst,
        const __hip_bfloat16* __restrict__ fs, const float* __restrict__ p0,
        const float* __restrict__ den0, float* __restrict__ out0) {
    int e = blockIdx.x;
    int s = src[e], d = dst[e];
    for (int j = threadIdx.x; j < HD0; j += 256) {
        int hh = j >> 8;
        float alpha = p0[e * NH + hh] / fmaxf(den0[d * NH + hh], 1e-9f);
        atomicAdd(&out0[(size_t)d * HD0 + j],
                  __bfloat162float(fs[(size_t)s * HD0 + j]) * alpha);
    }
}

// relu out0 and emit bf16 copy (into retired fs0b region)
__global__ void relu_bf16_kernel(const float* __restrict__ x,
                                 __hip_bfloat16* __restrict__ xb, int n) {
    int idx = blockIdx.x * 256 + threadIdx.x;
    if (idx < n) xb[idx] = __float2bfloat16(fmaxf(x[idx], 0.f));
}

__global__ void edge1_kernel(const int* __restrict__ src, const int* __restrict__ dst,
                             const float* __restrict__ fs1, const float* __restrict__ fd1,
                             const void* __restrict__ a1,
                             float* __restrict__ p1, float* __restrict__ den1,
                             const int* __restrict__ dflag) {
    int f32 = *dflag;
    int idx = blockIdx.x * 256 + threadIdx.x;   // e*NH + h
    if (idx >= N_EDGES * NH) return;
    int e = idx / NH, hh = idx % NH;
    int s = src[e], d = dst[e];
    float acc = 0.f;
    for (int o = 0; o < D1; ++o) {
        float x = fs1[(size_t)s * HD1 + hh * D1 + o] + fd1[(size_t)d * HD1 + hh * D1 + o];
        x = x > 0.f ? x : 0.2f * x;
        acc += x * ldin(a1, hh * D1 + o, f32);
    }
    float p = expf(acc);
    p1[idx] = p;
    atomicAdd(&den1[d * NH + hh], p);
}

// small aggregate (32-wide rows): gat_inner (z->h3) and layer1 (fs1->out1)
__global__ void agg_small_kernel(const int* __restrict__ src, const int* __restrict__ dst,
                                 const float* __restrict__ feat, const float* __restrict__ p,
                                 const float* __restrict__ den, float* __restrict__ out) {
    int idx = blockIdx.x * 256 + threadIdx.x;   // e*32 + j
    if (idx >= N_EDGES * HD1) return;
    int e = idx >> 5, j = idx & 31;
    int hh = j >> 3;
    int d = dst[e];
    float alpha = p[e * NH + hh] / fmaxf(den[d * NH + hh], 1e-9f);
    atomicAdd(&out[(size_t)d * HD1 + j], feat[(size_t)src[e] * HD1 + j] * alpha);
}

__global__ void relu_kernel(float* __restrict__ x, int n) {
    int idx = blockIdx.x * 256 + threadIdx.x;
    if (idx < n) x[idx] = fmaxf(x[idx], 0.f);
}

// final: out[n,o] = [h3 | out1] @ Wlin + blin; dual-dtype store
__global__ void final_kernel(const float* __restrict__ h3, const float* __restrict__ out1,
                             const void* __restrict__ Wlin, const void* __restrict__ blin,
                             void* __restrict__ out, const int* __restrict__ dflag) {
    int f32 = *dflag;
    int idx = blockIdx.x * 256 + threadIdx.x;   // n*OUTF + o
    if (idx >= N_NODES * OUTF) return;
    int n = idx / OUTF, o = idx % OUTF;
    float acc = ldin(blin, o, f32);
    for (int j = 0; j < HD1; ++j)
        acc += h3[(size_t)n * HD1 + j] * ldin(Wlin, j * OUTF + o, f32);
    for (int j = 0; j < HD1; ++j)
        acc += out1[(size_t)n * HD1 + j] * ldin(Wlin, (HD1 + j) * OUTF + o, f32);
    if (f32) ((float*)out)[idx] = acc;
    else     ((__hip_bfloat16*)out)[idx] = __float2bfloat16(acc);
}

// ---------------- launch ----------------
extern "C" void kernel_launch(void* const* d_in, const int* in_sizes, int n_in,
                              void* d_out, int out_size, void* d_ws, size_t ws_size,
                              hipStream_t stream) {
    const void* feats = d_in[0];
    const int*  src   = (const int*)d_in[1];
    const int*  dst   = (const int*)d_in[2];
    const void* tm    = d_in[3];
    const void* am    = d_in[4];
    const void* vm    = d_in[5];
    const void* W2    = d_in[6];
    const void* a2    = d_in[7];
    const void* Wl0   = d_in[8];
    const void* Wr0   = d_in[9];
    const void* a0    = d_in[10];
    const void* Wres0 = d_in[11];
    const void* b0    = d_in[12];
    const void* Wl1   = d_in[13];
    const void* Wr1   = d_in[14];
    const void* a1    = d_in[15];
    const void* Wres1 = d_in[16];
    const void* b1    = d_in[17];
    const void* Wlin  = d_in[18];
    const void* blin  = d_in[19];

    float* ws = (float*)d_ws;
    int*   dflag  = (int*)(ws + OFF_FLAG);
    float* colsum = ws + OFF_COLSUM;
    float* maskm  = ws + OFF_MASKM;
    float* rscale = ws + OFF_RSCALE;
    float* z      = ws + OFF_Z;
    float* es     = ws + OFF_ES;
    float* ed     = ws + OFF_ED;
    float* p2     = ws + OFF_P2;
    float* den2   = ws + OFF_DEN2;
    float* h3     = ws + OFF_H3;
    float* out0   = ws + OFF_OUT0;
    float* p0     = ws + OFF_P0;
    float* den0   = ws + OFF_DEN0;
    float* fs1    = ws + OFF_FS1;
    float* fd1    = ws + OFF_FD1;
    float* out1   = ws + OFF_OUT1;
    float* p1     = ws + OFF_P1;
    float* den1   = ws + OFF_DEN1;
    float* b0f    = ws + OFF_B0F;
    float* b1f    = ws + OFF_B1F;
    __hip_bfloat16* fs0b = (__hip_bfloat16*)(ws + OFF_FS0B);
    __hip_bfloat16* fd0b = (__hip_bfloat16*)(ws + OFF_FD0B);
    __hip_bfloat16* abf  = (__hip_bfloat16*)(ws + OFF_ABF);
    __hip_bfloat16* bt   = (__hip_bfloat16*)(ws + OFF_BT);
    __hip_bfloat16* bt1  = (__hip_bfloat16*)(ws + OFF_BT1);
    __hip_bfloat16* out0b = fs0b;   // fs0b retired after agg0; reuse as bf16 out0

    // zero accumulators (ws poisoned 0xAA before every call)
    (void)hipMemsetAsync(dflag, 0, sizeof(int), stream);
    (void)hipMemsetAsync(colsum, 0, 1280 * sizeof(float), stream);
    (void)hipMemsetAsync(den2, 0, N_NODES * NH * sizeof(float), stream);
    (void)hipMemsetAsync(den0, 0, N_NODES * NH * sizeof(float), stream);
    (void)hipMemsetAsync(den1, 0, N_NODES * NH * sizeof(float), stream);
    (void)hipMemsetAsync(h3, 0, N_NODES * HD1 * sizeof(float), stream);

    // dtype detection
    detect_kernel<<<4096, 256, 0, stream>>>((const unsigned short*)feats,
                                            N_NODES * IN_F, dflag);

    // preprocess scalars
    colsum_kernel<<<dim3(5, 40), 256, 0, stream>>>(feats, colsum, dflag);
    maskprep_kernel<<<5, 256, 0, stream>>>(tm, am, vm, maskm, dflag);
    biasprep_kernel<<<4, 256, 0, stream>>>(b0, b1, b0f, b1f, dflag);
    rowscale_kernel<<<N_NODES, 256, 0, stream>>>(feats, colsum, rscale, dflag);

    // MFMA inputs
    abf_kernel<<<N_NODES, 256, 0, stream>>>(feats, colsum, rscale, maskm, abf, dflag);
    bt_kernel<<<(KPAD * NBIG2 + 255) / 256, 256, 0, stream>>>(Wl0, Wr0, Wres0, W2, bt, dflag);
    bt1_kernel<<<(HD0 * 96 + 255) / 256, 256, 0, stream>>>(Wl1, Wr1, Wres1, bt1, dflag);

    // big fused projection GEMM (Wl0 | Wr0 | Wres0 | W2-z)
    mfma_gemm<<<dim3(NBIG2 / 128, (N_NODES + 127) / 128), 256, 0, stream>>>(
        (const unsigned short*)abf, (const unsigned short*)bt, b0f, fs0b, fd0b, out0, z);

    // gat_inner (h3)
    esed_kernel<<<(N_NODES * NH + 255) / 256, 256, 0, stream>>>(z, a2, es, ed, dflag);
    edge2_kernel<<<(N_EDGES * NH + 255) / 256, 256, 0, stream>>>(src, dst, es, ed, p2, den2);
    agg_small_kernel<<<(N_EDGES * HD1 + 255) / 256, 256, 0, stream>>>(src, dst, z, p2, den2, h3);

    // GATv2 layer 0
    edge0_kernel<<<N_EDGES, 256, 0, stream>>>(src, dst, fs0b, fd0b, a0, p0, den0, dflag);
    agg0_kernel<<<N_EDGES, 256, 0, stream>>>(src, dst, fs0b, p0, den0, out0);
    // relu + bf16 copy (overwrites fs0b region, which is now dead)
    relu_bf16_kernel<<<(N_NODES * HD0 + 255) / 256, 256, 0, stream>>>(out0, out0b,
                                                                      N_NODES * HD0);

    // GATv2 layer 1: one fused MFMA GEMM (Wl1 | Wr1 | Wres1)
    mfma_gemm96<<<(N_NODES + 127) / 128, 256, 0, stream>>>(
        (const unsigned short*)out0b, (const unsigned short*)bt1, b1f, fs1, fd1, out1);

    edge1_kernel<<<(N_EDGES * NH + 255) / 256, 256, 0, stream>>>(src, dst, fs1, fd1, a1,
                                                                 p1, den1, dflag);
    agg_small_kernel<<<(N_EDGES * HD1 + 255) / 256, 256, 0, stream>>>(src, dst, fs1, p1, den1, out1);
    relu_kernel<<<(N_NODES * HD1 + 255) / 256, 256, 0, stream>>>(out1, N_NODES * HD1);

    // final linear
    final_kernel<<<(N_NODES * OUTF + 255) / 256, 256, 0, stream>>>(h3, out1, Wlin, blin,
                                                                   d_out, dflag);
}

// Round 7
// 785.302 us; speedup vs baseline: 5.2649x; 1.3434x over previous
//
#include <hip/hip_runtime.h>
#include <hip/hip_bf16.h>

// Problem constants
#define N_NODES 10000
#define N_EDGES 64000
#define IN_F    1247
#define KPAD    1280   // IN_F padded to mult of 32
#define NH      4
#define D0      256
#define D1      8
#define HD0     1024   // NH*D0
#define HD1     32     // NH*D1
#define NBIG    3072   // Wl0 | Wr0 | Wres0
#define NBIG2   3200   // + 32 z cols (from W2) + 96 pad
#define OUTF    6
#define INV_N   (1.0f / 10000.0f)

typedef __attribute__((ext_vector_type(8))) short bf16x8;
typedef __attribute__((ext_vector_type(4))) float f32x4;

// ---------------- workspace layout (float-slot offsets), ~126.1 MB ----------------
constexpr size_t OFF_FLAG   = 0;                          // 16
constexpr size_t OFF_COLSUM = 16;                         // 1280
constexpr size_t OFF_MASKM  = 1296;                       // 1280
constexpr size_t OFF_Z      = 2576;                       // N*32
constexpr size_t OFF_ES     = OFF_Z    + 320000;          // N*4
constexpr size_t OFF_ED     = OFF_ES   + 40000;           // N*4
constexpr size_t OFF_P2     = OFF_ED   + 40000;           // E*4
constexpr size_t OFF_H3     = OFF_P2   + 256000;          // N*32
constexpr size_t OFF_OUT0   = OFF_H3   + 320000;          // N*1024 f32
constexpr size_t OFF_P0     = OFF_OUT0 + 10240000;        // E*4
constexpr size_t OFF_FS1    = OFF_P0   + 256000;          // N*32
constexpr size_t OFF_FD1    = OFF_FS1  + 320000;          // N*32
constexpr size_t OFF_OUT1   = OFF_FD1  + 320000;          // N*32
constexpr size_t OFF_P1     = OFF_OUT1 + 320000;          // E*4
constexpr size_t OFF_B0F    = OFF_P1   + 256000;          // 1024
constexpr size_t OFF_B1F    = OFF_B0F  + 1024;            // 64
constexpr size_t OFF_DEG    = OFF_B1F  + 64;              // int 10016
constexpr size_t OFF_ROWPTR = OFF_DEG  + 10016;           // int 10016
constexpr size_t OFF_CURSOR = OFF_ROWPTR + 10016;         // int 10016
constexpr size_t OFF_CSRE   = OFF_CURSOR + 10016;         // int 64000
constexpr size_t OFF_FS0B   = OFF_CSRE + 64000;           // bf16 N*1024 (reused as out0b)
constexpr size_t OFF_FD0B   = OFF_FS0B + 5120000;         // bf16 N*1024
constexpr size_t OFF_ABF    = OFF_FD0B + 5120000;         // bf16 N*KPAD
constexpr size_t OFF_BT     = OFF_ABF  + 6400000;         // bf16 NBIG2*KPAD
constexpr size_t OFF_BT1    = OFF_BT   + 2048000;         // bf16 96*1024
constexpr size_t WS_FLOATS  = OFF_BT1  + 49152;           // ~31.52M f32

// dual-dtype load: is_f32 ? float : bf16
__device__ __forceinline__ float ldin(const void* p, size_t i, int f32) {
    return f32 ? ((const float*)p)[i]
               : __bfloat162float(((const __hip_bfloat16*)p)[i]);
}
__device__ __forceinline__ float bfu2f(unsigned short u) {
    union { unsigned int i; float f; } x;
    x.i = ((unsigned int)u) << 16;
    return x.f;
}

// ---------------- kernels ----------------

// dtype detection on first 131072 words (f32 data: ~256 expected exp==0xFF hits)
__global__ void detect_kernel(const unsigned short* __restrict__ w, int n,
                              int* __restrict__ flag) {
    int i = blockIdx.x * 256 + threadIdx.x;
    int stride = gridDim.x * 256;
    int found = 0;
    for (; i < n; i += stride) {
        if (((w[i] >> 7) & 0xFF) == 0xFF) found = 1;
    }
    if (found) atomicOr(flag, 1);
}

// column sums of (dual-dtype) features. grid (5,40), block 256
__global__ void colsum_kernel(const void* __restrict__ feats,
                              float* __restrict__ colsum, const int* __restrict__ dflag) {
    int f32 = *dflag;
    int c = blockIdx.x * blockDim.x + threadIdx.x;
    if (c >= IN_F) return;
    int r0 = blockIdx.y * 250;
    float s = 0.f;
    for (int r = r0; r < r0 + 250; ++r)
        s += ldin(feats, (size_t)r * IN_F + c, f32);
    atomicAdd(&colsum[c], s);
}

// maskmul[c] = tm[c]+am[c]+vm[c]
__global__ void maskprep_kernel(const void* __restrict__ tm, const void* __restrict__ am,
                                const void* __restrict__ vm, float* __restrict__ maskmul,
                                const int* __restrict__ dflag) {
    int f32 = *dflag;
    int c = blockIdx.x * 256 + threadIdx.x;
    if (c >= IN_F) return;
    maskmul[c] = ldin(tm, c, f32) + ldin(am, c, f32) + ldin(vm, c, f32);
}

// biases -> f32
__global__ void biasprep_kernel(const void* __restrict__ b0, const void* __restrict__ b1,
                                float* __restrict__ b0f, float* __restrict__ b1f,
                                const int* __restrict__ dflag) {
    int f32 = *dflag;
    int c = blockIdx.x * 256 + threadIdx.x;
    if (c < HD0) b0f[c] = ldin(b0, c, f32);
    if (c < HD1) b1f[c] = ldin(b1, c, f32);
}

// fused: per-row L1 scale + preprocessed bf16 A row. one block per node.
__global__ __launch_bounds__(256) void prep_row_kernel(
        const void* __restrict__ feats, const float* __restrict__ colsum,
        const float* __restrict__ maskmul, __hip_bfloat16* __restrict__ abf,
        const int* __restrict__ dflag) {
    int f32 = *dflag;
    int n = blockIdx.x;
    __shared__ float red[256];
    float s = 0.f;
    for (int c = threadIdx.x; c < IN_F; c += 256) {
        float f = ldin(feats, (size_t)n * IN_F + c, f32);
        float v = (f != 0.0f) ? f : 0.5f * colsum[c] * INV_N;   // 0.5*(h+h1)
        s += fabsf(v);
    }
    red[threadIdx.x] = s;
    __syncthreads();
    for (int st = 128; st > 0; st >>= 1) {
        if (threadIdx.x < st) red[threadIdx.x] += red[threadIdx.x + st];
        __syncthreads();
    }
    float scale = 1.0f / fmaxf(red[0], 1e-12f);
    for (int k = threadIdx.x; k < KPAD; k += 256) {
        float v = 0.f;
        if (k < IN_F) {
            float f = ldin(feats, (size_t)n * IN_F + k, f32);
            float t = (f != 0.0f) ? f : 0.5f * colsum[k] * INV_N;
            v = t * scale * maskmul[k];
        }
        abf[(size_t)n * KPAD + k] = __float2bfloat16(v);
    }
}

// fused transposed B [NBIG2][KPAD]: cols 0..3071 = {Wl0|Wr0|Wres0}, 3072..3103 = W2
__global__ void bt_kernel(const void* __restrict__ Wl0, const void* __restrict__ Wr0,
                          const void* __restrict__ Wres0, const void* __restrict__ W2,
                          __hip_bfloat16* __restrict__ bt, const int* __restrict__ dflag) {
    int f32 = *dflag;
    int idx = blockIdx.x * 256 + threadIdx.x;   // k*NBIG2 + n
    if (idx >= KPAD * NBIG2) return;
    int k = idx / NBIG2, n = idx % NBIG2;
    float v = 0.f;
    if (k < IN_F) {
        if (n < NBIG) {
            int seg = n >> 10, col = n & 1023;
            const void* W = (seg == 0) ? Wl0 : (seg == 1) ? Wr0 : Wres0;
            v = ldin(W, (size_t)k * HD0 + col, f32);
        } else if (n < NBIG + HD1) {
            int col = n - NBIG;                 // h*8+o
            int hh = col >> 3, o = col & 7;
            v = ldin(W2, ((size_t)hh * IN_F + k) * D1 + o, f32);
        }
    }
    bt[(size_t)n * KPAD + k] = __float2bfloat16(v);
}

// transposed layer-1 B [96][1024]
__global__ void bt1_kernel(const void* __restrict__ Wl1, const void* __restrict__ Wr1,
                           const void* __restrict__ Wres1, __hip_bfloat16* __restrict__ bt1,
                           const int* __restrict__ dflag) {
    int f32 = *dflag;
    int idx = blockIdx.x * 256 + threadIdx.x;   // k*96 + n
    if (idx >= HD0 * 96) return;
    int k = idx / 96, n = idx % 96;
    int seg = n >> 5, col = n & 31;
    const void* W = (seg == 0) ? Wl1 : (seg == 1) ? Wr1 : Wres1;
    bt1[(size_t)n * HD0 + k] = __float2bfloat16(ldin(W, (size_t)k * HD1 + col, f32));
}

// ---- CSR build ----
__global__ void deg_kernel(const int* __restrict__ dst, int* __restrict__ deg) {
    int e = blockIdx.x * 256 + threadIdx.x;
    if (e < N_EDGES) atomicAdd(&deg[dst[e]], 1);
}

// single-block exclusive scan over deg -> rowptr (+ cursor copy)
__global__ __launch_bounds__(256) void scan_kernel(const int* __restrict__ deg,
                                                   int* __restrict__ rowptr,
                                                   int* __restrict__ cursor) {
    __shared__ int sums[256];
    __shared__ int offs[257];
    int t = threadIdx.x;
    int base = t * 40;
    int s = 0;
    for (int i = 0; i < 40; ++i) {
        int idx = base + i;
        if (idx < N_NODES) s += deg[idx];
    }
    sums[t] = s;
    __syncthreads();
    if (t == 0) {
        int run = 0;
        for (int i = 0; i < 256; ++i) { offs[i] = run; run += sums[i]; }
        offs[256] = run;
    }
    __syncthreads();
    int run = offs[t];
    for (int i = 0; i < 40; ++i) {
        int idx = base + i;
        if (idx < N_NODES) {
            rowptr[idx] = run; cursor[idx] = run;
            run += deg[idx];
        }
    }
    if (t == 255) rowptr[N_NODES] = offs[256];
}

__global__ void scatter_kernel(const int* __restrict__ dst, int* __restrict__ cursor,
                               int* __restrict__ csr_eid) {
    int e = blockIdx.x * 256 + threadIdx.x;
    if (e >= N_EDGES) return;
    int pos = atomicAdd(&cursor[dst[e]], 1);
    csr_eid[pos] = e;
}

// MFMA GEMM: C[10000 x 3200] = abf @ bt^T. Epilogue: cols 0..1023 -> fs0b (bf16),
// 1024..2047 -> fd0b (bf16), 2048..3071 -> out0 (f32, +b0), 3072..3103 -> z (f32).
#define LDSTR 40
__global__ __launch_bounds__(256) void mfma_gemm(
        const unsigned short* __restrict__ A, const unsigned short* __restrict__ BT,
        const float* __restrict__ b0f, __hip_bfloat16* __restrict__ fs0b,
        __hip_bfloat16* __restrict__ fd0b, float* __restrict__ out0,
        float* __restrict__ z) {
    __shared__ unsigned short As[128 * LDSTR];
    __shared__ unsigned short Bs[128 * LDSTR];
    const int tid = threadIdx.x;
    const int wave = tid >> 6, lane = tid & 63;
    const int quad = lane >> 4, l16 = lane & 15;
    const int wm = (wave & 1) * 64, wn = (wave >> 1) * 64;
    const int bm = blockIdx.y * 128, bn = blockIdx.x * 128;

    f32x4 acc[4][4];
#pragma unroll
    for (int i = 0; i < 4; ++i)
#pragma unroll
        for (int j = 0; j < 4; ++j) acc[i][j] = (f32x4){0.f, 0.f, 0.f, 0.f};

    for (int k0 = 0; k0 < KPAD; k0 += 32) {
#pragma unroll
        for (int cc = 0; cc < 2; ++cc) {
            int c = tid + cc * 256;
            int r = c >> 2, kc = (c & 3) << 3;
            int gm = bm + r;
            uint4 v = {0u, 0u, 0u, 0u};
            if (gm < N_NODES)
                v = *(const uint4*)(A + (size_t)gm * KPAD + k0 + kc);
            *(uint4*)(&As[r * LDSTR + kc]) = v;
            uint4 w = *(const uint4*)(BT + (size_t)(bn + r) * KPAD + k0 + kc);
            *(uint4*)(&Bs[r * LDSTR + kc]) = w;
        }
        __syncthreads();
        bf16x8 af[4], bfr[4];
#pragma unroll
        for (int i = 0; i < 4; ++i)
            af[i] = *(const bf16x8*)(&As[(wm + i * 16 + l16) * LDSTR + quad * 8]);
#pragma unroll
        for (int j = 0; j < 4; ++j)
            bfr[j] = *(const bf16x8*)(&Bs[(wn + j * 16 + l16) * LDSTR + quad * 8]);
#pragma unroll
        for (int i = 0; i < 4; ++i)
#pragma unroll
            for (int j = 0; j < 4; ++j)
                acc[i][j] = __builtin_amdgcn_mfma_f32_16x16x32_bf16(
                    af[i], bfr[j], acc[i][j], 0, 0, 0);
        __syncthreads();
    }

    const int seg = bn >> 10;
#pragma unroll
    for (int i = 0; i < 4; ++i) {
#pragma unroll
        for (int r = 0; r < 4; ++r) {
            int gm = bm + wm + i * 16 + quad * 4 + r;
            if (gm >= N_NODES) continue;
#pragma unroll
            for (int j = 0; j < 4; ++j) {
                int gnl = (bn & 1023) + wn + j * 16 + l16;
                float v = acc[i][j][r];
                if (seg == 0)      fs0b[(size_t)gm * HD0 + gnl] = __float2bfloat16(v);
                else if (seg == 1) fd0b[(size_t)gm * HD0 + gnl] = __float2bfloat16(v);
                else if (seg == 2) out0[(size_t)gm * HD0 + gnl] = v + b0f[gnl];
                else if (gnl < HD1) z[(size_t)gm * HD1 + gnl] = v;
            }
        }
    }
}

// layer-1 fused MFMA GEMM: C[10000 x 96] = out0b @ bt1^T, K=1024.
__global__ __launch_bounds__(256) void mfma_gemm96(
        const unsigned short* __restrict__ A, const unsigned short* __restrict__ BT1,
        const float* __restrict__ b1f, float* __restrict__ fs1,
        float* __restrict__ fd1, float* __restrict__ out1) {
    __shared__ unsigned short As[128 * LDSTR];
    __shared__ unsigned short Bs[96 * LDSTR];
    const int tid = threadIdx.x;
    const int wave = tid >> 6, lane = tid & 63;
    const int quad = lane >> 4, l16 = lane & 15;
    const int bm = blockIdx.x * 128;

    f32x4 acc[2][6];
#pragma unroll
    for (int i = 0; i < 2; ++i)
#pragma unroll
        for (int j = 0; j < 6; ++j) acc[i][j] = (f32x4){0.f, 0.f, 0.f, 0.f};

    for (int k0 = 0; k0 < HD0; k0 += 32) {
#pragma unroll
        for (int cc = 0; cc < 2; ++cc) {
            int c = tid + cc * 256;
            int r = c >> 2, kc = (c & 3) << 3;
            int gm = bm + r;
            uint4 v = {0u, 0u, 0u, 0u};
            if (gm < N_NODES)
                v = *(const uint4*)(A + (size_t)gm * HD0 + k0 + kc);
            *(uint4*)(&As[r * LDSTR + kc]) = v;
            if (c < 384) {
                uint4 w = *(const uint4*)(BT1 + (size_t)r * HD0 + k0 + kc);
                *(uint4*)(&Bs[r * LDSTR + kc]) = w;
            }
        }
        __syncthreads();
        bf16x8 af[2], bfr[6];
#pragma unroll
        for (int i = 0; i < 2; ++i)
            af[i] = *(const bf16x8*)(&As[(wave * 32 + i * 16 + l16) * LDSTR + quad * 8]);
#pragma unroll
        for (int j = 0; j < 6; ++j)
            bfr[j] = *(const bf16x8*)(&Bs[(j * 16 + l16) * LDSTR + quad * 8]);
#pragma unroll
        for (int i = 0; i < 2; ++i)
#pragma unroll
            for (int j = 0; j < 6; ++j)
                acc[i][j] = __builtin_amdgcn_mfma_f32_16x16x32_bf16(
                    af[i], bfr[j], acc[i][j], 0, 0, 0);
        __syncthreads();
    }

#pragma unroll
    for (int i = 0; i < 2; ++i) {
#pragma unroll
        for (int r = 0; r < 4; ++r) {
            int gm = bm + wave * 32 + i * 16 + quad * 4 + r;
            if (gm >= N_NODES) continue;
#pragma unroll
            for (int j = 0; j < 6; ++j) {
                int col = j * 16 + l16;
                int seg = col >> 5, cl = col & 31;
                float v = acc[i][j][r];
                if (seg == 0)      fs1[(size_t)gm * HD1 + cl] = v;
                else if (seg == 1) fd1[(size_t)gm * HD1 + cl] = v;
                else               out1[(size_t)gm * HD1 + cl] = v + b1f[cl];
            }
        }
    }
}

// es/ed for gat_inner
__global__ void esed_kernel(const float* __restrict__ z, const void* __restrict__ a2,
                            float* __restrict__ es, float* __restrict__ ed,
                            const int* __restrict__ dflag) {
    int f32 = *dflag;
    int idx = blockIdx.x * 256 + threadIdx.x;   // n*NH + h
    if (idx >= N_NODES * NH) return;
    int hh = idx % NH;
    const float* zp = z + (size_t)idx * D1;
    float s1 = 0.f, s2 = 0.f;
    for (int o = 0; o < D1; ++o) {
        float zv = zp[o];
        s1 += zv * ldin(a2, hh * 2 * D1 + o, f32);
        s2 += zv * ldin(a2, hh * 2 * D1 + D1 + o, f32);
    }
    es[idx] = s1; ed[idx] = s2;
}

// gat_inner edge: p2 only (no den atomics — den computed in CSR agg)
__global__ void edge2_kernel(const int* __restrict__ src, const int* __restrict__ dst,
                             const float* __restrict__ es, const float* __restrict__ ed,
                             float* __restrict__ p2) {
    int idx = blockIdx.x * 256 + threadIdx.x;   // e*NH + h
    if (idx >= N_EDGES * NH) return;
    int e = idx / NH, hh = idx % NH;
    float x = es[src[e] * NH + hh] + ed[dst[e] * NH + hh];
    x = x > 0.f ? x : 0.2f * x;
    p2[idx] = expf(x);
}

// GATv2 layer0 logits, vectorized (ushort4/lane): p0 only
__global__ __launch_bounds__(256) void edge0_kernel(
        const int* __restrict__ src, const int* __restrict__ dst,
        const __hip_bfloat16* __restrict__ fs, const __hip_bfloat16* __restrict__ fd,
        const void* __restrict__ a0, float* __restrict__ p0,
        const int* __restrict__ dflag) {
    int f32 = *dflag;
    int e = blockIdx.x;
    int lane = threadIdx.x & 63, hh = threadIdx.x >> 6;
    int s = src[e], d = dst[e];
    const unsigned short* fsp = (const unsigned short*)fs + (size_t)s * HD0 + hh * D0;
    const unsigned short* fdp = (const unsigned short*)fd + (size_t)d * HD0 + hh * D0;
    ushort4 a = *(const ushort4*)(fsp + lane * 4);
    ushort4 b = *(const ushort4*)(fdp + lane * 4);
    float acc = 0.f;
#pragma unroll
    for (int i = 0; i < 4; ++i) {
        unsigned short ua = (i == 0) ? a.x : (i == 1) ? a.y : (i == 2) ? a.z : a.w;
        unsigned short ub = (i == 0) ? b.x : (i == 1) ? b.y : (i == 2) ? b.z : b.w;
        float x = bfu2f(ua) + bfu2f(ub);
        x = x > 0.f ? x : 0.2f * x;
        acc += x * ldin(a0, hh * D0 + lane * 4 + i, f32);
    }
    for (int off = 32; off > 0; off >>= 1) acc += __shfl_down(acc, off);
    if (lane == 0) p0[e * NH + hh] = expf(acc);
}

// CSR aggregation, 1024-wide: out0[n] += sum_e alpha * fs[src(e)]
__global__ __launch_bounds__(256) void agg0_csr_kernel(
        const int* __restrict__ rowptr, const int* __restrict__ csr_eid,
        const int* __restrict__ src, const __hip_bfloat16* __restrict__ fs,
        const float* __restrict__ p0, float* __restrict__ out0) {
    int n = blockIdx.x;
    int start = rowptr[n], end = rowptr[n + 1];
    int tid = threadIdx.x;
    __shared__ float invden[NH];
    if (tid < NH) {
        float s = 0.f;
        for (int i = start; i < end; ++i) s += p0[csr_eid[i] * NH + tid];
        invden[tid] = 1.0f / fmaxf(s, 1e-9f);
    }
    __syncthreads();
    float acc0x = 0.f, acc0y = 0.f, acc1x = 0.f, acc1y = 0.f;
    int base0 = 2 * tid;            // cols base0, base0+1   (head base0>>8)
    int base1 = 512 + 2 * tid;      // cols base1, base1+1
    int h0 = base0 >> 8, h1 = base1 >> 8;
    const unsigned short* fsu = (const unsigned short*)fs;
    for (int i = start; i < end; ++i) {
        int e = csr_eid[i];
        int s = src[e];
        float a0v = p0[e * NH + h0] * invden[h0];
        float a1v = p0[e * NH + h1] * invden[h1];
        unsigned int u0 = *(const unsigned int*)(fsu + (size_t)s * HD0 + base0);
        unsigned int u1 = *(const unsigned int*)(fsu + (size_t)s * HD0 + base1);
        acc0x += bfu2f((unsigned short)(u0 & 0xFFFF)) * a0v;
        acc0y += bfu2f((unsigned short)(u0 >> 16)) * a0v;
        acc1x += bfu2f((unsigned short)(u1 & 0xFFFF)) * a1v;
        acc1y += bfu2f((unsigned short)(u1 >> 16)) * a1v;
    }
    float2* o0 = (float2*)(out0 + (size_t)n * HD0 + base0);
    float2* o1 = (float2*)(out0 + (size_t)n * HD0 + base1);
    float2 v0 = *o0, v1 = *o1;
    v0.x += acc0x; v0.y += acc0y; v1.x += acc1x; v1.y += acc1y;
    *o0 = v0; *o1 = v1;
}

// CSR aggregation, 32-wide (f32 feat): out[n] += sum_e alpha * feat[src(e)]
__global__ __launch_bounds__(64) void agg32_csr_kernel(
        const int* __restrict__ rowptr, const int* __restrict__ csr_eid,
        const int* __restrict__ src, const float* __restrict__ feat,
        const float* __restrict__ p, float* __restrict__ out) {
    int n = blockIdx.x;
    int start = rowptr[n], end = rowptr[n + 1];
    int lane = threadIdx.x;
    __shared__ float invden[NH];
    if (lane < NH) {
        float s = 0.f;
        for (int i = start; i < end; ++i) s += p[csr_eid[i] * NH + lane];
        invden[lane] = 1.0f / fmaxf(s, 1e-9f);
    }
    __syncthreads();
    if (lane >= HD1) return;
    int hh = lane >> 3;
    float acc = 0.f;
    for (int i = start; i < end; ++i) {
        int e = csr_eid[i];
        acc += feat[(size_t)src[e] * HD1 + lane] * p[e * NH + hh] * invden[hh];
    }
    out[(size_t)n * HD1 + lane] += acc;
}

// relu out0 and emit bf16 copy (into retired fs0b region)
__global__ void relu_bf16_kernel(const float* __restrict__ x,
                                 __hip_bfloat16* __restrict__ xb, int n) {
    int idx = blockIdx.x * 256 + threadIdx.x;
    if (idx < n) xb[idx] = __float2bfloat16(fmaxf(x[idx], 0.f));
}

// layer1 edge: p1 only
__global__ void edge1_kernel(const int* __restrict__ src, const int* __restrict__ dst,
                             const float* __restrict__ fs1, const float* __restrict__ fd1,
                             const void* __restrict__ a1, float* __restrict__ p1,
                             const int* __restrict__ dflag) {
    int f32 = *dflag;
    int idx = blockIdx.x * 256 + threadIdx.x;   // e*NH + h
    if (idx >= N_EDGES * NH) return;
    int e = idx / NH, hh = idx % NH;
    int s = src[e], d = dst[e];
    float acc = 0.f;
    for (int o = 0; o < D1; ++o) {
        float x = fs1[(size_t)s * HD1 + hh * D1 + o] + fd1[(size_t)d * HD1 + hh * D1 + o];
        x = x > 0.f ? x : 0.2f * x;
        acc += x * ldin(a1, hh * D1 + o, f32);
    }
    p1[idx] = expf(acc);
}

__global__ void relu_kernel(float* __restrict__ x, int n) {
    int idx = blockIdx.x * 256 + threadIdx.x;
    if (idx < n) x[idx] = fmaxf(x[idx], 0.f);
}

// final: out[n,o] = [h3 | out1] @ Wlin + blin; dual-dtype store
__global__ void final_kernel(const float* __restrict__ h3, const float* __restrict__ out1,
                             const void* __restrict__ Wlin, const void* __restrict__ blin,
                             void* __restrict__ out, const int* __restrict__ dflag) {
    int f32 = *dflag;
    int idx = blockIdx.x * 256 + threadIdx.x;   // n*OUTF + o
    if (idx >= N_NODES * OUTF) return;
    int n = idx / OUTF, o = idx % OUTF;
    float acc = ldin(blin, o, f32);
    for (int j = 0; j < HD1; ++j)
        acc += h3[(size_t)n * HD1 + j] * ldin(Wlin, j * OUTF + o, f32);
    for (int j = 0; j < HD1; ++j)
        acc += out1[(size_t)n * HD1 + j] * ldin(Wlin, (HD1 + j) * OUTF + o, f32);
    if (f32) ((float*)out)[idx] = acc;
    else     ((__hip_bfloat16*)out)[idx] = __float2bfloat16(acc);
}

// ---------------- launch ----------------
extern "C" void kernel_launch(void* const* d_in, const int* in_sizes, int n_in,
                              void* d_out, int out_size, void* d_ws, size_t ws_size,
                              hipStream_t stream) {
    const void* feats = d_in[0];
    const int*  src   = (const int*)d_in[1];
    const int*  dst   = (const int*)d_in[2];
    const void* tm    = d_in[3];
    const void* am    = d_in[4];
    const void* vm    = d_in[5];
    const void* W2    = d_in[6];
    const void* a2    = d_in[7];
    const void* Wl0   = d_in[8];
    const void* Wr0   = d_in[9];
    const void* a0    = d_in[10];
    const void* Wres0 = d_in[11];
    const void* b0    = d_in[12];
    const void* Wl1   = d_in[13];
    const void* Wr1   = d_in[14];
    const void* a1    = d_in[15];
    const void* Wres1 = d_in[16];
    const void* b1    = d_in[17];
    const void* Wlin  = d_in[18];
    const void* blin  = d_in[19];

    float* ws = (float*)d_ws;
    int*   dflag  = (int*)(ws + OFF_FLAG);
    float* colsum = ws + OFF_COLSUM;
    float* maskm  = ws + OFF_MASKM;
    float* z      = ws + OFF_Z;
    float* es     = ws + OFF_ES;
    float* ed     = ws + OFF_ED;
    float* p2     = ws + OFF_P2;
    float* h3     = ws + OFF_H3;
    float* out0   = ws + OFF_OUT0;
    float* p0     = ws + OFF_P0;
    float* fs1    = ws + OFF_FS1;
    float* fd1    = ws + OFF_FD1;
    float* out1   = ws + OFF_OUT1;
    float* p1     = ws + OFF_P1;
    float* b0f    = ws + OFF_B0F;
    float* b1f    = ws + OFF_B1F;
    int*   deg    = (int*)(ws + OFF_DEG);
    int*   rowptr = (int*)(ws + OFF_ROWPTR);
    int*   cursor = (int*)(ws + OFF_CURSOR);
    int*   csre   = (int*)(ws + OFF_CSRE);
    __hip_bfloat16* fs0b = (__hip_bfloat16*)(ws + OFF_FS0B);
    __hip_bfloat16* fd0b = (__hip_bfloat16*)(ws + OFF_FD0B);
    __hip_bfloat16* abf  = (__hip_bfloat16*)(ws + OFF_ABF);
    __hip_bfloat16* bt   = (__hip_bfloat16*)(ws + OFF_BT);
    __hip_bfloat16* bt1  = (__hip_bfloat16*)(ws + OFF_BT1);
    __hip_bfloat16* out0b = fs0b;   // fs0b retired after agg0; reuse

    // zero accumulators (ws poisoned 0xAA before every call)
    (void)hipMemsetAsync(dflag, 0, sizeof(int), stream);
    (void)hipMemsetAsync(colsum, 0, 1280 * sizeof(float), stream);
    (void)hipMemsetAsync(h3, 0, N_NODES * HD1 * sizeof(float), stream);
    (void)hipMemsetAsync(deg, 0, N_NODES * sizeof(int), stream);

    // dtype detection (subset scan)
    detect_kernel<<<64, 256, 0, stream>>>((const unsigned short*)feats, 131072, dflag);

    // CSR build
    deg_kernel<<<(N_EDGES + 255) / 256, 256, 0, stream>>>(dst, deg);
    scan_kernel<<<1, 256, 0, stream>>>(deg, rowptr, cursor);
    scatter_kernel<<<(N_EDGES + 255) / 256, 256, 0, stream>>>(dst, cursor, csre);

    // preprocess
    colsum_kernel<<<dim3(5, 40), 256, 0, stream>>>(feats, colsum, dflag);
    maskprep_kernel<<<5, 256, 0, stream>>>(tm, am, vm, maskm, dflag);
    biasprep_kernel<<<4, 256, 0, stream>>>(b0, b1, b0f, b1f, dflag);
    prep_row_kernel<<<N_NODES, 256, 0, stream>>>(feats, colsum, maskm, abf, dflag);
    bt_kernel<<<(KPAD * NBIG2 + 255) / 256, 256, 0, stream>>>(Wl0, Wr0, Wres0, W2, bt, dflag);
    bt1_kernel<<<(HD0 * 96 + 255) / 256, 256, 0, stream>>>(Wl1, Wr1, Wres1, bt1, dflag);

    // big fused projection GEMM (Wl0 | Wr0 | Wres0 | W2-z)
    mfma_gemm<<<dim3(NBIG2 / 128, (N_NODES + 127) / 128), 256, 0, stream>>>(
        (const unsigned short*)abf, (const unsigned short*)bt, b0f, fs0b, fd0b, out0, z);

    // gat_inner (h3)
    esed_kernel<<<(N_NODES * NH + 255) / 256, 256, 0, stream>>>(z, a2, es, ed, dflag);
    edge2_kernel<<<(N_EDGES * NH + 255) / 256, 256, 0, stream>>>(src, dst, es, ed, p2);
    agg32_csr_kernel<<<N_NODES, 64, 0, stream>>>(rowptr, csre, src, z, p2, h3);

    // GATv2 layer 0
    edge0_kernel<<<N_EDGES, 256, 0, stream>>>(src, dst, fs0b, fd0b, a0, p0, dflag);
    agg0_csr_kernel<<<N_NODES, 256, 0, stream>>>(rowptr, csre, src, fs0b, p0, out0);
    relu_bf16_kernel<<<(N_NODES * HD0 + 255) / 256, 256, 0, stream>>>(out0, out0b,
                                                                      N_NODES * HD0);

    // GATv2 layer 1
    mfma_gemm96<<<(N_NODES + 127) / 128, 256, 0, stream>>>(
        (const unsigned short*)out0b, (const unsigned short*)bt1, b1f, fs1, fd1, out1);
    edge1_kernel<<<(N_EDGES * NH + 255) / 256, 256, 0, stream>>>(src, dst, fs1, fd1, a1,
                                                                 p1, dflag);
    agg32_csr_kernel<<<N_NODES, 64, 0, stream>>>(rowptr, csre, src, fs1, p1, out1);
    relu_kernel<<<(N_NODES * HD1 + 255) / 256, 256, 0, stream>>>(out1, N_NODES * HD1);

    // final linear
    final_kernel<<<(N_NODES * OUTF + 255) / 256, 256, 0, stream>>>(h3, out1, Wlin, blin,
                                                                   d_out, dflag);
}

// Round 8
// 758.366 us; speedup vs baseline: 5.4519x; 1.0355x over previous
//
#include <hip/hip_runtime.h>
#include <hip/hip_bf16.h>

// Problem constants
#define N_NODES 10000
#define N_EDGES 64000
#define IN_F    1247
#define KPAD    1280   // IN_F padded to mult of 32
#define NH      4
#define D0      256
#define D1      8
#define HD0     1024   // NH*D0
#define HD1     32     // NH*D1
#define NBIG    3072   // Wl0 | Wr0 | Wres0
#define NBIG2   3200   // + 32 z cols (from W2) + 96 pad
#define OUTF    6
#define INV_N   (1.0f / 10000.0f)
#define MPAD    10112  // N_NODES padded to mult of 128 (for guard-free DMA staging)

typedef __attribute__((ext_vector_type(8))) short bf16x8;
typedef __attribute__((ext_vector_type(4))) float f32x4;
typedef unsigned int u32;

// async 16B global -> LDS (DMA). LDS dest: wave-uniform base + lane*16.
__device__ __forceinline__ void async_copy16(const unsigned short* gsrc,
                                             unsigned short* ldst) {
    __builtin_amdgcn_global_load_lds(
        (const __attribute__((address_space(1))) u32*)(gsrc),
        (__attribute__((address_space(3))) u32*)(ldst), 16, 0, 0);
}

// ---------------- workspace layout (float-slot offsets), ~126.4 MB ----------------
constexpr size_t OFF_FLAG   = 0;                          // 16
constexpr size_t OFF_COLSUM = 16;                         // 1280
constexpr size_t OFF_MASKM  = 1296;                       // 1280
constexpr size_t OFF_Z      = 2576;                       // N*32
constexpr size_t OFF_ES     = OFF_Z    + 320000;          // N*4
constexpr size_t OFF_ED     = OFF_ES   + 40000;           // N*4
constexpr size_t OFF_P2     = OFF_ED   + 40000;           // E*4
constexpr size_t OFF_H3     = OFF_P2   + 256000;          // N*32
constexpr size_t OFF_OUT0   = OFF_H3   + 320000;          // N*1024 f32
constexpr size_t OFF_P0     = OFF_OUT0 + 10240000;        // E*4
constexpr size_t OFF_FS1    = OFF_P0   + 256000;          // N*32
constexpr size_t OFF_FD1    = OFF_FS1  + 320000;          // N*32
constexpr size_t OFF_OUT1   = OFF_FD1  + 320000;          // N*32
constexpr size_t OFF_P1     = OFF_OUT1 + 320000;          // E*4
constexpr size_t OFF_B0F    = OFF_P1   + 256000;          // 1024
constexpr size_t OFF_B1F    = OFF_B0F  + 1024;            // 64
constexpr size_t OFF_DEG    = OFF_B1F  + 64;              // int 10016
constexpr size_t OFF_ROWPTR = OFF_DEG  + 10016;           // int 10016
constexpr size_t OFF_CURSOR = OFF_ROWPTR + 10016;         // int 10016
constexpr size_t OFF_CSRE   = OFF_CURSOR + 10016;         // int 64000
constexpr size_t OFF_FS0B   = OFF_CSRE + 64000;           // bf16 N*1024 (reused as out0b)
constexpr size_t OFF_FD0B   = OFF_FS0B + 5120000;         // bf16 N*1024
constexpr size_t OFF_ABF    = OFF_FD0B + 5120000;         // bf16 MPAD*KPAD -> 6,471,680 slots
constexpr size_t OFF_BT     = OFF_ABF  + 6471680;         // bf16 NBIG2*KPAD
constexpr size_t OFF_BT1    = OFF_BT   + 2048000;         // bf16 96*1024
constexpr size_t WS_FLOATS  = OFF_BT1  + 49152;           // ~31.59M f32

// dual-dtype load: is_f32 ? float : bf16
__device__ __forceinline__ float ldin(const void* p, size_t i, int f32) {
    return f32 ? ((const float*)p)[i]
               : __bfloat162float(((const __hip_bfloat16*)p)[i]);
}
__device__ __forceinline__ float bfu2f(unsigned short u) {
    union { unsigned int i; float f; } x;
    x.i = ((unsigned int)u) << 16;
    return x.f;
}

// ---------------- kernels ----------------

// dtype detection on first 131072 words (f32 data: ~256 expected exp==0xFF hits)
__global__ void detect_kernel(const unsigned short* __restrict__ w, int n,
                              int* __restrict__ flag) {
    int i = blockIdx.x * 256 + threadIdx.x;
    int stride = gridDim.x * 256;
    int found = 0;
    for (; i < n; i += stride) {
        if (((w[i] >> 7) & 0xFF) == 0xFF) found = 1;
    }
    if (found) atomicOr(flag, 1);
}

// column sums of (dual-dtype) features. grid (5,40), block 256
__global__ void colsum_kernel(const void* __restrict__ feats,
                              float* __restrict__ colsum, const int* __restrict__ dflag) {
    int f32 = *dflag;
    int c = blockIdx.x * blockDim.x + threadIdx.x;
    if (c >= IN_F) return;
    int r0 = blockIdx.y * 250;
    float s = 0.f;
    for (int r = r0; r < r0 + 250; ++r)
        s += ldin(feats, (size_t)r * IN_F + c, f32);
    atomicAdd(&colsum[c], s);
}

// maskmul[c] = tm[c]+am[c]+vm[c]
__global__ void maskprep_kernel(const void* __restrict__ tm, const void* __restrict__ am,
                                const void* __restrict__ vm, float* __restrict__ maskmul,
                                const int* __restrict__ dflag) {
    int f32 = *dflag;
    int c = blockIdx.x * 256 + threadIdx.x;
    if (c >= IN_F) return;
    maskmul[c] = ldin(tm, c, f32) + ldin(am, c, f32) + ldin(vm, c, f32);
}

// biases -> f32
__global__ void biasprep_kernel(const void* __restrict__ b0, const void* __restrict__ b1,
                                float* __restrict__ b0f, float* __restrict__ b1f,
                                const int* __restrict__ dflag) {
    int f32 = *dflag;
    int c = blockIdx.x * 256 + threadIdx.x;
    if (c < HD0) b0f[c] = ldin(b0, c, f32);
    if (c < HD1) b1f[c] = ldin(b1, c, f32);
}

// fused single-pass: impute row into LDS, L1-scale, mask, emit bf16 A row
__global__ __launch_bounds__(256) void prep_row_kernel(
        const void* __restrict__ feats, const float* __restrict__ colsum,
        const float* __restrict__ maskmul, __hip_bfloat16* __restrict__ abf,
        const int* __restrict__ dflag) {
    int f32 = *dflag;
    int n = blockIdx.x;
    __shared__ float rowbuf[IN_F];
    __shared__ float red[256];
    float s = 0.f;
    for (int c = threadIdx.x; c < IN_F; c += 256) {
        float f = ldin(feats, (size_t)n * IN_F + c, f32);
        float v = (f != 0.0f) ? f : 0.5f * colsum[c] * INV_N;   // 0.5*(h+h1)
        rowbuf[c] = v;
        s += fabsf(v);
    }
    red[threadIdx.x] = s;
    __syncthreads();
    for (int st = 128; st > 0; st >>= 1) {
        if (threadIdx.x < st) red[threadIdx.x] += red[threadIdx.x + st];
        __syncthreads();
    }
    float scale = 1.0f / fmaxf(red[0], 1e-12f);
    for (int k = threadIdx.x; k < KPAD; k += 256) {
        float v = (k < IN_F) ? rowbuf[k] * scale * maskmul[k] : 0.f;
        abf[(size_t)n * KPAD + k] = __float2bfloat16(v);
    }
}

// fused transposed B [NBIG2][KPAD]: cols 0..3071 = {Wl0|Wr0|Wres0}, 3072..3103 = W2
__global__ void bt_kernel(const void* __restrict__ Wl0, const void* __restrict__ Wr0,
                          const void* __restrict__ Wres0, const void* __restrict__ W2,
                          __hip_bfloat16* __restrict__ bt, const int* __restrict__ dflag) {
    int f32 = *dflag;
    int idx = blockIdx.x * 256 + threadIdx.x;   // k*NBIG2 + n
    if (idx >= KPAD * NBIG2) return;
    int k = idx / NBIG2, n = idx % NBIG2;
    float v = 0.f;
    if (k < IN_F) {
        if (n < NBIG) {
            int seg = n >> 10, col = n & 1023;
            const void* W = (seg == 0) ? Wl0 : (seg == 1) ? Wr0 : Wres0;
            v = ldin(W, (size_t)k * HD0 + col, f32);
        } else if (n < NBIG + HD1) {
            int col = n - NBIG;                 // h*8+o
            int hh = col >> 3, o = col & 7;
            v = ldin(W2, ((size_t)hh * IN_F + k) * D1 + o, f32);
        }
    }
    bt[(size_t)n * KPAD + k] = __float2bfloat16(v);
}

// transposed layer-1 B [96][1024]
__global__ void bt1_kernel(const void* __restrict__ Wl1, const void* __restrict__ Wr1,
                           const void* __restrict__ Wres1, __hip_bfloat16* __restrict__ bt1,
                           const int* __restrict__ dflag) {
    int f32 = *dflag;
    int idx = blockIdx.x * 256 + threadIdx.x;   // k*96 + n
    if (idx >= HD0 * 96) return;
    int k = idx / 96, n = idx % 96;
    int seg = n >> 5, col = n & 31;
    const void* W = (seg == 0) ? Wl1 : (seg == 1) ? Wr1 : Wres1;
    bt1[(size_t)n * HD0 + k] = __float2bfloat16(ldin(W, (size_t)k * HD1 + col, f32));
}

// ---- CSR build ----
__global__ void deg_kernel(const int* __restrict__ dst, int* __restrict__ deg) {
    int e = blockIdx.x * 256 + threadIdx.x;
    if (e < N_EDGES) atomicAdd(&deg[dst[e]], 1);
}

__global__ __launch_bounds__(256) void scan_kernel(const int* __restrict__ deg,
                                                   int* __restrict__ rowptr,
                                                   int* __restrict__ cursor) {
    __shared__ int sums[256];
    __shared__ int offs[257];
    int t = threadIdx.x;
    int base = t * 40;
    int s = 0;
    for (int i = 0; i < 40; ++i) {
        int idx = base + i;
        if (idx < N_NODES) s += deg[idx];
    }
    sums[t] = s;
    __syncthreads();
    if (t == 0) {
        int run = 0;
        for (int i = 0; i < 256; ++i) { offs[i] = run; run += sums[i]; }
        offs[256] = run;
    }
    __syncthreads();
    int run = offs[t];
    for (int i = 0; i < 40; ++i) {
        int idx = base + i;
        if (idx < N_NODES) {
            rowptr[idx] = run; cursor[idx] = run;
            run += deg[idx];
        }
    }
    if (t == 255) rowptr[N_NODES] = offs[256];
}

__global__ void scatter_kernel(const int* __restrict__ dst, int* __restrict__ cursor,
                               int* __restrict__ csr_eid) {
    int e = blockIdx.x * 256 + threadIdx.x;
    if (e >= N_EDGES) return;
    int pos = atomicAdd(&cursor[dst[e]], 1);
    csr_eid[pos] = e;
}

// MFMA GEMM: C[MPAD x 3200] = abf @ bt^T via global_load_lds DMA staging with
// fragment-major LDS chunks (chunk f*64+lane = A[row f*16+(lane&15)][k (lane>>4)*8])
// -> MFMA fragment reads are ds_read_b128 at base+lane*16 (conflict-free).
// Epilogue: cols 0..1023 -> fs0b (bf16), 1024..2047 -> fd0b (bf16),
// 2048..3071 -> out0 (f32, +b0), 3072..3103 -> z (f32).
__global__ __launch_bounds__(256) void mfma_gemm(
        const unsigned short* __restrict__ A, const unsigned short* __restrict__ BT,
        const float* __restrict__ b0f, __hip_bfloat16* __restrict__ fs0b,
        __hip_bfloat16* __restrict__ fd0b, float* __restrict__ out0,
        float* __restrict__ z) {
    __shared__ unsigned short As[128 * 32];   // 8KB, fragment-major chunks
    __shared__ unsigned short Bs[128 * 32];   // 8KB
    const int tid = threadIdx.x;
    const int wave = tid >> 6, lane = tid & 63;
    const int quad = lane >> 4, l16 = lane & 15;
    const int wm = (wave & 1) * 64, wn = (wave >> 1) * 64;
    const int bm = blockIdx.y * 128, bn = blockIdx.x * 128;
    const int srow = lane & 15;          // staging: row within 16-row group
    const int skc  = (lane >> 4) * 8;    // staging: k offset (ushorts)

    f32x4 acc[4][4];
#pragma unroll
    for (int i = 0; i < 4; ++i)
#pragma unroll
        for (int j = 0; j < 4; ++j) acc[i][j] = (f32x4){0.f, 0.f, 0.f, 0.f};

    for (int k0 = 0; k0 < KPAD; k0 += 32) {
        // DMA-stage A and B tiles: each wave deposits 2 groups of 64 chunks each
#pragma unroll
        for (int t = 0; t < 2; ++t) {
            int f = t * 4 + wave;
            async_copy16(A + (size_t)(bm + f * 16 + srow) * KPAD + k0 + skc,
                         As + f * 512);
            async_copy16(BT + (size_t)(bn + f * 16 + srow) * KPAD + k0 + skc,
                         Bs + f * 512);
        }
        __syncthreads();   // drains vmcnt (global_load_lds) before reads
        bf16x8 af[4], bfr[4];
#pragma unroll
        for (int i = 0; i < 4; ++i)
            af[i] = *(const bf16x8*)(As + ((wave & 1) * 4 + i) * 512 + lane * 8);
#pragma unroll
        for (int j = 0; j < 4; ++j)
            bfr[j] = *(const bf16x8*)(Bs + ((wave >> 1) * 4 + j) * 512 + lane * 8);
#pragma unroll
        for (int i = 0; i < 4; ++i)
#pragma unroll
            for (int j = 0; j < 4; ++j)
                acc[i][j] = __builtin_amdgcn_mfma_f32_16x16x32_bf16(
                    af[i], bfr[j], acc[i][j], 0, 0, 0);
        __syncthreads();
    }

    const int seg = bn >> 10;
#pragma unroll
    for (int i = 0; i < 4; ++i) {
#pragma unroll
        for (int r = 0; r < 4; ++r) {
            int gm = bm + wm + i * 16 + quad * 4 + r;
            if (gm >= N_NODES) continue;
#pragma unroll
            for (int j = 0; j < 4; ++j) {
                int gnl = (bn & 1023) + wn + j * 16 + l16;
                float v = acc[i][j][r];
                if (seg == 0)      fs0b[(size_t)gm * HD0 + gnl] = __float2bfloat16(v);
                else if (seg == 1) fd0b[(size_t)gm * HD0 + gnl] = __float2bfloat16(v);
                else if (seg == 2) out0[(size_t)gm * HD0 + gnl] = v + b0f[gnl];
                else if (gnl < HD1) z[(size_t)gm * HD1 + gnl] = v;
            }
        }
    }
}

// layer-1 fused MFMA GEMM: C[10000 x 96] = out0b @ bt1^T, K=1024, 64-row tiles
// (grid 157), same DMA fragment-major staging. cols 0..31 -> fs1, 32..63 -> fd1,
// 64..95 -> out1(+b1).
__global__ __launch_bounds__(256) void mfma_gemm96(
        const unsigned short* __restrict__ A, const unsigned short* __restrict__ BT1,
        const float* __restrict__ b1f, float* __restrict__ fs1,
        float* __restrict__ fd1, float* __restrict__ out1) {
    __shared__ unsigned short As[64 * 32];    // 4KB: 4 groups
    __shared__ unsigned short Bs[96 * 32];    // 6KB: 6 groups
    const int tid = threadIdx.x;
    const int wave = tid >> 6, lane = tid & 63;
    const int quad = lane >> 4, l16 = lane & 15;
    const int bm = blockIdx.x * 64;
    const int srow = lane & 15;
    const int skc  = (lane >> 4) * 8;

    f32x4 acc[6];
#pragma unroll
    for (int j = 0; j < 6; ++j) acc[j] = (f32x4){0.f, 0.f, 0.f, 0.f};

    for (int k0 = 0; k0 < HD0; k0 += 32) {
        // A: 4 groups (one per wave); B: 6 groups (waves 0..3 then waves 0..1)
        async_copy16(A + (size_t)(bm + wave * 16 + srow) * HD0 + k0 + skc,
                     As + wave * 512);
        async_copy16(BT1 + (size_t)(wave * 16 + srow) * HD0 + k0 + skc,
                     Bs + wave * 512);
        if (wave < 2) {
            int f = 4 + wave;
            async_copy16(BT1 + (size_t)(f * 16 + srow) * HD0 + k0 + skc,
                         Bs + f * 512);
        }
        __syncthreads();
        bf16x8 af = *(const bf16x8*)(As + wave * 512 + lane * 8);
#pragma unroll
        for (int j = 0; j < 6; ++j) {
            bf16x8 bfr = *(const bf16x8*)(Bs + j * 512 + lane * 8);
            acc[j] = __builtin_amdgcn_mfma_f32_16x16x32_bf16(af, bfr, acc[j], 0, 0, 0);
        }
        __syncthreads();
    }

#pragma unroll
    for (int r = 0; r < 4; ++r) {
        int gm = bm + wave * 16 + quad * 4 + r;
        if (gm >= N_NODES) continue;
#pragma unroll
        for (int j = 0; j < 6; ++j) {
            int col = j * 16 + l16;
            int seg = col >> 5, cl = col & 31;
            float v = acc[j][r];
            if (seg == 0)      fs1[(size_t)gm * HD1 + cl] = v;
            else if (seg == 1) fd1[(size_t)gm * HD1 + cl] = v;
            else               out1[(size_t)gm * HD1 + cl] = v + b1f[cl];
        }
    }
}

// es/ed for gat_inner
__global__ void esed_kernel(const float* __restrict__ z, const void* __restrict__ a2,
                            float* __restrict__ es, float* __restrict__ ed,
                            const int* __restrict__ dflag) {
    int f32 = *dflag;
    int idx = blockIdx.x * 256 + threadIdx.x;   // n*NH + h
    if (idx >= N_NODES * NH) return;
    int hh = idx % NH;
    const float* zp = z + (size_t)idx * D1;
    float s1 = 0.f, s2 = 0.f;
    for (int o = 0; o < D1; ++o) {
        float zv = zp[o];
        s1 += zv * ldin(a2, hh * 2 * D1 + o, f32);
        s2 += zv * ldin(a2, hh * 2 * D1 + D1 + o, f32);
    }
    es[idx] = s1; ed[idx] = s2;
}

// gat_inner edge: p2 only
__global__ void edge2_kernel(const int* __restrict__ src, const int* __restrict__ dst,
                             const float* __restrict__ es, const float* __restrict__ ed,
                             float* __restrict__ p2) {
    int idx = blockIdx.x * 256 + threadIdx.x;   // e*NH + h
    if (idx >= N_EDGES * NH) return;
    int e = idx / NH, hh = idx % NH;
    float x = es[src[e] * NH + hh] + ed[dst[e] * NH + hh];
    x = x > 0.f ? x : 0.2f * x;
    p2[idx] = expf(x);
}

// GATv2 layer0 logits, vectorized (ushort4/lane): p0 only
__global__ __launch_bounds__(256) void edge0_kernel(
        const int* __restrict__ src, const int* __restrict__ dst,
        const __hip_bfloat16* __restrict__ fs, const __hip_bfloat16* __restrict__ fd,
        const void* __restrict__ a0, float* __restrict__ p0,
        const int* __restrict__ dflag) {
    int f32 = *dflag;
    int e = blockIdx.x;
    int lane = threadIdx.x & 63, hh = threadIdx.x >> 6;
    int s = src[e], d = dst[e];
    const unsigned short* fsp = (const unsigned short*)fs + (size_t)s * HD0 + hh * D0;
    const unsigned short* fdp = (const unsigned short*)fd + (size_t)d * HD0 + hh * D0;
    ushort4 a = *(const ushort4*)(fsp + lane * 4);
    ushort4 b = *(const ushort4*)(fdp + lane * 4);
    float acc = 0.f;
#pragma unroll
    for (int i = 0; i < 4; ++i) {
        unsigned short ua = (i == 0) ? a.x : (i == 1) ? a.y : (i == 2) ? a.z : a.w;
        unsigned short ub = (i == 0) ? b.x : (i == 1) ? b.y : (i == 2) ? b.z : b.w;
        float x = bfu2f(ua) + bfu2f(ub);
        x = x > 0.f ? x : 0.2f * x;
        acc += x * ldin(a0, hh * D0 + lane * 4 + i, f32);
    }
    for (int off = 32; off > 0; off >>= 1) acc += __shfl_down(acc, off);
    if (lane == 0) p0[e * NH + hh] = expf(acc);
}

// CSR aggregation, 1024-wide: out0[n] += sum_e alpha * fs[src(e)]
__global__ __launch_bounds__(256) void agg0_csr_kernel(
        const int* __restrict__ rowptr, const int* __restrict__ csr_eid,
        const int* __restrict__ src, const __hip_bfloat16* __restrict__ fs,
        const float* __restrict__ p0, float* __restrict__ out0) {
    int n = blockIdx.x;
    int start = rowptr[n], end = rowptr[n + 1];
    int tid = threadIdx.x;
    __shared__ float invden[NH];
    if (tid < NH) {
        float s = 0.f;
        for (int i = start; i < end; ++i) s += p0[csr_eid[i] * NH + tid];
        invden[tid] = 1.0f / fmaxf(s, 1e-9f);
    }
    __syncthreads();
    float acc0x = 0.f, acc0y = 0.f, acc1x = 0.f, acc1y = 0.f;
    int base0 = 2 * tid;
    int base1 = 512 + 2 * tid;
    int h0 = base0 >> 8, h1 = base1 >> 8;
    const unsigned short* fsu = (const unsigned short*)fs;
    for (int i = start; i < end; ++i) {
        int e = csr_eid[i];
        int s = src[e];
        float a0v = p0[e * NH + h0] * invden[h0];
        float a1v = p0[e * NH + h1] * invden[h1];
        unsigned int u0 = *(const unsigned int*)(fsu + (size_t)s * HD0 + base0);
        unsigned int u1 = *(const unsigned int*)(fsu + (size_t)s * HD0 + base1);
        acc0x += bfu2f((unsigned short)(u0 & 0xFFFF)) * a0v;
        acc0y += bfu2f((unsigned short)(u0 >> 16)) * a0v;
        acc1x += bfu2f((unsigned short)(u1 & 0xFFFF)) * a1v;
        acc1y += bfu2f((unsigned short)(u1 >> 16)) * a1v;
    }
    float2* o0 = (float2*)(out0 + (size_t)n * HD0 + base0);
    float2* o1 = (float2*)(out0 + (size_t)n * HD0 + base1);
    float2 v0 = *o0, v1 = *o1;
    v0.x += acc0x; v0.y += acc0y; v1.x += acc1x; v1.y += acc1y;
    *o0 = v0; *o1 = v1;
}

// CSR aggregation, 32-wide (f32 feat)
__global__ __launch_bounds__(64) void agg32_csr_kernel(
        const int* __restrict__ rowptr, const int* __restrict__ csr_eid,
        const int* __restrict__ src, const float* __restrict__ feat,
        const float* __restrict__ p, float* __restrict__ out) {
    int n = blockIdx.x;
    int start = rowptr[n], end = rowptr[n + 1];
    int lane = threadIdx.x;
    __shared__ float invden[NH];
    if (lane < NH) {
        float s = 0.f;
        for (int i = start; i < end; ++i) s += p[csr_eid[i] * NH + lane];
        invden[lane] = 1.0f / fmaxf(s, 1e-9f);
    }
    __syncthreads();
    if (lane >= HD1) return;
    int hh = lane >> 3;
    float acc = 0.f;
    for (int i = start; i < end; ++i) {
        int e = csr_eid[i];
        acc += feat[(size_t)src[e] * HD1 + lane] * p[e * NH + hh] * invden[hh];
    }
    out[(size_t)n * HD1 + lane] += acc;
}

// relu out0 and emit bf16 copy (into retired fs0b region)
__global__ void relu_bf16_kernel(const float* __restrict__ x,
                                 __hip_bfloat16* __restrict__ xb, int n) {
    int idx = blockIdx.x * 256 + threadIdx.x;
    if (idx < n) xb[idx] = __float2bfloat16(fmaxf(x[idx], 0.f));
}

// layer1 edge: p1 only
__global__ void edge1_kernel(const int* __restrict__ src, const int* __restrict__ dst,
                             const float* __restrict__ fs1, const float* __restrict__ fd1,
                             const void* __restrict__ a1, float* __restrict__ p1,
                             const int* __restrict__ dflag) {
    int f32 = *dflag;
    int idx = blockIdx.x * 256 + threadIdx.x;   // e*NH + h
    if (idx >= N_EDGES * NH) return;
    int e = idx / NH, hh = idx % NH;
    int s = src[e], d = dst[e];
    float acc = 0.f;
    for (int o = 0; o < D1; ++o) {
        float x = fs1[(size_t)s * HD1 + hh * D1 + o] + fd1[(size_t)d * HD1 + hh * D1 + o];
        x = x > 0.f ? x : 0.2f * x;
        acc += x * ldin(a1, hh * D1 + o, f32);
    }
    p1[idx] = expf(acc);
}

__global__ void relu_kernel(float* __restrict__ x, int n) {
    int idx = blockIdx.x * 256 + threadIdx.x;
    if (idx < n) x[idx] = fmaxf(x[idx], 0.f);
}

// final: out[n,o] = [h3 | out1] @ Wlin + blin; dual-dtype store
__global__ void final_kernel(const float* __restrict__ h3, const float* __restrict__ out1,
                             const void* __restrict__ Wlin, const void* __restrict__ blin,
                             void* __restrict__ out, const int* __restrict__ dflag) {
    int f32 = *dflag;
    int idx = blockIdx.x * 256 + threadIdx.x;   // n*OUTF + o
    if (idx >= N_NODES * OUTF) return;
    int n = idx / OUTF, o = idx % OUTF;
    float acc = ldin(blin, o, f32);
    for (int j = 0; j < HD1; ++j)
        acc += h3[(size_t)n * HD1 + j] * ldin(Wlin, j * OUTF + o, f32);
    for (int j = 0; j < HD1; ++j)
        acc += out1[(size_t)n * HD1 + j] * ldin(Wlin, (HD1 + j) * OUTF + o, f32);
    if (f32) ((float*)out)[idx] = acc;
    else     ((__hip_bfloat16*)out)[idx] = __float2bfloat16(acc);
}

// ---------------- launch ----------------
extern "C" void kernel_launch(void* const* d_in, const int* in_sizes, int n_in,
                              void* d_out, int out_size, void* d_ws, size_t ws_size,
                              hipStream_t stream) {
    const void* feats = d_in[0];
    const int*  src   = (const int*)d_in[1];
    const int*  dst   = (const int*)d_in[2];
    const void* tm    = d_in[3];
    const void* am    = d_in[4];
    const void* vm    = d_in[5];
    const void* W2    = d_in[6];
    const void* a2    = d_in[7];
    const void* Wl0   = d_in[8];
    const void* Wr0   = d_in[9];
    const void* a0    = d_in[10];
    const void* Wres0 = d_in[11];
    const void* b0    = d_in[12];
    const void* Wl1   = d_in[13];
    const void* Wr1   = d_in[14];
    const void* a1    = d_in[15];
    const void* Wres1 = d_in[16];
    const void* b1    = d_in[17];
    const void* Wlin  = d_in[18];
    const void* blin  = d_in[19];

    float* ws = (float*)d_ws;
    int*   dflag  = (int*)(ws + OFF_FLAG);
    float* colsum = ws + OFF_COLSUM;
    float* maskm  = ws + OFF_MASKM;
    float* z      = ws + OFF_Z;
    float* es     = ws + OFF_ES;
    float* ed     = ws + OFF_ED;
    float* p2     = ws + OFF_P2;
    float* h3     = ws + OFF_H3;
    float* out0   = ws + OFF_OUT0;
    float* p0     = ws + OFF_P0;
    float* fs1    = ws + OFF_FS1;
    float* fd1    = ws + OFF_FD1;
    float* out1   = ws + OFF_OUT1;
    float* p1     = ws + OFF_P1;
    float* b0f    = ws + OFF_B0F;
    float* b1f    = ws + OFF_B1F;
    int*   deg    = (int*)(ws + OFF_DEG);
    int*   rowptr = (int*)(ws + OFF_ROWPTR);
    int*   cursor = (int*)(ws + OFF_CURSOR);
    int*   csre   = (int*)(ws + OFF_CSRE);
    __hip_bfloat16* fs0b = (__hip_bfloat16*)(ws + OFF_FS0B);
    __hip_bfloat16* fd0b = (__hip_bfloat16*)(ws + OFF_FD0B);
    __hip_bfloat16* abf  = (__hip_bfloat16*)(ws + OFF_ABF);
    __hip_bfloat16* bt   = (__hip_bfloat16*)(ws + OFF_BT);
    __hip_bfloat16* bt1  = (__hip_bfloat16*)(ws + OFF_BT1);
    __hip_bfloat16* out0b = fs0b;   // fs0b retired after agg0; reuse

    // zero accumulators (ws poisoned 0xAA before every call)
    (void)hipMemsetAsync(dflag, 0, sizeof(int), stream);
    (void)hipMemsetAsync(colsum, 0, 1280 * sizeof(float), stream);
    (void)hipMemsetAsync(h3, 0, N_NODES * HD1 * sizeof(float), stream);
    (void)hipMemsetAsync(deg, 0, N_NODES * sizeof(int), stream);

    // dtype detection (subset scan)
    detect_kernel<<<64, 256, 0, stream>>>((const unsigned short*)feats, 131072, dflag);

    // CSR build
    deg_kernel<<<(N_EDGES + 255) / 256, 256, 0, stream>>>(dst, deg);
    scan_kernel<<<1, 256, 0, stream>>>(deg, rowptr, cursor);
    scatter_kernel<<<(N_EDGES + 255) / 256, 256, 0, stream>>>(dst, cursor, csre);

    // preprocess
    colsum_kernel<<<dim3(5, 40), 256, 0, stream>>>(feats, colsum, dflag);
    maskprep_kernel<<<5, 256, 0, stream>>>(tm, am, vm, maskm, dflag);
    biasprep_kernel<<<4, 256, 0, stream>>>(b0, b1, b0f, b1f, dflag);
    prep_row_kernel<<<N_NODES, 256, 0, stream>>>(feats, colsum, maskm, abf, dflag);
    bt_kernel<<<(KPAD * NBIG2 + 255) / 256, 256, 0, stream>>>(Wl0, Wr0, Wres0, W2, bt, dflag);
    bt1_kernel<<<(HD0 * 96 + 255) / 256, 256, 0, stream>>>(Wl1, Wr1, Wres1, bt1, dflag);

    // big fused projection GEMM (Wl0 | Wr0 | Wres0 | W2-z)
    mfma_gemm<<<dim3(NBIG2 / 128, MPAD / 128), 256, 0, stream>>>(
        (const unsigned short*)abf, (const unsigned short*)bt, b0f, fs0b, fd0b, out0, z);

    // gat_inner (h3)
    esed_kernel<<<(N_NODES * NH + 255) / 256, 256, 0, stream>>>(z, a2, es, ed, dflag);
    edge2_kernel<<<(N_EDGES * NH + 255) / 256, 256, 0, stream>>>(src, dst, es, ed, p2);
    agg32_csr_kernel<<<N_NODES, 64, 0, stream>>>(rowptr, csre, src, z, p2, h3);

    // GATv2 layer 0
    edge0_kernel<<<N_EDGES, 256, 0, stream>>>(src, dst, fs0b, fd0b, a0, p0, dflag);
    agg0_csr_kernel<<<N_NODES, 256, 0, stream>>>(rowptr, csre, src, fs0b, p0, out0);
    relu_bf16_kernel<<<(N_NODES * HD0 + 255) / 256, 256, 0, stream>>>(out0, out0b,
                                                                      N_NODES * HD0);

    // GATv2 layer 1
    mfma_gemm96<<<(N_NODES + 63) / 64, 256, 0, stream>>>(
        (const unsigned short*)out0b, (const unsigned short*)bt1, b1f, fs1, fd1, out1);
    edge1_kernel<<<(N_EDGES * NH + 255) / 256, 256, 0, stream>>>(src, dst, fs1, fd1, a1,
                                                                 p1, dflag);
    agg32_csr_kernel<<<N_NODES, 64, 0, stream>>>(rowptr, csre, src, fs1, p1, out1);
    relu_kernel<<<(N_NODES * HD1 + 255) / 256, 256, 0, stream>>>(out1, N_NODES * HD1);

    // final linear
    final_kernel<<<(N_NODES * OUTF + 255) / 256, 256, 0, stream>>>(h3, out1, Wlin, blin,
                                                                   d_out, dflag);
}

// Round 9
// 685.860 us; speedup vs baseline: 6.0283x; 1.1057x over previous
//
#include <hip/hip_runtime.h>
#include <hip/hip_bf16.h>

// Problem constants
#define N_NODES 10000
#define N_EDGES 64000
#define IN_F    1247
#define KPAD    1280   // IN_F padded to mult of 32
#define NH      4
#define D0      256
#define D1      8
#define HD0     1024   // NH*D0
#define HD1     32     // NH*D1
#define NBIG    3072   // Wl0 | Wr0 | Wres0
#define NBIG2   3200   // + 32 z cols (from W2) + 96 pad
#define OUTF    6
#define INV_N   (1.0f / 10000.0f)
#define MPAD    10240  // N_NODES padded to 80 row-tiles (XCD swizzle: 80 = 8 XCD * 10)

typedef __attribute__((ext_vector_type(8))) short bf16x8;
typedef __attribute__((ext_vector_type(4))) float f32x4;
typedef unsigned int u32;

// async 16B global -> LDS (DMA). LDS dest: wave-uniform base + lane*16.
__device__ __forceinline__ void async_copy16(const unsigned short* gsrc,
                                             unsigned short* ldst) {
    __builtin_amdgcn_global_load_lds(
        (const __attribute__((address_space(1))) u32*)(gsrc),
        (__attribute__((address_space(3))) u32*)(ldst), 16, 0, 0);
}

// ---------------- workspace layout (float-slot offsets), ~126.6 MB ----------------
constexpr size_t OFF_FLAG   = 0;                          // 16
constexpr size_t OFF_COLSUM = 16;                         // 1280
constexpr size_t OFF_MASKM  = 1296;                       // 1280
constexpr size_t OFF_Z      = 2576;                       // N*32
constexpr size_t OFF_ES     = OFF_Z    + 320000;          // N*4
constexpr size_t OFF_ED     = OFF_ES   + 40000;           // N*4
constexpr size_t OFF_P2     = OFF_ED   + 40000;           // E*4
constexpr size_t OFF_H3     = OFF_P2   + 256000;          // N*32
constexpr size_t OFF_OUT0   = OFF_H3   + 320000;          // N*1024 f32 (res+bias)
constexpr size_t OFF_FS1    = OFF_OUT0 + 10240000;        // N*32
constexpr size_t OFF_FD1    = OFF_FS1  + 320000;          // N*32
constexpr size_t OFF_OUT1   = OFF_FD1  + 320000;          // N*32
constexpr size_t OFF_P1     = OFF_OUT1 + 320000;          // E*4
constexpr size_t OFF_B0F    = OFF_P1   + 256000;          // 1024
constexpr size_t OFF_B1F    = OFF_B0F  + 1024;            // 64
constexpr size_t OFF_DEG    = OFF_B1F  + 64;              // int 10016
constexpr size_t OFF_ROWPTR = OFF_DEG  + 10016;           // int 10016
constexpr size_t OFF_CURSOR = OFF_ROWPTR + 10016;         // int 10016
constexpr size_t OFF_CSRE   = OFF_CURSOR + 10016;         // int 64000
constexpr size_t OFF_FS0B   = OFF_CSRE + 64000;           // bf16 N*1024
constexpr size_t OFF_FD0B   = OFF_FS0B + 5120000;         // bf16 N*1024 (reused as out0b)
constexpr size_t OFF_ABF    = OFF_FD0B + 5120000;         // bf16 MPAD*KPAD -> 6,553,600 slots
constexpr size_t OFF_BT     = OFF_ABF  + 6553600;         // bf16 NBIG2*KPAD
constexpr size_t OFF_BT1    = OFF_BT   + 2048000;         // bf16 96*1024
constexpr size_t WS_FLOATS  = OFF_BT1  + 49152;

// dual-dtype load: is_f32 ? float : bf16
__device__ __forceinline__ float ldin(const void* p, size_t i, int f32) {
    return f32 ? ((const float*)p)[i]
               : __bfloat162float(((const __hip_bfloat16*)p)[i]);
}
__device__ __forceinline__ float bfu2f(unsigned short u) {
    union { unsigned int i; float f; } x;
    x.i = ((unsigned int)u) << 16;
    return x.f;
}
__device__ __forceinline__ unsigned short f2bu(float v) {
    __hip_bfloat16 h = __float2bfloat16(v);
    unsigned short u;
    __builtin_memcpy(&u, &h, 2);
    return u;
}

// ---------------- kernels ----------------

// dtype detection on first 131072 words
__global__ void detect_kernel(const unsigned short* __restrict__ w, int n,
                              int* __restrict__ flag) {
    int i = blockIdx.x * 256 + threadIdx.x;
    int stride = gridDim.x * 256;
    int found = 0;
    for (; i < n; i += stride) {
        if (((w[i] >> 7) & 0xFF) == 0xFF) found = 1;
    }
    if (found) atomicOr(flag, 1);
}

// column sums of features. grid (5,40), block 256
__global__ void colsum_kernel(const void* __restrict__ feats,
                              float* __restrict__ colsum, const int* __restrict__ dflag) {
    int f32 = *dflag;
    int c = blockIdx.x * blockDim.x + threadIdx.x;
    if (c >= IN_F) return;
    int r0 = blockIdx.y * 250;
    float s = 0.f;
    for (int r = r0; r < r0 + 250; ++r)
        s += ldin(feats, (size_t)r * IN_F + c, f32);
    atomicAdd(&colsum[c], s);
}

__global__ void maskprep_kernel(const void* __restrict__ tm, const void* __restrict__ am,
                                const void* __restrict__ vm, float* __restrict__ maskmul,
                                const int* __restrict__ dflag) {
    int f32 = *dflag;
    int c = blockIdx.x * 256 + threadIdx.x;
    if (c >= IN_F) return;
    maskmul[c] = ldin(tm, c, f32) + ldin(am, c, f32) + ldin(vm, c, f32);
}

__global__ void biasprep_kernel(const void* __restrict__ b0, const void* __restrict__ b1,
                                float* __restrict__ b0f, float* __restrict__ b1f,
                                const int* __restrict__ dflag) {
    int f32 = *dflag;
    int c = blockIdx.x * 256 + threadIdx.x;
    if (c < HD0) b0f[c] = ldin(b0, c, f32);
    if (c < HD1) b1f[c] = ldin(b1, c, f32);
}

// fused single-pass: impute row into LDS, L1-scale, mask, emit bf16 A row
__global__ __launch_bounds__(256) void prep_row_kernel(
        const void* __restrict__ feats, const float* __restrict__ colsum,
        const float* __restrict__ maskmul, __hip_bfloat16* __restrict__ abf,
        const int* __restrict__ dflag) {
    int f32 = *dflag;
    int n = blockIdx.x;
    __shared__ float rowbuf[IN_F];
    __shared__ float red[256];
    float s = 0.f;
    for (int c = threadIdx.x; c < IN_F; c += 256) {
        float f = ldin(feats, (size_t)n * IN_F + c, f32);
        float v = (f != 0.0f) ? f : 0.5f * colsum[c] * INV_N;   // 0.5*(h+h1)
        rowbuf[c] = v;
        s += fabsf(v);
    }
    red[threadIdx.x] = s;
    __syncthreads();
    for (int st = 128; st > 0; st >>= 1) {
        if (threadIdx.x < st) red[threadIdx.x] += red[threadIdx.x + st];
        __syncthreads();
    }
    float scale = 1.0f / fmaxf(red[0], 1e-12f);
    for (int k = threadIdx.x; k < KPAD; k += 256) {
        float v = (k < IN_F) ? rowbuf[k] * scale * maskmul[k] : 0.f;
        abf[(size_t)n * KPAD + k] = __float2bfloat16(v);
    }
}

// zero-fill abf pad rows (deterministic; avoids NaN poison through MFMA)
__global__ void abf_pad_kernel(__hip_bfloat16* __restrict__ abf) {
    int idx = blockIdx.x * 256 + threadIdx.x;   // (MPAD-N_NODES)*KPAD els
    if (idx >= (MPAD - N_NODES) * KPAD) return;
    abf[(size_t)N_NODES * KPAD + idx] = __float2bfloat16(0.f);
}

// fused transposed B [NBIG2][KPAD]
__global__ void bt_kernel(const void* __restrict__ Wl0, const void* __restrict__ Wr0,
                          const void* __restrict__ Wres0, const void* __restrict__ W2,
                          __hip_bfloat16* __restrict__ bt, const int* __restrict__ dflag) {
    int f32 = *dflag;
    int idx = blockIdx.x * 256 + threadIdx.x;   // k*NBIG2 + n
    if (idx >= KPAD * NBIG2) return;
    int k = idx / NBIG2, n = idx % NBIG2;
    float v = 0.f;
    if (k < IN_F) {
        if (n < NBIG) {
            int seg = n >> 10, col = n & 1023;
            const void* W = (seg == 0) ? Wl0 : (seg == 1) ? Wr0 : Wres0;
            v = ldin(W, (size_t)k * HD0 + col, f32);
        } else if (n < NBIG + HD1) {
            int col = n - NBIG;                 // h*8+o
            int hh = col >> 3, o = col & 7;
            v = ldin(W2, ((size_t)hh * IN_F + k) * D1 + o, f32);
        }
    }
    bt[(size_t)n * KPAD + k] = __float2bfloat16(v);
}

// transposed layer-1 B [96][1024]
__global__ void bt1_kernel(const void* __restrict__ Wl1, const void* __restrict__ Wr1,
                           const void* __restrict__ Wres1, __hip_bfloat16* __restrict__ bt1,
                           const int* __restrict__ dflag) {
    int f32 = *dflag;
    int idx = blockIdx.x * 256 + threadIdx.x;   // k*96 + n
    if (idx >= HD0 * 96) return;
    int k = idx / 96, n = idx % 96;
    int seg = n >> 5, col = n & 31;
    const void* W = (seg == 0) ? Wl1 : (seg == 1) ? Wr1 : Wres1;
    bt1[(size_t)n * HD0 + k] = __float2bfloat16(ldin(W, (size_t)k * HD1 + col, f32));
}

// ---- CSR build ----
__global__ void deg_kernel(const int* __restrict__ dst, int* __restrict__ deg) {
    int e = blockIdx.x * 256 + threadIdx.x;
    if (e < N_EDGES) atomicAdd(&deg[dst[e]], 1);
}

__global__ __launch_bounds__(256) void scan_kernel(const int* __restrict__ deg,
                                                   int* __restrict__ rowptr,
                                                   int* __restrict__ cursor) {
    __shared__ int sums[256];
    __shared__ int offs[257];
    int t = threadIdx.x;
    int base = t * 40;
    int s = 0;
    for (int i = 0; i < 40; ++i) {
        int idx = base + i;
        if (idx < N_NODES) s += deg[idx];
    }
    sums[t] = s;
    __syncthreads();
    if (t == 0) {
        int run = 0;
        for (int i = 0; i < 256; ++i) { offs[i] = run; run += sums[i]; }
        offs[256] = run;
    }
    __syncthreads();
    int run = offs[t];
    for (int i = 0; i < 40; ++i) {
        int idx = base + i;
        if (idx < N_NODES) {
            rowptr[idx] = run; cursor[idx] = run;
            run += deg[idx];
        }
    }
    if (t == 255) rowptr[N_NODES] = offs[256];
}

__global__ void scatter_kernel(const int* __restrict__ dst, int* __restrict__ cursor,
                               int* __restrict__ csr_eid) {
    int e = blockIdx.x * 256 + threadIdx.x;
    if (e >= N_EDGES) return;
    int pos = atomicAdd(&cursor[dst[e]], 1);
    csr_eid[pos] = e;
}

// MFMA GEMM: C[MPAD x 3200] = abf @ bt^T, DMA staging, fragment-major LDS,
// XCD-aware swizzle: flat grid 2000 = 8 XCD * (25 cols x 10 rows). Each XCD owns
// a 10-row-tile A stripe (3.3MB, L2-resident) and walks columns outer.
__global__ __launch_bounds__(256) void mfma_gemm(
        const unsigned short* __restrict__ A, const unsigned short* __restrict__ BT,
        const float* __restrict__ b0f, __hip_bfloat16* __restrict__ fs0b,
        __hip_bfloat16* __restrict__ fd0b, float* __restrict__ out0,
        float* __restrict__ z) {
    __shared__ unsigned short As[128 * 32];   // 8KB, fragment-major chunks
    __shared__ unsigned short Bs[128 * 32];   // 8KB
    const int g = blockIdx.x;
    const int xcd = g & 7, l = g >> 3;
    const int colb = l / 10, rowl = l - colb * 10;
    const int bm = (xcd * 10 + rowl) * 128;
    const int bn = colb * 128;
    const int tid = threadIdx.x;
    const int wave = tid >> 6, lane = tid & 63;
    const int quad = lane >> 4, l16 = lane & 15;
    const int wm = (wave & 1) * 64, wn = (wave >> 1) * 64;
    const int srow = lane & 15;
    const int skc  = (lane >> 4) * 8;

    f32x4 acc[4][4];
#pragma unroll
    for (int i = 0; i < 4; ++i)
#pragma unroll
        for (int j = 0; j < 4; ++j) acc[i][j] = (f32x4){0.f, 0.f, 0.f, 0.f};

    for (int k0 = 0; k0 < KPAD; k0 += 32) {
#pragma unroll
        for (int t = 0; t < 2; ++t) {
            int f = t * 4 + wave;
            async_copy16(A + (size_t)(bm + f * 16 + srow) * KPAD + k0 + skc,
                         As + f * 512);
            async_copy16(BT + (size_t)(bn + f * 16 + srow) * KPAD + k0 + skc,
                         Bs + f * 512);
        }
        __syncthreads();
        bf16x8 af[4], bfr[4];
#pragma unroll
        for (int i = 0; i < 4; ++i)
            af[i] = *(const bf16x8*)(As + ((wave & 1) * 4 + i) * 512 + lane * 8);
#pragma unroll
        for (int j = 0; j < 4; ++j)
            bfr[j] = *(const bf16x8*)(Bs + ((wave >> 1) * 4 + j) * 512 + lane * 8);
#pragma unroll
        for (int i = 0; i < 4; ++i)
#pragma unroll
            for (int j = 0; j < 4; ++j)
                acc[i][j] = __builtin_amdgcn_mfma_f32_16x16x32_bf16(
                    af[i], bfr[j], acc[i][j], 0, 0, 0);
        __syncthreads();
    }

    const int seg = bn >> 10;
#pragma unroll
    for (int i = 0; i < 4; ++i) {
#pragma unroll
        for (int r = 0; r < 4; ++r) {
            int gm = bm + wm + i * 16 + quad * 4 + r;
            if (gm >= N_NODES) continue;
#pragma unroll
            for (int j = 0; j < 4; ++j) {
                int gnl = (bn & 1023) + wn + j * 16 + l16;
                float v = acc[i][j][r];
                if (seg == 0)      fs0b[(size_t)gm * HD0 + gnl] = __float2bfloat16(v);
                else if (seg == 1) fd0b[(size_t)gm * HD0 + gnl] = __float2bfloat16(v);
                else if (seg == 2) out0[(size_t)gm * HD0 + gnl] = v + b0f[gnl];
                else if (gnl < HD1) z[(size_t)gm * HD1 + gnl] = v;
            }
        }
    }
}

// fused layer-0 attention: per node — logits (2 passes, alpha recomputed),
// aggregation, +res(out0 f32), relu, bf16 store into out0b (fd0b region).
__global__ __launch_bounds__(256) void att0_kernel(
        const int* __restrict__ rowptr, const int* __restrict__ csre,
        const int* __restrict__ src, const __hip_bfloat16* __restrict__ fs,
        const __hip_bfloat16* __restrict__ fd, const void* __restrict__ a0,
        const float* __restrict__ out0res, __hip_bfloat16* __restrict__ out0b,
        const int* __restrict__ dflag) {
    int f32 = *dflag;
    int n = blockIdx.x;
    int t = threadIdx.x, wave = t >> 6, lane = t & 63;
    __shared__ float sfd[HD0];
    __shared__ float sa0[HD0];
    __shared__ float sinv[NH];
    {
        const unsigned short* fdp = (const unsigned short*)fd + (size_t)n * HD0;
        ushort4 u = *(const ushort4*)(fdp + 4 * t);
        sfd[4 * t + 0] = bfu2f(u.x); sfd[4 * t + 1] = bfu2f(u.y);
        sfd[4 * t + 2] = bfu2f(u.z); sfd[4 * t + 3] = bfu2f(u.w);
#pragma unroll
        for (int i = 0; i < 4; ++i) sa0[4 * t + i] = ldin(a0, 4 * t + i, f32);
    }
    __syncthreads();
    int start = rowptr[n], end = rowptr[n + 1];
    const unsigned short* fsu = (const unsigned short*)fs;
    // pass 1: denominators (wave = head)
    float den = 0.f;
    for (int i = start; i < end; ++i) {
        int s = src[csre[i]];
        ushort4 u = *(const ushort4*)(fsu + (size_t)s * HD0 + 4 * t);
        float part = 0.f;
#pragma unroll
        for (int j = 0; j < 4; ++j) {
            unsigned short uj = (j == 0) ? u.x : (j == 1) ? u.y : (j == 2) ? u.z : u.w;
            float x = bfu2f(uj) + sfd[4 * t + j];
            x = x > 0.f ? x : 0.2f * x;
            part += x * sa0[4 * t + j];
        }
        for (int off = 32; off > 0; off >>= 1) part += __shfl_xor(part, off);
        den += expf(part);
    }
    if (lane == 0) sinv[wave] = 1.0f / fmaxf(den, 1e-9f);
    __syncthreads();
    float inv = sinv[wave];
    // pass 2: recompute alpha, aggregate
    float acc[4] = {0.f, 0.f, 0.f, 0.f};
    for (int i = start; i < end; ++i) {
        int s = src[csre[i]];
        ushort4 u = *(const ushort4*)(fsu + (size_t)s * HD0 + 4 * t);
        float fv[4], part = 0.f;
#pragma unroll
        for (int j = 0; j < 4; ++j) {
            unsigned short uj = (j == 0) ? u.x : (j == 1) ? u.y : (j == 2) ? u.z : u.w;
            fv[j] = bfu2f(uj);
            float x = fv[j] + sfd[4 * t + j];
            x = x > 0.f ? x : 0.2f * x;
            part += x * sa0[4 * t + j];
        }
        for (int off = 32; off > 0; off >>= 1) part += __shfl_xor(part, off);
        float alpha = expf(part) * inv;
#pragma unroll
        for (int j = 0; j < 4; ++j) acc[j] += fv[j] * alpha;
    }
    float4 base = *(const float4*)(out0res + (size_t)n * HD0 + 4 * t);
    ushort4 o;
    o.x = f2bu(fmaxf(base.x + acc[0], 0.f));
    o.y = f2bu(fmaxf(base.y + acc[1], 0.f));
    o.z = f2bu(fmaxf(base.z + acc[2], 0.f));
    o.w = f2bu(fmaxf(base.w + acc[3], 0.f));
    *(ushort4*)((unsigned short*)out0b + (size_t)n * HD0 + 4 * t) = o;
}

// layer-1 fused MFMA GEMM: C[10000 x 96] = out0b @ bt1^T, K=1024, 64-row tiles
__global__ __launch_bounds__(256) void mfma_gemm96(
        const unsigned short* __restrict__ A, const unsigned short* __restrict__ BT1,
        const float* __restrict__ b1f, float* __restrict__ fs1,
        float* __restrict__ fd1, float* __restrict__ out1) {
    __shared__ unsigned short As[64 * 32];
    __shared__ unsigned short Bs[96 * 32];
    const int tid = threadIdx.x;
    const int wave = tid >> 6, lane = tid & 63;
    const int quad = lane >> 4, l16 = lane & 15;
    const int bm = blockIdx.x * 64;
    const int srow = lane & 15;
    const int skc  = (lane >> 4) * 8;

    f32x4 acc[6];
#pragma unroll
    for (int j = 0; j < 6; ++j) acc[j] = (f32x4){0.f, 0.f, 0.f, 0.f};

    for (int k0 = 0; k0 < HD0; k0 += 32) {
        async_copy16(A + (size_t)(bm + wave * 16 + srow) * HD0 + k0 + skc,
                     As + wave * 512);
        async_copy16(BT1 + (size_t)(wave * 16 + srow) * HD0 + k0 + skc,
                     Bs + wave * 512);
        if (wave < 2) {
            int f = 4 + wave;
            async_copy16(BT1 + (size_t)(f * 16 + srow) * HD0 + k0 + skc,
                         Bs + f * 512);
        }
        __syncthreads();
        bf16x8 af = *(const bf16x8*)(As + wave * 512 + lane * 8);
#pragma unroll
        for (int j = 0; j < 6; ++j) {
            bf16x8 bfr = *(const bf16x8*)(Bs + j * 512 + lane * 8);
            acc[j] = __builtin_amdgcn_mfma_f32_16x16x32_bf16(af, bfr, acc[j], 0, 0, 0);
        }
        __syncthreads();
    }

#pragma unroll
    for (int r = 0; r < 4; ++r) {
        int gm = bm + wave * 16 + quad * 4 + r;
        if (gm >= N_NODES) continue;
#pragma unroll
        for (int j = 0; j < 6; ++j) {
            int col = j * 16 + l16;
            int seg = col >> 5, cl = col & 31;
            float v = acc[j][r];
            if (seg == 0)      fs1[(size_t)gm * HD1 + cl] = v;
            else if (seg == 1) fd1[(size_t)gm * HD1 + cl] = v;
            else               out1[(size_t)gm * HD1 + cl] = v + b1f[cl];
        }
    }
}

// es/ed for gat_inner
__global__ void esed_kernel(const float* __restrict__ z, const void* __restrict__ a2,
                            float* __restrict__ es, float* __restrict__ ed,
                            const int* __restrict__ dflag) {
    int f32 = *dflag;
    int idx = blockIdx.x * 256 + threadIdx.x;   // n*NH + h
    if (idx >= N_NODES * NH) return;
    int hh = idx % NH;
    const float* zp = z + (size_t)idx * D1;
    float s1 = 0.f, s2 = 0.f;
    for (int o = 0; o < D1; ++o) {
        float zv = zp[o];
        s1 += zv * ldin(a2, hh * 2 * D1 + o, f32);
        s2 += zv * ldin(a2, hh * 2 * D1 + D1 + o, f32);
    }
    es[idx] = s1; ed[idx] = s2;
}

// gat_inner edge: p2 only
__global__ void edge2_kernel(const int* __restrict__ src, const int* __restrict__ dst,
                             const float* __restrict__ es, const float* __restrict__ ed,
                             float* __restrict__ p2) {
    int idx = blockIdx.x * 256 + threadIdx.x;   // e*NH + h
    if (idx >= N_EDGES * NH) return;
    int e = idx / NH, hh = idx % NH;
    float x = es[src[e] * NH + hh] + ed[dst[e] * NH + hh];
    x = x > 0.f ? x : 0.2f * x;
    p2[idx] = expf(x);
}

// CSR aggregation, 32-wide (f32 feat)
__global__ __launch_bounds__(64) void agg32_csr_kernel(
        const int* __restrict__ rowptr, const int* __restrict__ csr_eid,
        const int* __restrict__ src, const float* __restrict__ feat,
        const float* __restrict__ p, float* __restrict__ out) {
    int n = blockIdx.x;
    int start = rowptr[n], end = rowptr[n + 1];
    int lane = threadIdx.x;
    __shared__ float invden[NH];
    if (lane < NH) {
        float s = 0.f;
        for (int i = start; i < end; ++i) s += p[csr_eid[i] * NH + lane];
        invden[lane] = 1.0f / fmaxf(s, 1e-9f);
    }
    __syncthreads();
    if (lane >= HD1) return;
    int hh = lane >> 3;
    float acc = 0.f;
    for (int i = start; i < end; ++i) {
        int e = csr_eid[i];
        acc += feat[(size_t)src[e] * HD1 + lane] * p[e * NH + hh] * invden[hh];
    }
    out[(size_t)n * HD1 + lane] += acc;
}

// layer1 edge: p1 only
__global__ void edge1_kernel(const int* __restrict__ src, const int* __restrict__ dst,
                             const float* __restrict__ fs1, const float* __restrict__ fd1,
                             const void* __restrict__ a1, float* __restrict__ p1,
                             const int* __restrict__ dflag) {
    int f32 = *dflag;
    int idx = blockIdx.x * 256 + threadIdx.x;   // e*NH + h
    if (idx >= N_EDGES * NH) return;
    int e = idx / NH, hh = idx % NH;
    int s = src[e], d = dst[e];
    float acc = 0.f;
    for (int o = 0; o < D1; ++o) {
        float x = fs1[(size_t)s * HD1 + hh * D1 + o] + fd1[(size_t)d * HD1 + hh * D1 + o];
        x = x > 0.f ? x : 0.2f * x;
        acc += x * ldin(a1, hh * D1 + o, f32);
    }
    p1[idx] = expf(acc);
}

// final: out[n,o] = [h3 | relu(out1)] @ Wlin + blin; dual-dtype store
__global__ void final_kernel(const float* __restrict__ h3, const float* __restrict__ out1,
                             const void* __restrict__ Wlin, const void* __restrict__ blin,
                             void* __restrict__ out, const int* __restrict__ dflag) {
    int f32 = *dflag;
    int idx = blockIdx.x * 256 + threadIdx.x;   // n*OUTF + o
    if (idx >= N_NODES * OUTF) return;
    int n = idx / OUTF, o = idx % OUTF;
    float acc = ldin(blin, o, f32);
    for (int j = 0; j < HD1; ++j)
        acc += h3[(size_t)n * HD1 + j] * ldin(Wlin, j * OUTF + o, f32);
    for (int j = 0; j < HD1; ++j)
        acc += fmaxf(out1[(size_t)n * HD1 + j], 0.f) * ldin(Wlin, (HD1 + j) * OUTF + o, f32);
    if (f32) ((float*)out)[idx] = acc;
    else     ((__hip_bfloat16*)out)[idx] = __float2bfloat16(acc);
}

// ---------------- launch ----------------
extern "C" void kernel_launch(void* const* d_in, const int* in_sizes, int n_in,
                              void* d_out, int out_size, void* d_ws, size_t ws_size,
                              hipStream_t stream) {
    const void* feats = d_in[0];
    const int*  src   = (const int*)d_in[1];
    const int*  dst   = (const int*)d_in[2];
    const void* tm    = d_in[3];
    const void* am    = d_in[4];
    const void* vm    = d_in[5];
    const void* W2    = d_in[6];
    const void* a2    = d_in[7];
    const void* Wl0   = d_in[8];
    const void* Wr0   = d_in[9];
    const void* a0    = d_in[10];
    const void* Wres0 = d_in[11];
    const void* b0    = d_in[12];
    const void* Wl1   = d_in[13];
    const void* Wr1   = d_in[14];
    const void* a1    = d_in[15];
    const void* Wres1 = d_in[16];
    const void* b1    = d_in[17];
    const void* Wlin  = d_in[18];
    const void* blin  = d_in[19];

    float* ws = (float*)d_ws;
    int*   dflag  = (int*)(ws + OFF_FLAG);
    float* colsum = ws + OFF_COLSUM;
    float* maskm  = ws + OFF_MASKM;
    float* z      = ws + OFF_Z;
    float* es     = ws + OFF_ES;
    float* ed     = ws + OFF_ED;
    float* p2     = ws + OFF_P2;
    float* h3     = ws + OFF_H3;
    float* out0   = ws + OFF_OUT0;
    float* fs1    = ws + OFF_FS1;
    float* fd1    = ws + OFF_FD1;
    float* out1   = ws + OFF_OUT1;
    float* p1     = ws + OFF_P1;
    float* b0f    = ws + OFF_B0F;
    float* b1f    = ws + OFF_B1F;
    int*   deg    = (int*)(ws + OFF_DEG);
    int*   rowptr = (int*)(ws + OFF_ROWPTR);
    int*   cursor = (int*)(ws + OFF_CURSOR);
    int*   csre   = (int*)(ws + OFF_CSRE);
    __hip_bfloat16* fs0b = (__hip_bfloat16*)(ws + OFF_FS0B);
    __hip_bfloat16* fd0b = (__hip_bfloat16*)(ws + OFF_FD0B);
    __hip_bfloat16* abf  = (__hip_bfloat16*)(ws + OFF_ABF);
    __hip_bfloat16* bt   = (__hip_bfloat16*)(ws + OFF_BT);
    __hip_bfloat16* bt1  = (__hip_bfloat16*)(ws + OFF_BT1);
    __hip_bfloat16* out0b = fd0b;   // fd0b row n retired after att0 block n reads it

    // zero accumulators (ws poisoned 0xAA before every call)
    (void)hipMemsetAsync(dflag, 0, sizeof(int), stream);
    (void)hipMemsetAsync(colsum, 0, 1280 * sizeof(float), stream);
    (void)hipMemsetAsync(h3, 0, N_NODES * HD1 * sizeof(float), stream);
    (void)hipMemsetAsync(deg, 0, N_NODES * sizeof(int), stream);

    // dtype detection (subset scan)
    detect_kernel<<<64, 256, 0, stream>>>((const unsigned short*)feats, 131072, dflag);

    // CSR build
    deg_kernel<<<(N_EDGES + 255) / 256, 256, 0, stream>>>(dst, deg);
    scan_kernel<<<1, 256, 0, stream>>>(deg, rowptr, cursor);
    scatter_kernel<<<(N_EDGES + 255) / 256, 256, 0, stream>>>(dst, cursor, csre);

    // preprocess
    colsum_kernel<<<dim3(5, 40), 256, 0, stream>>>(feats, colsum, dflag);
    maskprep_kernel<<<5, 256, 0, stream>>>(tm, am, vm, maskm, dflag);
    biasprep_kernel<<<4, 256, 0, stream>>>(b0, b1, b0f, b1f, dflag);
    prep_row_kernel<<<N_NODES, 256, 0, stream>>>(feats, colsum, maskm, abf, dflag);
    abf_pad_kernel<<<((MPAD - N_NODES) * KPAD + 255) / 256, 256, 0, stream>>>(abf);
    bt_kernel<<<(KPAD * NBIG2 + 255) / 256, 256, 0, stream>>>(Wl0, Wr0, Wres0, W2, bt, dflag);
    bt1_kernel<<<(HD0 * 96 + 255) / 256, 256, 0, stream>>>(Wl1, Wr1, Wres1, bt1, dflag);

    // big fused projection GEMM (Wl0 | Wr0 | Wres0 | W2-z), XCD-swizzled flat grid
    mfma_gemm<<<2000, 256, 0, stream>>>(
        (const unsigned short*)abf, (const unsigned short*)bt, b0f, fs0b, fd0b, out0, z);

    // gat_inner (h3)
    esed_kernel<<<(N_NODES * NH + 255) / 256, 256, 0, stream>>>(z, a2, es, ed, dflag);
    edge2_kernel<<<(N_EDGES * NH + 255) / 256, 256, 0, stream>>>(src, dst, es, ed, p2);
    agg32_csr_kernel<<<N_NODES, 64, 0, stream>>>(rowptr, csre, src, z, p2, h3);

    // GATv2 layer 0: fused attention (logits + softmax + aggregate + res + relu + bf16)
    att0_kernel<<<N_NODES, 256, 0, stream>>>(rowptr, csre, src, fs0b, fd0b, a0,
                                             out0, out0b, dflag);

    // GATv2 layer 1
    mfma_gemm96<<<(N_NODES + 63) / 64, 256, 0, stream>>>(
        (const unsigned short*)out0b, (const unsigned short*)bt1, b1f, fs1, fd1, out1);
    edge1_kernel<<<(N_EDGES * NH + 255) / 256, 256, 0, stream>>>(src, dst, fs1, fd1, a1,
                                                                 p1, dflag);
    agg32_csr_kernel<<<N_NODES, 64, 0, stream>>>(rowptr, csre, src, fs1, p1, out1);

    // final linear (relu(out1) folded in)
    final_kernel<<<(N_NODES * OUTF + 255) / 256, 256, 0, stream>>>(h3, out1, Wlin, blin,
                                                                   d_out, dflag);
}

// Round 10
// 622.797 us; speedup vs baseline: 6.6387x; 1.1013x over previous
//
#include <hip/hip_runtime.h>
#include <hip/hip_bf16.h>

// Problem constants
#define N_NODES 10000
#define N_EDGES 64000
#define IN_F    1247
#define KPAD    1280   // IN_F padded to mult of 32
#define NH      4
#define D0      256
#define D1      8
#define HD0     1024   // NH*D0
#define HD1     32     // NH*D1
#define NBIG    3072   // Wl0 | Wr0 | Wres0
#define NBIG2   3200   // + 32 z cols (from W2) + 96 pad
#define OUTF    6
#define INV_N   (1.0f / 10000.0f)
#define MPAD    10240  // 80 row-tiles (XCD swizzle: 80 = 8 XCD * 10)

typedef __attribute__((ext_vector_type(8))) short bf16x8;
typedef __attribute__((ext_vector_type(4))) float f32x4;
typedef unsigned int u32;

// async 16B global -> LDS (DMA). LDS dest: wave-uniform base + lane*16.
__device__ __forceinline__ void async_copy16(const unsigned short* gsrc,
                                             unsigned short* ldst) {
    __builtin_amdgcn_global_load_lds(
        (const __attribute__((address_space(1))) u32*)(gsrc),
        (__attribute__((address_space(3))) u32*)(ldst), 16, 0, 0);
}

// ---------------- workspace layout (float-slot offsets), ~123.6 MB ----------------
constexpr size_t OFF_FLAG   = 0;                          // 16
constexpr size_t OFF_COLSUM = 16;                         // 1280
constexpr size_t OFF_MASKM  = 1296;                       // 1280
constexpr size_t OFF_Z      = 2576;                       // N*32
constexpr size_t OFF_ES     = OFF_Z    + 320000;          // N*4
constexpr size_t OFF_ED     = OFF_ES   + 40000;           // N*4
constexpr size_t OFF_H3     = OFF_ED   + 40000;           // N*32
constexpr size_t OFF_OUT0   = OFF_H3   + 320000;          // N*1024 f32 (res+bias)
constexpr size_t OFF_FS1    = OFF_OUT0 + 10240000;        // N*32
constexpr size_t OFF_FD1    = OFF_FS1  + 320000;          // N*32
constexpr size_t OFF_OUT1   = OFF_FD1  + 320000;          // N*32
constexpr size_t OFF_B0F    = OFF_OUT1 + 320000;          // 1024
constexpr size_t OFF_B1F    = OFF_B0F  + 1024;            // 64
constexpr size_t OFF_DEG    = OFF_B1F  + 64;              // int 10016
constexpr size_t OFF_ROWPTR = OFF_DEG  + 10016;           // int 10016
constexpr size_t OFF_CURSOR = OFF_ROWPTR + 10016;         // int 10016
constexpr size_t OFF_CSRE   = OFF_CURSOR + 10016;         // int 64000
constexpr size_t OFF_FS0B   = OFF_CSRE + 64000;           // bf16 N*1024
constexpr size_t OFF_FD0B   = OFF_FS0B + 5120000;         // bf16 N*1024 (reused as out0b)
constexpr size_t OFF_ABF    = OFF_FD0B + 5120000;         // bf16 MPAD*KPAD
constexpr size_t OFF_BT     = OFF_ABF  + 6553600;         // bf16 NBIG2*KPAD
constexpr size_t OFF_BT1    = OFF_BT   + 2048000;         // bf16 96*1024
constexpr size_t WS_FLOATS  = OFF_BT1  + 49152;           // ~30.9M f32

// dual-dtype load: is_f32 ? float : bf16
__device__ __forceinline__ float ldin(const void* p, size_t i, int f32) {
    return f32 ? ((const float*)p)[i]
               : __bfloat162float(((const __hip_bfloat16*)p)[i]);
}
__device__ __forceinline__ float bfu2f(unsigned short u) {
    union { unsigned int i; float f; } x;
    x.i = ((unsigned int)u) << 16;
    return x.f;
}
__device__ __forceinline__ unsigned short f2bu(float v) {
    __hip_bfloat16 h = __float2bfloat16(v);
    unsigned short u;
    __builtin_memcpy(&u, &h, 2);
    return u;
}

// ---------------- kernels ----------------

// dtype detection on first 131072 words
__global__ void detect_kernel(const unsigned short* __restrict__ w, int n,
                              int* __restrict__ flag) {
    int i = blockIdx.x * 256 + threadIdx.x;
    int stride = gridDim.x * 256;
    int found = 0;
    for (; i < n; i += stride) {
        if (((w[i] >> 7) & 0xFF) == 0xFF) found = 1;
    }
    if (found) atomicOr(flag, 1);
}

// column sums of features. grid (5,40), block 256
__global__ void colsum_kernel(const void* __restrict__ feats,
                              float* __restrict__ colsum, const int* __restrict__ dflag) {
    int f32 = *dflag;
    int c = blockIdx.x * blockDim.x + threadIdx.x;
    if (c >= IN_F) return;
    int r0 = blockIdx.y * 250;
    float s = 0.f;
    for (int r = r0; r < r0 + 250; ++r)
        s += ldin(feats, (size_t)r * IN_F + c, f32);
    atomicAdd(&colsum[c], s);
}

// fused small preps: maskmul + b0f + b1f
__global__ void smallprep_kernel(const void* __restrict__ tm, const void* __restrict__ am,
                                 const void* __restrict__ vm, const void* __restrict__ b0,
                                 const void* __restrict__ b1, float* __restrict__ maskmul,
                                 float* __restrict__ b0f, float* __restrict__ b1f,
                                 const int* __restrict__ dflag) {
    int f32 = *dflag;
    int c = blockIdx.x * 256 + threadIdx.x;
    if (c < IN_F) maskmul[c] = ldin(tm, c, f32) + ldin(am, c, f32) + ldin(vm, c, f32);
    if (c < HD0) b0f[c] = ldin(b0, c, f32);
    if (c < HD1) b1f[c] = ldin(b1, c, f32);
}

// fused single-pass: impute row into LDS, L1-scale, mask, emit bf16 A row
__global__ __launch_bounds__(256) void prep_row_kernel(
        const void* __restrict__ feats, const float* __restrict__ colsum,
        const float* __restrict__ maskmul, __hip_bfloat16* __restrict__ abf,
        const int* __restrict__ dflag) {
    int f32 = *dflag;
    int n = blockIdx.x;
    __shared__ float rowbuf[IN_F];
    __shared__ float red[256];
    float s = 0.f;
    for (int c = threadIdx.x; c < IN_F; c += 256) {
        float f = ldin(feats, (size_t)n * IN_F + c, f32);
        float v = (f != 0.0f) ? f : 0.5f * colsum[c] * INV_N;   // 0.5*(h+h1)
        rowbuf[c] = v;
        s += fabsf(v);
    }
    red[threadIdx.x] = s;
    __syncthreads();
    for (int st = 128; st > 0; st >>= 1) {
        if (threadIdx.x < st) red[threadIdx.x] += red[threadIdx.x + st];
        __syncthreads();
    }
    float scale = 1.0f / fmaxf(red[0], 1e-12f);
    for (int k = threadIdx.x; k < KPAD; k += 256) {
        float v = (k < IN_F) ? rowbuf[k] * scale * maskmul[k] : 0.f;
        abf[(size_t)n * KPAD + k] = __float2bfloat16(v);
    }
}

// zero-fill abf pad rows
__global__ void abf_pad_kernel(__hip_bfloat16* __restrict__ abf) {
    int idx = blockIdx.x * 256 + threadIdx.x;
    if (idx >= (MPAD - N_NODES) * KPAD) return;
    abf[(size_t)N_NODES * KPAD + idx] = __float2bfloat16(0.f);
}

// fused transposed B [NBIG2][KPAD]
__global__ void bt_kernel(const void* __restrict__ Wl0, const void* __restrict__ Wr0,
                          const void* __restrict__ Wres0, const void* __restrict__ W2,
                          __hip_bfloat16* __restrict__ bt, const int* __restrict__ dflag) {
    int f32 = *dflag;
    int idx = blockIdx.x * 256 + threadIdx.x;   // k*NBIG2 + n
    if (idx >= KPAD * NBIG2) return;
    int k = idx / NBIG2, n = idx % NBIG2;
    float v = 0.f;
    if (k < IN_F) {
        if (n < NBIG) {
            int seg = n >> 10, col = n & 1023;
            const void* W = (seg == 0) ? Wl0 : (seg == 1) ? Wr0 : Wres0;
            v = ldin(W, (size_t)k * HD0 + col, f32);
        } else if (n < NBIG + HD1) {
            int col = n - NBIG;                 // h*8+o
            int hh = col >> 3, o = col & 7;
            v = ldin(W2, ((size_t)hh * IN_F + k) * D1 + o, f32);
        }
    }
    bt[(size_t)n * KPAD + k] = __float2bfloat16(v);
}

// transposed layer-1 B [96][1024]
__global__ void bt1_kernel(const void* __restrict__ Wl1, const void* __restrict__ Wr1,
                           const void* __restrict__ Wres1, __hip_bfloat16* __restrict__ bt1,
                           const int* __restrict__ dflag) {
    int f32 = *dflag;
    int idx = blockIdx.x * 256 + threadIdx.x;   // k*96 + n
    if (idx >= HD0 * 96) return;
    int k = idx / 96, n = idx % 96;
    int seg = n >> 5, col = n & 31;
    const void* W = (seg == 0) ? Wl1 : (seg == 1) ? Wr1 : Wres1;
    bt1[(size_t)n * HD0 + k] = __float2bfloat16(ldin(W, (size_t)k * HD1 + col, f32));
}

// ---- CSR build ----
__global__ void deg_kernel(const int* __restrict__ dst, int* __restrict__ deg) {
    int e = blockIdx.x * 256 + threadIdx.x;
    if (e < N_EDGES) atomicAdd(&deg[dst[e]], 1);
}

__global__ __launch_bounds__(256) void scan_kernel(const int* __restrict__ deg,
                                                   int* __restrict__ rowptr,
                                                   int* __restrict__ cursor) {
    __shared__ int sums[256];
    __shared__ int offs[257];
    int t = threadIdx.x;
    int base = t * 40;
    int s = 0;
    for (int i = 0; i < 40; ++i) {
        int idx = base + i;
        if (idx < N_NODES) s += deg[idx];
    }
    sums[t] = s;
    __syncthreads();
    if (t == 0) {
        int run = 0;
        for (int i = 0; i < 256; ++i) { offs[i] = run; run += sums[i]; }
        offs[256] = run;
    }
    __syncthreads();
    int run = offs[t];
    for (int i = 0; i < 40; ++i) {
        int idx = base + i;
        if (idx < N_NODES) {
            rowptr[idx] = run; cursor[idx] = run;
            run += deg[idx];
        }
    }
    if (t == 255) rowptr[N_NODES] = offs[256];
}

__global__ void scatter_kernel(const int* __restrict__ dst, int* __restrict__ cursor,
                               int* __restrict__ csr_eid) {
    int e = blockIdx.x * 256 + threadIdx.x;
    if (e >= N_EDGES) return;
    int pos = atomicAdd(&cursor[dst[e]], 1);
    csr_eid[pos] = e;
}

// MFMA GEMM: C[MPAD x 3200] = abf @ bt^T, double-buffered DMA staging,
// fragment-major LDS, XCD-aware swizzle (flat grid 2000 = 8 XCD * 25 cols * 10 rows).
__global__ __launch_bounds__(256) void mfma_gemm(
        const unsigned short* __restrict__ A, const unsigned short* __restrict__ BT,
        const float* __restrict__ b0f, __hip_bfloat16* __restrict__ fs0b,
        __hip_bfloat16* __restrict__ fd0b, float* __restrict__ out0,
        float* __restrict__ z) {
    __shared__ unsigned short As[2][128 * 32];   // 2 x 8KB ping-pong
    __shared__ unsigned short Bs[2][128 * 32];
    const int g = blockIdx.x;
    const int xcd = g & 7, l = g >> 3;
    const int colb = l / 10, rowl = l - colb * 10;
    const int bm = (xcd * 10 + rowl) * 128;
    const int bn = colb * 128;
    const int tid = threadIdx.x;
    const int wave = tid >> 6, lane = tid & 63;
    const int quad = lane >> 4, l16 = lane & 15;
    const int wm = (wave & 1) * 64, wn = (wave >> 1) * 64;
    const int srow = lane & 15;
    const int skc  = (lane >> 4) * 8;

    f32x4 acc[4][4];
#pragma unroll
    for (int i = 0; i < 4; ++i)
#pragma unroll
        for (int j = 0; j < 4; ++j) acc[i][j] = (f32x4){0.f, 0.f, 0.f, 0.f};

    // prologue: stage tile 0 into buffer 0
#pragma unroll
    for (int t = 0; t < 2; ++t) {
        int f = t * 4 + wave;
        async_copy16(A + (size_t)(bm + f * 16 + srow) * KPAD + skc, As[0] + f * 512);
        async_copy16(BT + (size_t)(bn + f * 16 + srow) * KPAD + skc, Bs[0] + f * 512);
    }
    __syncthreads();

    for (int it = 0; it < KPAD / 32; ++it) {
        int cur = it & 1;
        if (it + 1 < KPAD / 32) {
            int k1 = (it + 1) * 32;
#pragma unroll
            for (int t = 0; t < 2; ++t) {
                int f = t * 4 + wave;
                async_copy16(A + (size_t)(bm + f * 16 + srow) * KPAD + k1 + skc,
                             As[cur ^ 1] + f * 512);
                async_copy16(BT + (size_t)(bn + f * 16 + srow) * KPAD + k1 + skc,
                             Bs[cur ^ 1] + f * 512);
            }
        }
        bf16x8 af[4], bfr[4];
#pragma unroll
        for (int i = 0; i < 4; ++i)
            af[i] = *(const bf16x8*)(As[cur] + ((wave & 1) * 4 + i) * 512 + lane * 8);
#pragma unroll
        for (int j = 0; j < 4; ++j)
            bfr[j] = *(const bf16x8*)(Bs[cur] + ((wave >> 1) * 4 + j) * 512 + lane * 8);
#pragma unroll
        for (int i = 0; i < 4; ++i)
#pragma unroll
            for (int j = 0; j < 4; ++j)
                acc[i][j] = __builtin_amdgcn_mfma_f32_16x16x32_bf16(
                    af[i], bfr[j], acc[i][j], 0, 0, 0);
        __syncthreads();   // drains next-tile DMA (overlapped with compute above)
    }

    const int seg = bn >> 10;
#pragma unroll
    for (int i = 0; i < 4; ++i) {
#pragma unroll
        for (int r = 0; r < 4; ++r) {
            int gm = bm + wm + i * 16 + quad * 4 + r;
            if (gm >= N_NODES) continue;
#pragma unroll
            for (int j = 0; j < 4; ++j) {
                int gnl = (bn & 1023) + wn + j * 16 + l16;
                float v = acc[i][j][r];
                if (seg == 0)      fs0b[(size_t)gm * HD0 + gnl] = __float2bfloat16(v);
                else if (seg == 1) fd0b[(size_t)gm * HD0 + gnl] = __float2bfloat16(v);
                else if (seg == 2) out0[(size_t)gm * HD0 + gnl] = v + b0f[gnl];
                else if (gnl < HD1) z[(size_t)gm * HD1 + gnl] = v;
            }
        }
    }
}

// fused layer-0 attention, SINGLE pass: out0b = relu(res + (sum p*fs)/(sum p)), bf16.
__global__ __launch_bounds__(256) void att0_kernel(
        const int* __restrict__ rowptr, const int* __restrict__ csre,
        const int* __restrict__ src, const __hip_bfloat16* __restrict__ fs,
        const __hip_bfloat16* __restrict__ fd, const void* __restrict__ a0,
        const float* __restrict__ out0res, __hip_bfloat16* __restrict__ out0b,
        const int* __restrict__ dflag) {
    int f32 = *dflag;
    int n = blockIdx.x;
    int t = threadIdx.x;
    __shared__ float sfd[HD0];
    __shared__ float sa0[HD0];
    {
        const unsigned short* fdp = (const unsigned short*)fd + (size_t)n * HD0;
        ushort4 u = *(const ushort4*)(fdp + 4 * t);
        sfd[4 * t + 0] = bfu2f(u.x); sfd[4 * t + 1] = bfu2f(u.y);
        sfd[4 * t + 2] = bfu2f(u.z); sfd[4 * t + 3] = bfu2f(u.w);
#pragma unroll
        for (int i = 0; i < 4; ++i) sa0[4 * t + i] = ldin(a0, 4 * t + i, f32);
    }
    __syncthreads();
    int start = rowptr[n], end = rowptr[n + 1];
    const unsigned short* fsu = (const unsigned short*)fs;
    float den = 0.f;
    float acc[4] = {0.f, 0.f, 0.f, 0.f};
    for (int i = start; i < end; ++i) {
        int s = src[csre[i]];
        ushort4 u = *(const ushort4*)(fsu + (size_t)s * HD0 + 4 * t);
        float fv[4], part = 0.f;
#pragma unroll
        for (int j = 0; j < 4; ++j) {
            unsigned short uj = (j == 0) ? u.x : (j == 1) ? u.y : (j == 2) ? u.z : u.w;
            fv[j] = bfu2f(uj);
            float x = fv[j] + sfd[4 * t + j];
            x = x > 0.f ? x : 0.2f * x;
            part += x * sa0[4 * t + j];
        }
        for (int off = 32; off > 0; off >>= 1) part += __shfl_xor(part, off);
        float p = expf(part);
        den += p;   // identical across the wave (= head)
#pragma unroll
        for (int j = 0; j < 4; ++j) acc[j] += p * fv[j];
    }
    float inv = 1.0f / fmaxf(den, 1e-9f);
    float4 base = *(const float4*)(out0res + (size_t)n * HD0 + 4 * t);
    ushort4 o;
    o.x = f2bu(fmaxf(base.x + acc[0] * inv, 0.f));
    o.y = f2bu(fmaxf(base.y + acc[1] * inv, 0.f));
    o.z = f2bu(fmaxf(base.z + acc[2] * inv, 0.f));
    o.w = f2bu(fmaxf(base.w + acc[3] * inv, 0.f));
    *(ushort4*)((unsigned short*)out0b + (size_t)n * HD0 + 4 * t) = o;
}

// layer-1 fused MFMA GEMM: C[10000 x 96] = out0b @ bt1^T, K=1024, 64-row tiles,
// double-buffered DMA staging.
__global__ __launch_bounds__(256) void mfma_gemm96(
        const unsigned short* __restrict__ A, const unsigned short* __restrict__ BT1,
        const float* __restrict__ b1f, float* __restrict__ fs1,
        float* __restrict__ fd1, float* __restrict__ out1) {
    __shared__ unsigned short As[2][64 * 32];
    __shared__ unsigned short Bs[2][96 * 32];
    const int tid = threadIdx.x;
    const int wave = tid >> 6, lane = tid & 63;
    const int quad = lane >> 4, l16 = lane & 15;
    const int bm = blockIdx.x * 64;
    const int srow = lane & 15;
    const int skc  = (lane >> 4) * 8;

    f32x4 acc[6];
#pragma unroll
    for (int j = 0; j < 6; ++j) acc[j] = (f32x4){0.f, 0.f, 0.f, 0.f};

    // prologue
    async_copy16(A + (size_t)(bm + wave * 16 + srow) * HD0 + skc, As[0] + wave * 512);
    async_copy16(BT1 + (size_t)(wave * 16 + srow) * HD0 + skc, Bs[0] + wave * 512);
    if (wave < 2) {
        int f = 4 + wave;
        async_copy16(BT1 + (size_t)(f * 16 + srow) * HD0 + skc, Bs[0] + f * 512);
    }
    __syncthreads();

    for (int it = 0; it < HD0 / 32; ++it) {
        int cur = it & 1;
        if (it + 1 < HD0 / 32) {
            int k1 = (it + 1) * 32;
            async_copy16(A + (size_t)(bm + wave * 16 + srow) * HD0 + k1 + skc,
                         As[cur ^ 1] + wave * 512);
            async_copy16(BT1 + (size_t)(wave * 16 + srow) * HD0 + k1 + skc,
                         Bs[cur ^ 1] + wave * 512);
            if (wave < 2) {
                int f = 4 + wave;
                async_copy16(BT1 + (size_t)(f * 16 + srow) * HD0 + k1 + skc,
                             Bs[cur ^ 1] + f * 512);
            }
        }
        bf16x8 af = *(const bf16x8*)(As[cur] + wave * 512 + lane * 8);
#pragma unroll
        for (int j = 0; j < 6; ++j) {
            bf16x8 bfr = *(const bf16x8*)(Bs[cur] + j * 512 + lane * 8);
            acc[j] = __builtin_amdgcn_mfma_f32_16x16x32_bf16(af, bfr, acc[j], 0, 0, 0);
        }
        __syncthreads();
    }

#pragma unroll
    for (int r = 0; r < 4; ++r) {
        int gm = bm + wave * 16 + quad * 4 + r;
        if (gm >= N_NODES) continue;
#pragma unroll
        for (int j = 0; j < 6; ++j) {
            int col = j * 16 + l16;
            int seg = col >> 5, cl = col & 31;
            float v = acc[j][r];
            if (seg == 0)      fs1[(size_t)gm * HD1 + cl] = v;
            else if (seg == 1) fd1[(size_t)gm * HD1 + cl] = v;
            else               out1[(size_t)gm * HD1 + cl] = v + b1f[cl];
        }
    }
}

// es/ed for gat_inner
__global__ void esed_kernel(const float* __restrict__ z, const void* __restrict__ a2,
                            float* __restrict__ es, float* __restrict__ ed,
                            const int* __restrict__ dflag) {
    int f32 = *dflag;
    int idx = blockIdx.x * 256 + threadIdx.x;   // n*NH + h
    if (idx >= N_NODES * NH) return;
    int hh = idx % NH;
    const float* zp = z + (size_t)idx * D1;
    float s1 = 0.f, s2 = 0.f;
    for (int o = 0; o < D1; ++o) {
        float zv = zp[o];
        s1 += zv * ldin(a2, hh * 2 * D1 + o, f32);
        s2 += zv * ldin(a2, hh * 2 * D1 + D1 + o, f32);
    }
    es[idx] = s1; ed[idx] = s2;
}

// gat_inner fused attention, single pass: h3[n] = (sum p*z[src])/(sum p)
__global__ __launch_bounds__(64) void att32z_kernel(
        const int* __restrict__ rowptr, const int* __restrict__ csre,
        const int* __restrict__ src, const float* __restrict__ z,
        const float* __restrict__ es, const float* __restrict__ ed,
        float* __restrict__ h3) {
    int n = blockIdx.x;
    int lane = threadIdx.x;
    if (lane >= HD1) return;
    int h = lane >> 3;
    float edn = ed[n * NH + h];
    float den = 0.f, acc = 0.f;
    int start = rowptr[n], end = rowptr[n + 1];
    for (int i = start; i < end; ++i) {
        int s = src[csre[i]];
        float x = es[s * NH + h] + edn;
        x = x > 0.f ? x : 0.2f * x;
        float p = expf(x);
        den += p;
        acc += p * z[(size_t)s * HD1 + lane];
    }
    h3[(size_t)n * HD1 + lane] = acc / fmaxf(den, 1e-9f);
}

// layer-1 fused attention, single pass: out1[n] += (sum p*fs1[src])/(sum p)
__global__ __launch_bounds__(64) void att32e_kernel(
        const int* __restrict__ rowptr, const int* __restrict__ csre,
        const int* __restrict__ src, const float* __restrict__ fs1,
        const float* __restrict__ fd1, const void* __restrict__ a1,
        float* __restrict__ out1, const int* __restrict__ dflag) {
    int f32 = *dflag;
    int n = blockIdx.x;
    int lane = threadIdx.x;
    if (lane >= HD1) return;
    float fdn = fd1[(size_t)n * HD1 + lane];
    float a = ldin(a1, lane, f32);            // a1[h][o], lane = h*8+o
    float den = 0.f, acc = 0.f;
    int start = rowptr[n], end = rowptr[n + 1];
    for (int i = start; i < end; ++i) {
        int s = src[csre[i]];
        float fsv = fs1[(size_t)s * HD1 + lane];
        float x = fsv + fdn;
        x = x > 0.f ? x : 0.2f * x;
        float term = x * a;
        term += __shfl_xor(term, 1);
        term += __shfl_xor(term, 2);
        term += __shfl_xor(term, 4);          // head-wide logit (8 lanes/oct)
        float p = expf(term);
        den += p;
        acc += p * fsv;
    }
    out1[(size_t)n * HD1 + lane] += acc / fmaxf(den, 1e-9f);
}

// final: out[n,o] = [h3 | relu(out1)] @ Wlin + blin; dual-dtype store
__global__ void final_kernel(const float* __restrict__ h3, const float* __restrict__ out1,
                             const void* __restrict__ Wlin, const void* __restrict__ blin,
                             void* __restrict__ out, const int* __restrict__ dflag) {
    int f32 = *dflag;
    int idx = blockIdx.x * 256 + threadIdx.x;   // n*OUTF + o
    if (idx >= N_NODES * OUTF) return;
    int n = idx / OUTF, o = idx % OUTF;
    float acc = ldin(blin, o, f32);
    for (int j = 0; j < HD1; ++j)
        acc += h3[(size_t)n * HD1 + j] * ldin(Wlin, j * OUTF + o, f32);
    for (int j = 0; j < HD1; ++j)
        acc += fmaxf(out1[(size_t)n * HD1 + j], 0.f) * ldin(Wlin, (HD1 + j) * OUTF + o, f32);
    if (f32) ((float*)out)[idx] = acc;
    else     ((__hip_bfloat16*)out)[idx] = __float2bfloat16(acc);
}

// ---------------- launch ----------------
extern "C" void kernel_launch(void* const* d_in, const int* in_sizes, int n_in,
                              void* d_out, int out_size, void* d_ws, size_t ws_size,
                              hipStream_t stream) {
    const void* feats = d_in[0];
    const int*  src   = (const int*)d_in[1];
    const int*  dst   = (const int*)d_in[2];
    const void* tm    = d_in[3];
    const void* am    = d_in[4];
    const void* vm    = d_in[5];
    const void* W2    = d_in[6];
    const void* a2    = d_in[7];
    const void* Wl0   = d_in[8];
    const void* Wr0   = d_in[9];
    const void* a0    = d_in[10];
    const void* Wres0 = d_in[11];
    const void* b0    = d_in[12];
    const void* Wl1   = d_in[13];
    const void* Wr1   = d_in[14];
    const void* a1    = d_in[15];
    const void* Wres1 = d_in[16];
    const void* b1    = d_in[17];
    const void* Wlin  = d_in[18];
    const void* blin  = d_in[19];

    float* ws = (float*)d_ws;
    int*   dflag  = (int*)(ws + OFF_FLAG);
    float* colsum = ws + OFF_COLSUM;
    float* maskm  = ws + OFF_MASKM;
    float* z      = ws + OFF_Z;
    float* es     = ws + OFF_ES;
    float* ed     = ws + OFF_ED;
    float* h3     = ws + OFF_H3;
    float* out0   = ws + OFF_OUT0;
    float* fs1    = ws + OFF_FS1;
    float* fd1    = ws + OFF_FD1;
    float* out1   = ws + OFF_OUT1;
    float* b0f    = ws + OFF_B0F;
    float* b1f    = ws + OFF_B1F;
    int*   deg    = (int*)(ws + OFF_DEG);
    int*   rowptr = (int*)(ws + OFF_ROWPTR);
    int*   cursor = (int*)(ws + OFF_CURSOR);
    int*   csre   = (int*)(ws + OFF_CSRE);
    __hip_bfloat16* fs0b = (__hip_bfloat16*)(ws + OFF_FS0B);
    __hip_bfloat16* fd0b = (__hip_bfloat16*)(ws + OFF_FD0B);
    __hip_bfloat16* abf  = (__hip_bfloat16*)(ws + OFF_ABF);
    __hip_bfloat16* bt   = (__hip_bfloat16*)(ws + OFF_BT);
    __hip_bfloat16* bt1  = (__hip_bfloat16*)(ws + OFF_BT1);
    __hip_bfloat16* out0b = fd0b;   // fd0b row n retired after att0 block n reads it

    // zero accumulators (ws poisoned 0xAA before every call)
    (void)hipMemsetAsync(dflag, 0, sizeof(int), stream);
    (void)hipMemsetAsync(colsum, 0, 1280 * sizeof(float), stream);
    (void)hipMemsetAsync(deg, 0, N_NODES * sizeof(int), stream);

    // dtype detection (subset scan)
    detect_kernel<<<64, 256, 0, stream>>>((const unsigned short*)feats, 131072, dflag);

    // CSR build
    deg_kernel<<<(N_EDGES + 255) / 256, 256, 0, stream>>>(dst, deg);
    scan_kernel<<<1, 256, 0, stream>>>(deg, rowptr, cursor);
    scatter_kernel<<<(N_EDGES + 255) / 256, 256, 0, stream>>>(dst, cursor, csre);

    // preprocess
    colsum_kernel<<<dim3(5, 40), 256, 0, stream>>>(feats, colsum, dflag);
    smallprep_kernel<<<5, 256, 0, stream>>>(tm, am, vm, b0, b1, maskm, b0f, b1f, dflag);
    prep_row_kernel<<<N_NODES, 256, 0, stream>>>(feats, colsum, maskm, abf, dflag);
    abf_pad_kernel<<<((MPAD - N_NODES) * KPAD + 255) / 256, 256, 0, stream>>>(abf);
    bt_kernel<<<(KPAD * NBIG2 + 255) / 256, 256, 0, stream>>>(Wl0, Wr0, Wres0, W2, bt, dflag);
    bt1_kernel<<<(HD0 * 96 + 255) / 256, 256, 0, stream>>>(Wl1, Wr1, Wres1, bt1, dflag);

    // big fused projection GEMM (Wl0 | Wr0 | Wres0 | W2-z), XCD-swizzled, dbuf
    mfma_gemm<<<2000, 256, 0, stream>>>(
        (const unsigned short*)abf, (const unsigned short*)bt, b0f, fs0b, fd0b, out0, z);

    // gat_inner (h3): es/ed then single-pass CSR attention
    esed_kernel<<<(N_NODES * NH + 255) / 256, 256, 0, stream>>>(z, a2, es, ed, dflag);
    att32z_kernel<<<N_NODES, 64, 0, stream>>>(rowptr, csre, src, z, es, ed, h3);

    // GATv2 layer 0: fused single-pass attention
    att0_kernel<<<N_NODES, 256, 0, stream>>>(rowptr, csre, src, fs0b, fd0b, a0,
                                             out0, out0b, dflag);

    // GATv2 layer 1
    mfma_gemm96<<<(N_NODES + 63) / 64, 256, 0, stream>>>(
        (const unsigned short*)out0b, (const unsigned short*)bt1, b1f, fs1, fd1, out1);
    att32e_kernel<<<N_NODES, 64, 0, stream>>>(rowptr, csre, src, fs1, fd1, a1, out1, dflag);

    // final linear (relu(out1) folded in)
    final_kernel<<<(N_NODES * OUTF + 255) / 256, 256, 0, stream>>>(h3, out1, Wlin, blin,
                                                                   d_out, dflag);
}

// Round 11
// 618.976 us; speedup vs baseline: 6.6797x; 1.0062x over previous
//
#include <hip/hip_runtime.h>
#include <hip/hip_bf16.h>

// Problem constants
#define N_NODES 10000
#define N_EDGES 64000
#define IN_F    1247
#define KPAD    1280   // IN_F padded to mult of 32
#define NH      4
#define D0      256
#define D1      8
#define HD0     1024   // NH*D0
#define HD1     32     // NH*D1
#define NBIG    3072   // Wl0 | Wr0 | Wres0
#define NBIG2   3200   // + 32 z cols (from W2) + 96 pad
#define OUTF    6
#define INV_N   (1.0f / 10000.0f)
#define MPAD    10240  // 80 row-tiles (XCD swizzle: 80 = 8 XCD * 10)

typedef __attribute__((ext_vector_type(8))) short bf16x8;
typedef __attribute__((ext_vector_type(4))) float f32x4;
typedef unsigned int u32;

// async 16B global -> LDS (DMA). LDS dest: wave-uniform base + lane*16.
__device__ __forceinline__ void async_copy16(const unsigned short* gsrc,
                                             unsigned short* ldst) {
    __builtin_amdgcn_global_load_lds(
        (const __attribute__((address_space(1))) u32*)(gsrc),
        (__attribute__((address_space(3))) u32*)(ldst), 16, 0, 0);
}

// ---------------- workspace layout (float-slot offsets) ----------------
constexpr size_t OFF_FLAG   = 0;                          // 16
constexpr size_t OFF_COLSUM = 16;                         // 1280
constexpr size_t OFF_MASKM  = 1296;                       // 1280
constexpr size_t OFF_Z      = 2576;                       // N*32
constexpr size_t OFF_ES     = OFF_Z    + 320000;          // N*4
constexpr size_t OFF_ED     = OFF_ES   + 40000;           // N*4
constexpr size_t OFF_H3     = OFF_ED   + 40000;           // N*32
constexpr size_t OFF_OUT0   = OFF_H3   + 320000;          // bf16 N*1024 (res+bias)
constexpr size_t OFF_FS1    = OFF_OUT0 + 10240000;        // N*32
constexpr size_t OFF_FD1    = OFF_FS1  + 320000;          // N*32
constexpr size_t OFF_OUT1   = OFF_FD1  + 320000;          // N*32
constexpr size_t OFF_B0F    = OFF_OUT1 + 320000;          // 1024
constexpr size_t OFF_B1F    = OFF_B0F  + 1024;            // 64
constexpr size_t OFF_DEG    = OFF_B1F  + 64;              // int 10016
constexpr size_t OFF_ROWPTR = OFF_DEG  + 10016;           // int 10016
constexpr size_t OFF_CURSOR = OFF_ROWPTR + 10016;         // int 10016
constexpr size_t OFF_CSRE   = OFF_CURSOR + 10016;         // int 64000
constexpr size_t OFF_FS0B   = OFF_CSRE + 64000;           // bf16 N*1024
constexpr size_t OFF_FD0B   = OFF_FS0B + 5120000;         // bf16 N*1024 (reused as out0b)
constexpr size_t OFF_ABF    = OFF_FD0B + 5120000;         // bf16 MPAD*KPAD
constexpr size_t OFF_BT     = OFF_ABF  + 6553600;         // bf16 NBIG2*KPAD
constexpr size_t OFF_BT1    = OFF_BT   + 2048000;         // bf16 96*1024
constexpr size_t WS_FLOATS  = OFF_BT1  + 49152;

// dual-dtype load: is_f32 ? float : bf16
__device__ __forceinline__ float ldin(const void* p, size_t i, int f32) {
    return f32 ? ((const float*)p)[i]
               : __bfloat162float(((const __hip_bfloat16*)p)[i]);
}
__device__ __forceinline__ float bfu2f(unsigned short u) {
    union { unsigned int i; float f; } x;
    x.i = ((unsigned int)u) << 16;
    return x.f;
}
__device__ __forceinline__ unsigned short f2bu(float v) {
    __hip_bfloat16 h = __float2bfloat16(v);
    unsigned short u;
    __builtin_memcpy(&u, &h, 2);
    return u;
}

// ---------------- kernels ----------------

// dtype detection on first 131072 words
__global__ void detect_kernel(const unsigned short* __restrict__ w, int n,
                              int* __restrict__ flag) {
    int i = blockIdx.x * 256 + threadIdx.x;
    int stride = gridDim.x * 256;
    int found = 0;
    for (; i < n; i += stride) {
        if (((w[i] >> 7) & 0xFF) == 0xFF) found = 1;
    }
    if (found) atomicOr(flag, 1);
}

// column sums of features. grid (5,40), block 256
__global__ void colsum_kernel(const void* __restrict__ feats,
                              float* __restrict__ colsum, const int* __restrict__ dflag) {
    int f32 = *dflag;
    int c = blockIdx.x * blockDim.x + threadIdx.x;
    if (c >= IN_F) return;
    int r0 = blockIdx.y * 250;
    float s = 0.f;
    for (int r = r0; r < r0 + 250; ++r)
        s += ldin(feats, (size_t)r * IN_F + c, f32);
    atomicAdd(&colsum[c], s);
}

// fused small preps: maskmul + b0f + b1f
__global__ void smallprep_kernel(const void* __restrict__ tm, const void* __restrict__ am,
                                 const void* __restrict__ vm, const void* __restrict__ b0,
                                 const void* __restrict__ b1, float* __restrict__ maskmul,
                                 float* __restrict__ b0f, float* __restrict__ b1f,
                                 const int* __restrict__ dflag) {
    int f32 = *dflag;
    int c = blockIdx.x * 256 + threadIdx.x;
    if (c < IN_F) maskmul[c] = ldin(tm, c, f32) + ldin(am, c, f32) + ldin(vm, c, f32);
    if (c < HD0) b0f[c] = ldin(b0, c, f32);
    if (c < HD1) b1f[c] = ldin(b1, c, f32);
}

// fused single-pass: impute row into LDS, L1-scale, mask, emit bf16 A row
__global__ __launch_bounds__(256) void prep_row_kernel(
        const void* __restrict__ feats, const float* __restrict__ colsum,
        const float* __restrict__ maskmul, __hip_bfloat16* __restrict__ abf,
        const int* __restrict__ dflag) {
    int f32 = *dflag;
    int n = blockIdx.x;
    __shared__ float rowbuf[IN_F];
    __shared__ float red[256];
    float s = 0.f;
    for (int c = threadIdx.x; c < IN_F; c += 256) {
        float f = ldin(feats, (size_t)n * IN_F + c, f32);
        float v = (f != 0.0f) ? f : 0.5f * colsum[c] * INV_N;   // 0.5*(h+h1)
        rowbuf[c] = v;
        s += fabsf(v);
    }
    red[threadIdx.x] = s;
    __syncthreads();
    for (int st = 128; st > 0; st >>= 1) {
        if (threadIdx.x < st) red[threadIdx.x] += red[threadIdx.x + st];
        __syncthreads();
    }
    float scale = 1.0f / fmaxf(red[0], 1e-12f);
    for (int k = threadIdx.x; k < KPAD; k += 256) {
        float v = (k < IN_F) ? rowbuf[k] * scale * maskmul[k] : 0.f;
        abf[(size_t)n * KPAD + k] = __float2bfloat16(v);
    }
}

// zero-fill abf pad rows
__global__ void abf_pad_kernel(__hip_bfloat16* __restrict__ abf) {
    int idx = blockIdx.x * 256 + threadIdx.x;
    if (idx >= (MPAD - N_NODES) * KPAD) return;
    abf[(size_t)N_NODES * KPAD + idx] = __float2bfloat16(0.f);
}

// fused transposed B [NBIG2][KPAD]
__global__ void bt_kernel(const void* __restrict__ Wl0, const void* __restrict__ Wr0,
                          const void* __restrict__ Wres0, const void* __restrict__ W2,
                          __hip_bfloat16* __restrict__ bt, const int* __restrict__ dflag) {
    int f32 = *dflag;
    int idx = blockIdx.x * 256 + threadIdx.x;   // k*NBIG2 + n
    if (idx >= KPAD * NBIG2) return;
    int k = idx / NBIG2, n = idx % NBIG2;
    float v = 0.f;
    if (k < IN_F) {
        if (n < NBIG) {
            int seg = n >> 10, col = n & 1023;
            const void* W = (seg == 0) ? Wl0 : (seg == 1) ? Wr0 : Wres0;
            v = ldin(W, (size_t)k * HD0 + col, f32);
        } else if (n < NBIG + HD1) {
            int col = n - NBIG;                 // h*8+o
            int hh = col >> 3, o = col & 7;
            v = ldin(W2, ((size_t)hh * IN_F + k) * D1 + o, f32);
        }
    }
    bt[(size_t)n * KPAD + k] = __float2bfloat16(v);
}

// transposed layer-1 B [96][1024]
__global__ void bt1_kernel(const void* __restrict__ Wl1, const void* __restrict__ Wr1,
                           const void* __restrict__ Wres1, __hip_bfloat16* __restrict__ bt1,
                           const int* __restrict__ dflag) {
    int f32 = *dflag;
    int idx = blockIdx.x * 256 + threadIdx.x;   // k*96 + n
    if (idx >= HD0 * 96) return;
    int k = idx / 96, n = idx % 96;
    int seg = n >> 5, col = n & 31;
    const void* W = (seg == 0) ? Wl1 : (seg == 1) ? Wr1 : Wres1;
    bt1[(size_t)n * HD0 + k] = __float2bfloat16(ldin(W, (size_t)k * HD1 + col, f32));
}

// ---- CSR build ----
__global__ void deg_kernel(const int* __restrict__ dst, int* __restrict__ deg) {
    int e = blockIdx.x * 256 + threadIdx.x;
    if (e < N_EDGES) atomicAdd(&deg[dst[e]], 1);
}

__global__ __launch_bounds__(256) void scan_kernel(const int* __restrict__ deg,
                                                   int* __restrict__ rowptr,
                                                   int* __restrict__ cursor) {
    __shared__ int sums[256];
    __shared__ int offs[257];
    int t = threadIdx.x;
    int base = t * 40;
    int s = 0;
    for (int i = 0; i < 40; ++i) {
        int idx = base + i;
        if (idx < N_NODES) s += deg[idx];
    }
    sums[t] = s;
    __syncthreads();
    if (t == 0) {
        int run = 0;
        for (int i = 0; i < 256; ++i) { offs[i] = run; run += sums[i]; }
        offs[256] = run;
    }
    __syncthreads();
    int run = offs[t];
    for (int i = 0; i < 40; ++i) {
        int idx = base + i;
        if (idx < N_NODES) {
            rowptr[idx] = run; cursor[idx] = run;
            run += deg[idx];
        }
    }
    if (t == 255) rowptr[N_NODES] = offs[256];
}

__global__ void scatter_kernel(const int* __restrict__ dst, int* __restrict__ cursor,
                               int* __restrict__ csr_eid) {
    int e = blockIdx.x * 256 + threadIdx.x;
    if (e >= N_EDGES) return;
    int pos = atomicAdd(&cursor[dst[e]], 1);
    csr_eid[pos] = e;
}

// MFMA GEMM: C[MPAD x 3200] = abf @ bt^T. Triple-buffered DMA staging with manual
// s_waitcnt vmcnt(N) + raw s_barrier (prefetch depth 2 stays in flight across the
// barrier), fragment-major LDS, XCD-aware swizzle (flat grid 2000).
// Epilogue: cols 0..1023 -> fs0b (bf16), 1024..2047 -> fd0b (bf16),
// 2048..3071 -> out0r (bf16, +b0), 3072..3103 -> z (f32).
__global__ __launch_bounds__(256) void mfma_gemm(
        const unsigned short* __restrict__ A, const unsigned short* __restrict__ BT,
        const float* __restrict__ b0f, __hip_bfloat16* __restrict__ fs0b,
        __hip_bfloat16* __restrict__ fd0b, __hip_bfloat16* __restrict__ out0r,
        float* __restrict__ z) {
    __shared__ unsigned short As[3][128 * 32];   // 3 x 8KB
    __shared__ unsigned short Bs[3][128 * 32];
    const int g = blockIdx.x;
    const int xcd = g & 7, l = g >> 3;
    const int colb = l / 10, rowl = l - colb * 10;
    const int bm = (xcd * 10 + rowl) * 128;
    const int bn = colb * 128;
    const int tid = threadIdx.x;
    const int wave = tid >> 6, lane = tid & 63;
    const int quad = lane >> 4, l16 = lane & 15;
    const int wm = (wave & 1) * 64, wn = (wave >> 1) * 64;
    const int srow = lane & 15;
    const int skc  = (lane >> 4) * 8;
    const int NIT = KPAD / 32;   // 40

    f32x4 acc[4][4];
#pragma unroll
    for (int i = 0; i < 4; ++i)
#pragma unroll
        for (int j = 0; j < 4; ++j) acc[i][j] = (f32x4){0.f, 0.f, 0.f, 0.f};

    // prologue: stage tiles 0 and 1 (4 DMAs per wave per tile, in order)
#pragma unroll
    for (int p = 0; p < 2; ++p) {
#pragma unroll
        for (int t = 0; t < 2; ++t) {
            int f = t * 4 + wave;
            async_copy16(A + (size_t)(bm + f * 16 + srow) * KPAD + p * 32 + skc,
                         As[p] + f * 512);
            async_copy16(BT + (size_t)(bn + f * 16 + srow) * KPAD + p * 32 + skc,
                         Bs[p] + f * 512);
        }
    }

    for (int it = 0; it < NIT; ++it) {
        int cur = it % 3;
        if (it + 2 < NIT) {
            int k2 = (it + 2) * 32, b2 = (it + 2) % 3;
#pragma unroll
            for (int t = 0; t < 2; ++t) {
                int f = t * 4 + wave;
                async_copy16(A + (size_t)(bm + f * 16 + srow) * KPAD + k2 + skc,
                             As[b2] + f * 512);
                async_copy16(BT + (size_t)(bn + f * 16 + srow) * KPAD + k2 + skc,
                             Bs[b2] + f * 512);
            }
            asm volatile("s_waitcnt vmcnt(8)" ::: "memory");   // tile `it` landed
        } else if (it + 2 == NIT) {
            asm volatile("s_waitcnt vmcnt(4)" ::: "memory");
        } else {
            asm volatile("s_waitcnt vmcnt(0)" ::: "memory");
        }
        asm volatile("s_barrier" ::: "memory");   // all waves' tile-`it` deposits done

        bf16x8 af[4], bfr[4];
#pragma unroll
        for (int i = 0; i < 4; ++i)
            af[i] = *(const bf16x8*)(As[cur] + ((wave & 1) * 4 + i) * 512 + lane * 8);
#pragma unroll
        for (int j = 0; j < 4; ++j)
            bfr[j] = *(const bf16x8*)(Bs[cur] + ((wave >> 1) * 4 + j) * 512 + lane * 8);
#pragma unroll
        for (int i = 0; i < 4; ++i)
#pragma unroll
            for (int j = 0; j < 4; ++j)
                acc[i][j] = __builtin_amdgcn_mfma_f32_16x16x32_bf16(
                    af[i], bfr[j], acc[i][j], 0, 0, 0);

        asm volatile("s_barrier" ::: "memory");   // gate buffer reuse (reads done)
    }

    const int seg = bn >> 10;
#pragma unroll
    for (int i = 0; i < 4; ++i) {
#pragma unroll
        for (int r = 0; r < 4; ++r) {
            int gm = bm + wm + i * 16 + quad * 4 + r;
            if (gm >= N_NODES) continue;
#pragma unroll
            for (int j = 0; j < 4; ++j) {
                int gnl = (bn & 1023) + wn + j * 16 + l16;
                float v = acc[i][j][r];
                if (seg == 0)      fs0b[(size_t)gm * HD0 + gnl] = __float2bfloat16(v);
                else if (seg == 1) fd0b[(size_t)gm * HD0 + gnl] = __float2bfloat16(v);
                else if (seg == 2) out0r[(size_t)gm * HD0 + gnl] = __float2bfloat16(v + b0f[gnl]);
                else if (gnl < HD1) z[(size_t)gm * HD1 + gnl] = v;
            }
        }
    }
}

// fused layer-0 attention, single pass: out0b = relu(res + (sum p*fs)/(sum p)), bf16.
__global__ __launch_bounds__(256) void att0_kernel(
        const int* __restrict__ rowptr, const int* __restrict__ csre,
        const int* __restrict__ src, const __hip_bfloat16* __restrict__ fs,
        const __hip_bfloat16* __restrict__ fd, const void* __restrict__ a0,
        const __hip_bfloat16* __restrict__ out0res, __hip_bfloat16* __restrict__ out0b,
        const int* __restrict__ dflag) {
    int f32 = *dflag;
    int n = blockIdx.x;
    int t = threadIdx.x;
    __shared__ float sfd[HD0];
    __shared__ float sa0[HD0];
    {
        const unsigned short* fdp = (const unsigned short*)fd + (size_t)n * HD0;
        ushort4 u = *(const ushort4*)(fdp + 4 * t);
        sfd[4 * t + 0] = bfu2f(u.x); sfd[4 * t + 1] = bfu2f(u.y);
        sfd[4 * t + 2] = bfu2f(u.z); sfd[4 * t + 3] = bfu2f(u.w);
#pragma unroll
        for (int i = 0; i < 4; ++i) sa0[4 * t + i] = ldin(a0, 4 * t + i, f32);
    }
    __syncthreads();
    int start = rowptr[n], end = rowptr[n + 1];
    const unsigned short* fsu = (const unsigned short*)fs;
    float den = 0.f;
    float acc[4] = {0.f, 0.f, 0.f, 0.f};
    for (int i = start; i < end; ++i) {
        int s = src[csre[i]];
        ushort4 u = *(const ushort4*)(fsu + (size_t)s * HD0 + 4 * t);
        float fv[4], part = 0.f;
#pragma unroll
        for (int j = 0; j < 4; ++j) {
            unsigned short uj = (j == 0) ? u.x : (j == 1) ? u.y : (j == 2) ? u.z : u.w;
            fv[j] = bfu2f(uj);
            float x = fv[j] + sfd[4 * t + j];
            x = x > 0.f ? x : 0.2f * x;
            part += x * sa0[4 * t + j];
        }
        for (int off = 32; off > 0; off >>= 1) part += __shfl_xor(part, off);
        float p = expf(part);
        den += p;   // identical across the wave (= head)
#pragma unroll
        for (int j = 0; j < 4; ++j) acc[j] += p * fv[j];
    }
    float inv = 1.0f / fmaxf(den, 1e-9f);
    ushort4 ub = *(const ushort4*)((const unsigned short*)out0res + (size_t)n * HD0 + 4 * t);
    ushort4 o;
    o.x = f2bu(fmaxf(bfu2f(ub.x) + acc[0] * inv, 0.f));
    o.y = f2bu(fmaxf(bfu2f(ub.y) + acc[1] * inv, 0.f));
    o.z = f2bu(fmaxf(bfu2f(ub.z) + acc[2] * inv, 0.f));
    o.w = f2bu(fmaxf(bfu2f(ub.w) + acc[3] * inv, 0.f));
    *(ushort4*)((unsigned short*)out0b + (size_t)n * HD0 + 4 * t) = o;
}

// layer-1 fused MFMA GEMM: C[10000 x 96] = out0b @ bt1^T, K=1024, 64-row tiles,
// double-buffered DMA staging.
__global__ __launch_bounds__(256) void mfma_gemm96(
        const unsigned short* __restrict__ A, const unsigned short* __restrict__ BT1,
        const float* __restrict__ b1f, float* __restrict__ fs1,
        float* __restrict__ fd1, float* __restrict__ out1) {
    __shared__ unsigned short As[2][64 * 32];
    __shared__ unsigned short Bs[2][96 * 32];
    const int tid = threadIdx.x;
    const int wave = tid >> 6, lane = tid & 63;
    const int quad = lane >> 4, l16 = lane & 15;
    const int bm = blockIdx.x * 64;
    const int srow = lane & 15;
    const int skc  = (lane >> 4) * 8;

    f32x4 acc[6];
#pragma unroll
    for (int j = 0; j < 6; ++j) acc[j] = (f32x4){0.f, 0.f, 0.f, 0.f};

    async_copy16(A + (size_t)(bm + wave * 16 + srow) * HD0 + skc, As[0] + wave * 512);
    async_copy16(BT1 + (size_t)(wave * 16 + srow) * HD0 + skc, Bs[0] + wave * 512);
    if (wave < 2) {
        int f = 4 + wave;
        async_copy16(BT1 + (size_t)(f * 16 + srow) * HD0 + skc, Bs[0] + f * 512);
    }
    __syncthreads();

    for (int it = 0; it < HD0 / 32; ++it) {
        int cur = it & 1;
        if (it + 1 < HD0 / 32) {
            int k1 = (it + 1) * 32;
            async_copy16(A + (size_t)(bm + wave * 16 + srow) * HD0 + k1 + skc,
                         As[cur ^ 1] + wave * 512);
            async_copy16(BT1 + (size_t)(wave * 16 + srow) * HD0 + k1 + skc,
                         Bs[cur ^ 1] + wave * 512);
            if (wave < 2) {
                int f = 4 + wave;
                async_copy16(BT1 + (size_t)(f * 16 + srow) * HD0 + k1 + skc,
                             Bs[cur ^ 1] + f * 512);
            }
        }
        bf16x8 af = *(const bf16x8*)(As[cur] + wave * 512 + lane * 8);
#pragma unroll
        for (int j = 0; j < 6; ++j) {
            bf16x8 bfr = *(const bf16x8*)(Bs[cur] + j * 512 + lane * 8);
            acc[j] = __builtin_amdgcn_mfma_f32_16x16x32_bf16(af, bfr, acc[j], 0, 0, 0);
        }
        __syncthreads();
    }

#pragma unroll
    for (int r = 0; r < 4; ++r) {
        int gm = bm + wave * 16 + quad * 4 + r;
        if (gm >= N_NODES) continue;
#pragma unroll
        for (int j = 0; j < 6; ++j) {
            int col = j * 16 + l16;
            int seg = col >> 5, cl = col & 31;
            float v = acc[j][r];
            if (seg == 0)      fs1[(size_t)gm * HD1 + cl] = v;
            else if (seg == 1) fd1[(size_t)gm * HD1 + cl] = v;
            else               out1[(size_t)gm * HD1 + cl] = v + b1f[cl];
        }
    }
}

// es/ed for gat_inner
__global__ void esed_kernel(const float* __restrict__ z, const void* __restrict__ a2,
                            float* __restrict__ es, float* __restrict__ ed,
                            const int* __restrict__ dflag) {
    int f32 = *dflag;
    int idx = blockIdx.x * 256 + threadIdx.x;   // n*NH + h
    if (idx >= N_NODES * NH) return;
    int hh = idx % NH;
    const float* zp = z + (size_t)idx * D1;
    float s1 = 0.f, s2 = 0.f;
    for (int o = 0; o < D1; ++o) {
        float zv = zp[o];
        s1 += zv * ldin(a2, hh * 2 * D1 + o, f32);
        s2 += zv * ldin(a2, hh * 2 * D1 + D1 + o, f32);
    }
    es[idx] = s1; ed[idx] = s2;
}

// gat_inner fused attention, 8 nodes per 256-block: h3[n] = (sum p*z[src])/(sum p)
__global__ __launch_bounds__(256) void att32z_kernel(
        const int* __restrict__ rowptr, const int* __restrict__ csre,
        const int* __restrict__ src, const float* __restrict__ z,
        const float* __restrict__ es, const float* __restrict__ ed,
        float* __restrict__ h3) {
    int n = blockIdx.x * 8 + (threadIdx.x >> 5);
    int lane = threadIdx.x & 31;
    int h = lane >> 3;
    float edn = ed[n * NH + h];
    float den = 0.f, acc = 0.f;
    int start = rowptr[n], end = rowptr[n + 1];
    for (int i = start; i < end; ++i) {
        int s = src[csre[i]];
        float x = es[s * NH + h] + edn;
        x = x > 0.f ? x : 0.2f * x;
        float p = expf(x);
        den += p;
        acc += p * z[(size_t)s * HD1 + lane];
    }
    h3[(size_t)n * HD1 + lane] = acc / fmaxf(den, 1e-9f);
}

// layer-1 fused attention, 8 nodes per 256-block: out1[n] += (sum p*fs1)/(sum p)
__global__ __launch_bounds__(256) void att32e_kernel(
        const int* __restrict__ rowptr, const int* __restrict__ csre,
        const int* __restrict__ src, const float* __restrict__ fs1,
        const float* __restrict__ fd1, const void* __restrict__ a1,
        float* __restrict__ out1, const int* __restrict__ dflag) {
    int f32 = *dflag;
    int n = blockIdx.x * 8 + (threadIdx.x >> 5);
    int lane = threadIdx.x & 31;
    float fdn = fd1[(size_t)n * HD1 + lane];
    float a = ldin(a1, lane, f32);            // a1[h][o], lane = h*8+o
    float den = 0.f, acc = 0.f;
    int start = rowptr[n], end = rowptr[n + 1];
    for (int i = start; i < end; ++i) {
        int s = src[csre[i]];
        float fsv = fs1[(size_t)s * HD1 + lane];
        float x = fsv + fdn;
        x = x > 0.f ? x : 0.2f * x;
        float term = x * a;
        term += __shfl_xor(term, 1);
        term += __shfl_xor(term, 2);
        term += __shfl_xor(term, 4);          // head-wide logit (8 lanes/oct)
        float p = expf(term);
        den += p;
        acc += p * fsv;
    }
    out1[(size_t)n * HD1 + lane] += acc / fmaxf(den, 1e-9f);
}

// final: out[n,o] = [h3 | relu(out1)] @ Wlin + blin; dual-dtype store
__global__ void final_kernel(const float* __restrict__ h3, const float* __restrict__ out1,
                             const void* __restrict__ Wlin, const void* __restrict__ blin,
                             void* __restrict__ out, const int* __restrict__ dflag) {
    int f32 = *dflag;
    int idx = blockIdx.x * 256 + threadIdx.x;   // n*OUTF + o
    if (idx >= N_NODES * OUTF) return;
    int n = idx / OUTF, o = idx % OUTF;
    float acc = ldin(blin, o, f32);
    for (int j = 0; j < HD1; ++j)
        acc += h3[(size_t)n * HD1 + j] * ldin(Wlin, j * OUTF + o, f32);
    for (int j = 0; j < HD1; ++j)
        acc += fmaxf(out1[(size_t)n * HD1 + j], 0.f) * ldin(Wlin, (HD1 + j) * OUTF + o, f32);
    if (f32) ((float*)out)[idx] = acc;
    else     ((__hip_bfloat16*)out)[idx] = __float2bfloat16(acc);
}

// ---------------- launch ----------------
extern "C" void kernel_launch(void* const* d_in, const int* in_sizes, int n_in,
                              void* d_out, int out_size, void* d_ws, size_t ws_size,
                              hipStream_t stream) {
    const void* feats = d_in[0];
    const int*  src   = (const int*)d_in[1];
    const int*  dst   = (const int*)d_in[2];
    const void* tm    = d_in[3];
    const void* am    = d_in[4];
    const void* vm    = d_in[5];
    const void* W2    = d_in[6];
    const void* a2    = d_in[7];
    const void* Wl0   = d_in[8];
    const void* Wr0   = d_in[9];
    const void* a0    = d_in[10];
    const void* Wres0 = d_in[11];
    const void* b0    = d_in[12];
    const void* Wl1   = d_in[13];
    const void* Wr1   = d_in[14];
    const void* a1    = d_in[15];
    const void* Wres1 = d_in[16];
    const void* b1    = d_in[17];
    const void* Wlin  = d_in[18];
    const void* blin  = d_in[19];

    float* ws = (float*)d_ws;
    int*   dflag  = (int*)(ws + OFF_FLAG);
    float* colsum = ws + OFF_COLSUM;
    float* maskm  = ws + OFF_MASKM;
    float* z      = ws + OFF_Z;
    float* es     = ws + OFF_ES;
    float* ed     = ws + OFF_ED;
    float* h3     = ws + OFF_H3;
    float* fs1    = ws + OFF_FS1;
    float* fd1    = ws + OFF_FD1;
    float* out1   = ws + OFF_OUT1;
    float* b0f    = ws + OFF_B0F;
    float* b1f    = ws + OFF_B1F;
    int*   deg    = (int*)(ws + OFF_DEG);
    int*   rowptr = (int*)(ws + OFF_ROWPTR);
    int*   cursor = (int*)(ws + OFF_CURSOR);
    int*   csre   = (int*)(ws + OFF_CSRE);
    __hip_bfloat16* out0r = (__hip_bfloat16*)(ws + OFF_OUT0);
    __hip_bfloat16* fs0b = (__hip_bfloat16*)(ws + OFF_FS0B);
    __hip_bfloat16* fd0b = (__hip_bfloat16*)(ws + OFF_FD0B);
    __hip_bfloat16* abf  = (__hip_bfloat16*)(ws + OFF_ABF);
    __hip_bfloat16* bt   = (__hip_bfloat16*)(ws + OFF_BT);
    __hip_bfloat16* bt1  = (__hip_bfloat16*)(ws + OFF_BT1);
    __hip_bfloat16* out0b = fd0b;   // fd0b row n retired after att0 block n reads it

    // zero accumulators (flag+colsum contiguous; ws poisoned 0xAA before every call)
    (void)hipMemsetAsync(ws, 0, (16 + 1280) * sizeof(float), stream);
    (void)hipMemsetAsync(deg, 0, N_NODES * sizeof(int), stream);

    // dtype detection (subset scan)
    detect_kernel<<<64, 256, 0, stream>>>((const unsigned short*)feats, 131072, dflag);

    // CSR build
    deg_kernel<<<(N_EDGES + 255) / 256, 256, 0, stream>>>(dst, deg);
    scan_kernel<<<1, 256, 0, stream>>>(deg, rowptr, cursor);
    scatter_kernel<<<(N_EDGES + 255) / 256, 256, 0, stream>>>(dst, cursor, csre);

    // preprocess
    colsum_kernel<<<dim3(5, 40), 256, 0, stream>>>(feats, colsum, dflag);
    smallprep_kernel<<<5, 256, 0, stream>>>(tm, am, vm, b0, b1, maskm, b0f, b1f, dflag);
    prep_row_kernel<<<N_NODES, 256, 0, stream>>>(feats, colsum, maskm, abf, dflag);
    abf_pad_kernel<<<((MPAD - N_NODES) * KPAD + 255) / 256, 256, 0, stream>>>(abf);
    bt_kernel<<<(KPAD * NBIG2 + 255) / 256, 256, 0, stream>>>(Wl0, Wr0, Wres0, W2, bt, dflag);
    bt1_kernel<<<(HD0 * 96 + 255) / 256, 256, 0, stream>>>(Wl1, Wr1, Wres1, bt1, dflag);

    // big fused projection GEMM (Wl0 | Wr0 | Wres0 | W2-z), XCD-swizzled, tbuf+vmcnt
    mfma_gemm<<<2000, 256, 0, stream>>>(
        (const unsigned short*)abf, (const unsigned short*)bt, b0f, fs0b, fd0b, out0r, z);

    // gat_inner (h3): es/ed then single-pass CSR attention
    esed_kernel<<<(N_NODES * NH + 255) / 256, 256, 0, stream>>>(z, a2, es, ed, dflag);
    att32z_kernel<<<N_NODES / 8, 256, 0, stream>>>(rowptr, csre, src, z, es, ed, h3);

    // GATv2 layer 0: fused single-pass attention
    att0_kernel<<<N_NODES, 256, 0, stream>>>(rowptr, csre, src, fs0b, fd0b, a0,
                                             out0r, out0b, dflag);

    // GATv2 layer 1
    mfma_gemm96<<<(N_NODES + 63) / 64, 256, 0, stream>>>(
        (const unsigned short*)out0b, (const unsigned short*)bt1, b1f, fs1, fd1, out1);
    att32e_kernel<<<N_NODES / 8, 256, 0, stream>>>(rowptr, csre, src, fs1, fd1, a1,
                                                   out1, dflag);

    // final linear (relu(out1) folded in)
    final_kernel<<<(N_NODES * OUTF + 255) / 256, 256, 0, stream>>>(h3, out1, Wlin, blin,
                                                                   d_out, dflag);
}

// Round 12
// 601.026 us; speedup vs baseline: 6.8792x; 1.0299x over previous
//
#include <hip/hip_runtime.h>
#include <hip/hip_bf16.h>

// Problem constants
#define N_NODES 10000
#define N_EDGES 64000
#define IN_F    1247
#define KPAD    1280   // IN_F padded to mult of 32
#define NH      4
#define D0      256
#define D1      8
#define HD0     1024   // NH*D0
#define HD1     32     // NH*D1
#define NBIG    3072   // Wl0 | Wr0 | Wres0
#define NBIG2   3200   // + 32 z cols (from W2) + 96 pad
#define OUTF    6
#define INV_N   (1.0f / 10000.0f)
#define MPAD    10240  // 80 row-tiles (XCD swizzle: 80 = 8 XCD * 10)

typedef __attribute__((ext_vector_type(8))) short bf16x8;
typedef __attribute__((ext_vector_type(4))) float f32x4;
typedef unsigned int u32;

// async 16B global -> LDS (DMA). LDS dest: wave-uniform base + lane*16.
__device__ __forceinline__ void async_copy16(const unsigned short* gsrc,
                                             unsigned short* ldst) {
    __builtin_amdgcn_global_load_lds(
        (const __attribute__((address_space(1))) u32*)(gsrc),
        (__attribute__((address_space(3))) u32*)(ldst), 16, 0, 0);
}

// ---------------- workspace layout (float-slot offsets) ----------------
constexpr size_t OFF_FLAG   = 0;                          // 16
constexpr size_t OFF_COLSUM = 16;                         // 1280
constexpr size_t OFF_MASKM  = 1296;                       // 1280
constexpr size_t OFF_Z      = 2576;                       // N*32
constexpr size_t OFF_ES     = OFF_Z    + 320000;          // N*4
constexpr size_t OFF_ED     = OFF_ES   + 40000;           // N*4
constexpr size_t OFF_H3     = OFF_ED   + 40000;           // N*32
constexpr size_t OFF_OUT0   = OFF_H3   + 320000;          // bf16 N*1024 (res+bias)
constexpr size_t OFF_FS1    = OFF_OUT0 + 10240000;        // N*32
constexpr size_t OFF_FD1    = OFF_FS1  + 320000;          // N*32
constexpr size_t OFF_OUT1   = OFF_FD1  + 320000;          // N*32
constexpr size_t OFF_B0F    = OFF_OUT1 + 320000;          // 1024
constexpr size_t OFF_B1F    = OFF_B0F  + 1024;            // 64
constexpr size_t OFF_DEG    = OFF_B1F  + 64;              // int 10016
constexpr size_t OFF_ROWPTR = OFF_DEG  + 10016;           // int 10016
constexpr size_t OFF_CURSOR = OFF_ROWPTR + 10016;         // int 10016
constexpr size_t OFF_CSRE   = OFF_CURSOR + 10016;         // int 64000
constexpr size_t OFF_FS0B   = OFF_CSRE + 64000;           // bf16 N*1024
constexpr size_t OFF_FD0B   = OFF_FS0B + 5120000;         // bf16 N*1024 (reused as out0b)
constexpr size_t OFF_ABF    = OFF_FD0B + 5120000;         // bf16 MPAD*KPAD
constexpr size_t OFF_BT     = OFF_ABF  + 6553600;         // bf16 NBIG2*KPAD
constexpr size_t OFF_BT1    = OFF_BT   + 2048000;         // bf16 96*1024
constexpr size_t WS_FLOATS  = OFF_BT1  + 49152;

// dual-dtype load: is_f32 ? float : bf16
__device__ __forceinline__ float ldin(const void* p, size_t i, int f32) {
    return f32 ? ((const float*)p)[i]
               : __bfloat162float(((const __hip_bfloat16*)p)[i]);
}
__device__ __forceinline__ float bfu2f(unsigned short u) {
    union { unsigned int i; float f; } x;
    x.i = ((unsigned int)u) << 16;
    return x.f;
}
__device__ __forceinline__ unsigned short f2bu(float v) {
    __hip_bfloat16 h = __float2bfloat16(v);
    unsigned short u;
    __builtin_memcpy(&u, &h, 2);
    return u;
}

// ---------------- kernels ----------------

// dtype detection on first 131072 words
__global__ void detect_kernel(const unsigned short* __restrict__ w, int n,
                              int* __restrict__ flag) {
    int i = blockIdx.x * 256 + threadIdx.x;
    int stride = gridDim.x * 256;
    int found = 0;
    for (; i < n; i += stride) {
        if (((w[i] >> 7) & 0xFF) == 0xFF) found = 1;
    }
    if (found) atomicOr(flag, 1);
}

// column sums of features. grid (5,40), block 256
__global__ void colsum_kernel(const void* __restrict__ feats,
                              float* __restrict__ colsum, const int* __restrict__ dflag) {
    int f32 = *dflag;
    int c = blockIdx.x * blockDim.x + threadIdx.x;
    if (c >= IN_F) return;
    int r0 = blockIdx.y * 250;
    float s = 0.f;
    for (int r = r0; r < r0 + 250; ++r)
        s += ldin(feats, (size_t)r * IN_F + c, f32);
    atomicAdd(&colsum[c], s);
}

// fused small preps: maskmul + b0f + b1f
__global__ void smallprep_kernel(const void* __restrict__ tm, const void* __restrict__ am,
                                 const void* __restrict__ vm, const void* __restrict__ b0,
                                 const void* __restrict__ b1, float* __restrict__ maskmul,
                                 float* __restrict__ b0f, float* __restrict__ b1f,
                                 const int* __restrict__ dflag) {
    int f32 = *dflag;
    int c = blockIdx.x * 256 + threadIdx.x;
    if (c < IN_F) maskmul[c] = ldin(tm, c, f32) + ldin(am, c, f32) + ldin(vm, c, f32);
    if (c < HD0) b0f[c] = ldin(b0, c, f32);
    if (c < HD1) b1f[c] = ldin(b1, c, f32);
}

// fused single-pass: impute row into LDS, L1-scale, mask, emit bf16 A row.
// grid = MPAD (pad rows emit zeros).
__global__ __launch_bounds__(256) void prep_row_kernel(
        const void* __restrict__ feats, const float* __restrict__ colsum,
        const float* __restrict__ maskmul, __hip_bfloat16* __restrict__ abf,
        const int* __restrict__ dflag) {
    int n = blockIdx.x;
    if (n >= N_NODES) {
        for (int k = threadIdx.x; k < KPAD; k += 256)
            abf[(size_t)n * KPAD + k] = __float2bfloat16(0.f);
        return;
    }
    int f32 = *dflag;
    __shared__ float rowbuf[IN_F];
    __shared__ float red[256];
    float s = 0.f;
    for (int c = threadIdx.x; c < IN_F; c += 256) {
        float f = ldin(feats, (size_t)n * IN_F + c, f32);
        float v = (f != 0.0f) ? f : 0.5f * colsum[c] * INV_N;   // 0.5*(h+h1)
        rowbuf[c] = v;
        s += fabsf(v);
    }
    red[threadIdx.x] = s;
    __syncthreads();
    for (int st = 128; st > 0; st >>= 1) {
        if (threadIdx.x < st) red[threadIdx.x] += red[threadIdx.x + st];
        __syncthreads();
    }
    float scale = 1.0f / fmaxf(red[0], 1e-12f);
    for (int k = threadIdx.x; k < KPAD; k += 256) {
        float v = (k < IN_F) ? rowbuf[k] * scale * maskmul[k] : 0.f;
        abf[(size_t)n * KPAD + k] = __float2bfloat16(v);
    }
}

// LDS-tiled transpose: bt rows seg*1024+n0.. from W_seg[k][n]. grid (32,40,3).
__global__ __launch_bounds__(256) void bt_transpose_kernel(
        const void* __restrict__ Wl0, const void* __restrict__ Wr0,
        const void* __restrict__ Wres0, __hip_bfloat16* __restrict__ bt,
        const int* __restrict__ dflag) {
    int f32 = *dflag;
    __shared__ float tile[32][33];
    int n0 = blockIdx.x * 32;
    int k0 = blockIdx.y * 32;
    const void* W = (blockIdx.z == 0) ? Wl0 : (blockIdx.z == 1) ? Wr0 : Wres0;
    int tx = threadIdx.x & 31, ty = threadIdx.x >> 5;
    for (int i = ty; i < 32; i += 8) {
        int k = k0 + i;
        tile[i][tx] = (k < IN_F) ? ldin(W, (size_t)k * HD0 + n0 + tx, f32) : 0.f;
    }
    __syncthreads();
    for (int i = ty; i < 32; i += 8) {
        bt[(size_t)(blockIdx.z * 1024 + n0 + i) * KPAD + k0 + tx] =
            __float2bfloat16(tile[tx][i]);
    }
}

// W2 z-columns: bt rows 3072..3103 (coalesced writes over k)
__global__ void w2cols_kernel(const void* __restrict__ W2, __hip_bfloat16* __restrict__ bt,
                              const int* __restrict__ dflag) {
    int f32 = *dflag;
    int idx = blockIdx.x * 256 + threadIdx.x;   // n*KPAD + k, n in 0..31
    if (idx >= 32 * KPAD) return;
    int n = idx / KPAD, k = idx % KPAD;
    int hh = n >> 3, o = n & 7;
    float v = (k < IN_F) ? ldin(W2, ((size_t)hh * IN_F + k) * D1 + o, f32) : 0.f;
    bt[(size_t)(NBIG + n) * KPAD + k] = __float2bfloat16(v);
}

// transposed layer-1 B [96][1024], coalesced writes
__global__ void bt1_kernel(const void* __restrict__ Wl1, const void* __restrict__ Wr1,
                           const void* __restrict__ Wres1, __hip_bfloat16* __restrict__ bt1,
                           const int* __restrict__ dflag) {
    int f32 = *dflag;
    int idx = blockIdx.x * 256 + threadIdx.x;   // n*HD0 + k
    if (idx >= 96 * HD0) return;
    int n = idx >> 10, k = idx & 1023;
    int seg = n >> 5, col = n & 31;
    const void* W = (seg == 0) ? Wl1 : (seg == 1) ? Wr1 : Wres1;
    bt1[idx] = __float2bfloat16(ldin(W, (size_t)k * HD1 + col, f32));
}

// ---- CSR build ----
__global__ void deg_kernel(const int* __restrict__ dst, int* __restrict__ deg) {
    int e = blockIdx.x * 256 + threadIdx.x;
    if (e < N_EDGES) atomicAdd(&deg[dst[e]], 1);
}

__global__ __launch_bounds__(256) void scan_kernel(const int* __restrict__ deg,
                                                   int* __restrict__ rowptr,
                                                   int* __restrict__ cursor) {
    __shared__ int sums[256];
    __shared__ int offs[257];
    int t = threadIdx.x;
    int base = t * 40;
    int s = 0;
    for (int i = 0; i < 40; ++i) {
        int idx = base + i;
        if (idx < N_NODES) s += deg[idx];
    }
    sums[t] = s;
    __syncthreads();
    if (t == 0) {
        int run = 0;
        for (int i = 0; i < 256; ++i) { offs[i] = run; run += sums[i]; }
        offs[256] = run;
    }
    __syncthreads();
    int run = offs[t];
    for (int i = 0; i < 40; ++i) {
        int idx = base + i;
        if (idx < N_NODES) {
            rowptr[idx] = run; cursor[idx] = run;
            run += deg[idx];
        }
    }
    if (t == 255) rowptr[N_NODES] = offs[256];
}

__global__ void scatter_kernel(const int* __restrict__ dst, int* __restrict__ cursor,
                               int* __restrict__ csr_eid) {
    int e = blockIdx.x * 256 + threadIdx.x;
    if (e >= N_EDGES) return;
    int pos = atomicAdd(&cursor[dst[e]], 1);
    csr_eid[pos] = e;
}

// MFMA GEMM: C[MPAD x 3200] = abf @ bt^T. Double-buffered (separate LDS arrays),
// single barrier per K-step, manual vmcnt; DMA staged one compute-phase ahead.
// XCD-aware swizzle (flat grid 2000). Epilogue: cols 0..1023 -> fs0b (bf16),
// 1024..2047 -> fd0b (bf16), 2048..3071 -> out0r (bf16, +b0), 3072..3103 -> z.
__global__ __launch_bounds__(256) void mfma_gemm(
        const unsigned short* __restrict__ A, const unsigned short* __restrict__ BT,
        const float* __restrict__ b0f, __hip_bfloat16* __restrict__ fs0b,
        __hip_bfloat16* __restrict__ fd0b, __hip_bfloat16* __restrict__ out0r,
        float* __restrict__ z) {
    __shared__ unsigned short As0[4096], Bs0[4096], As1[4096], Bs1[4096];  // 32KB
    const int g = blockIdx.x;
    const int xcd = g & 7, l = g >> 3;
    const int colb = l / 10, rowl = l - colb * 10;
    const int bm = (xcd * 10 + rowl) * 128;
    const int bn = colb * 128;
    const int tid = threadIdx.x;
    const int wave = tid >> 6, lane = tid & 63;
    const int quad = lane >> 4, l16 = lane & 15;
    const int wm = (wave & 1) * 64, wn = (wave >> 1) * 64;
    const int srow = lane & 15;
    const int skc  = (lane >> 4) * 8;
    const int NIT = KPAD / 32;   // 40 (even)

    f32x4 acc[4][4];
#pragma unroll
    for (int i = 0; i < 4; ++i)
#pragma unroll
        for (int j = 0; j < 4; ++j) acc[i][j] = (f32x4){0.f, 0.f, 0.f, 0.f};

#define STAGE(kk, Adst, Bdst) do {                                              \
        _Pragma("unroll")                                                       \
        for (int t = 0; t < 2; ++t) {                                           \
            int f = t * 4 + wave;                                               \
            async_copy16(A + (size_t)(bm + f * 16 + srow) * KPAD + (kk) + skc,  \
                         (Adst) + f * 512);                                     \
            async_copy16(BT + (size_t)(bn + f * 16 + srow) * KPAD + (kk) + skc, \
                         (Bdst) + f * 512);                                     \
        } } while (0)

#define COMPUTE(Asrc, Bsrc) do {                                                \
        bf16x8 af[4], bfr[4];                                                   \
        _Pragma("unroll")                                                       \
        for (int i = 0; i < 4; ++i)                                             \
            af[i] = *(const bf16x8*)((Asrc) + ((wave & 1) * 4 + i) * 512 + lane * 8); \
        _Pragma("unroll")                                                       \
        for (int j = 0; j < 4; ++j)                                             \
            bfr[j] = *(const bf16x8*)((Bsrc) + ((wave >> 1) * 4 + j) * 512 + lane * 8); \
        _Pragma("unroll")                                                       \
        for (int i = 0; i < 4; ++i)                                             \
            _Pragma("unroll")                                                   \
            for (int j = 0; j < 4; ++j)                                         \
                acc[i][j] = __builtin_amdgcn_mfma_f32_16x16x32_bf16(            \
                    af[i], bfr[j], acc[i][j], 0, 0, 0);                         \
        } while (0)

    STAGE(0, As0, Bs0);
    for (int it = 0; it < NIT; it += 2) {
        asm volatile("s_waitcnt vmcnt(0)" ::: "memory");  // tile it landed (own ops)
        asm volatile("s_barrier" ::: "memory");           // all deposits in, prior reads done
        STAGE((it + 1) * 32, As1, Bs1);                   // prefetch next (other arrays)
        COMPUTE(As0, Bs0);
        asm volatile("s_waitcnt vmcnt(0)" ::: "memory");
        asm volatile("s_barrier" ::: "memory");
        if (it + 2 < NIT) STAGE((it + 2) * 32, As0, Bs0);
        COMPUTE(As1, Bs1);
    }
#undef STAGE
#undef COMPUTE

    const int seg = bn >> 10;
#pragma unroll
    for (int i = 0; i < 4; ++i) {
#pragma unroll
        for (int r = 0; r < 4; ++r) {
            int gm = bm + wm + i * 16 + quad * 4 + r;
            if (gm >= N_NODES) continue;
#pragma unroll
            for (int j = 0; j < 4; ++j) {
                int gnl = (bn & 1023) + wn + j * 16 + l16;
                float v = acc[i][j][r];
                if (seg == 0)      fs0b[(size_t)gm * HD0 + gnl] = __float2bfloat16(v);
                else if (seg == 1) fd0b[(size_t)gm * HD0 + gnl] = __float2bfloat16(v);
                else if (seg == 2) out0r[(size_t)gm * HD0 + gnl] = __float2bfloat16(v + b0f[gnl]);
                else if (gnl < HD1) z[(size_t)gm * HD1 + gnl] = v;
            }
        }
    }
}

// fused layer-0 attention, single pass, src indices cached in LDS.
__global__ __launch_bounds__(256) void att0_kernel(
        const int* __restrict__ rowptr, const int* __restrict__ csre,
        const int* __restrict__ src, const __hip_bfloat16* __restrict__ fs,
        const __hip_bfloat16* __restrict__ fd, const void* __restrict__ a0,
        const __hip_bfloat16* __restrict__ out0res, __hip_bfloat16* __restrict__ out0b,
        const int* __restrict__ dflag) {
    int f32 = *dflag;
    int n = blockIdx.x;
    int t = threadIdx.x;
    __shared__ float sfd[HD0];
    __shared__ float sa0[HD0];
    __shared__ int sidx[128];
    int start = rowptr[n], end = rowptr[n + 1];
    int deg = end - start;
    {
        const unsigned short* fdp = (const unsigned short*)fd + (size_t)n * HD0;
        ushort4 u = *(const ushort4*)(fdp + 4 * t);
        sfd[4 * t + 0] = bfu2f(u.x); sfd[4 * t + 1] = bfu2f(u.y);
        sfd[4 * t + 2] = bfu2f(u.z); sfd[4 * t + 3] = bfu2f(u.w);
#pragma unroll
        for (int i = 0; i < 4; ++i) sa0[4 * t + i] = ldin(a0, 4 * t + i, f32);
        if (t < deg && t < 128) sidx[t] = src[csre[start + t]];
    }
    __syncthreads();
    const unsigned short* fsu = (const unsigned short*)fs;
    float den = 0.f;
    float acc[4] = {0.f, 0.f, 0.f, 0.f};
#pragma unroll 2
    for (int i = 0; i < deg; ++i) {
        int s = (i < 128) ? sidx[i] : src[csre[start + i]];
        ushort4 u = *(const ushort4*)(fsu + (size_t)s * HD0 + 4 * t);
        float fv[4], part = 0.f;
#pragma unroll
        for (int j = 0; j < 4; ++j) {
            unsigned short uj = (j == 0) ? u.x : (j == 1) ? u.y : (j == 2) ? u.z : u.w;
            fv[j] = bfu2f(uj);
            float x = fv[j] + sfd[4 * t + j];
            x = x > 0.f ? x : 0.2f * x;
            part += x * sa0[4 * t + j];
        }
        for (int off = 32; off > 0; off >>= 1) part += __shfl_xor(part, off);
        float p = expf(part);
        den += p;   // identical across the wave (= head)
#pragma unroll
        for (int j = 0; j < 4; ++j) acc[j] += p * fv[j];
    }
    float inv = 1.0f / fmaxf(den, 1e-9f);
    ushort4 ub = *(const ushort4*)((const unsigned short*)out0res + (size_t)n * HD0 + 4 * t);
    ushort4 o;
    o.x = f2bu(fmaxf(bfu2f(ub.x) + acc[0] * inv, 0.f));
    o.y = f2bu(fmaxf(bfu2f(ub.y) + acc[1] * inv, 0.f));
    o.z = f2bu(fmaxf(bfu2f(ub.z) + acc[2] * inv, 0.f));
    o.w = f2bu(fmaxf(bfu2f(ub.w) + acc[3] * inv, 0.f));
    *(ushort4*)((unsigned short*)out0b + (size_t)n * HD0 + 4 * t) = o;
}

// layer-1 fused MFMA GEMM: C[10000 x 96] = out0b @ bt1^T, K=1024, 64-row tiles,
// same dbuf single-barrier pipeline.
__global__ __launch_bounds__(256) void mfma_gemm96(
        const unsigned short* __restrict__ A, const unsigned short* __restrict__ BT1,
        const float* __restrict__ b1f, float* __restrict__ fs1,
        float* __restrict__ fd1, float* __restrict__ out1) {
    __shared__ unsigned short As0[2048], Bs0[3072], As1[2048], Bs1[3072];  // 20KB
    const int tid = threadIdx.x;
    const int wave = tid >> 6, lane = tid & 63;
    const int quad = lane >> 4, l16 = lane & 15;
    const int bm = blockIdx.x * 64;
    const int srow = lane & 15;
    const int skc  = (lane >> 4) * 8;
    const int NIT = HD0 / 32;   // 32 (even)

    f32x4 acc[6];
#pragma unroll
    for (int j = 0; j < 6; ++j) acc[j] = (f32x4){0.f, 0.f, 0.f, 0.f};

#define STAGE96(kk, Adst, Bdst) do {                                              \
        async_copy16(A + (size_t)(bm + wave * 16 + srow) * HD0 + (kk) + skc,      \
                     (Adst) + wave * 512);                                        \
        async_copy16(BT1 + (size_t)(wave * 16 + srow) * HD0 + (kk) + skc,         \
                     (Bdst) + wave * 512);                                        \
        if (wave < 2)                                                             \
            async_copy16(BT1 + (size_t)((4 + wave) * 16 + srow) * HD0 + (kk) + skc, \
                         (Bdst) + (4 + wave) * 512);                              \
        } while (0)

#define COMPUTE96(Asrc, Bsrc) do {                                                \
        bf16x8 af = *(const bf16x8*)((Asrc) + wave * 512 + lane * 8);             \
        _Pragma("unroll")                                                         \
        for (int j = 0; j < 6; ++j) {                                             \
            bf16x8 bfr = *(const bf16x8*)((Bsrc) + j * 512 + lane * 8);           \
            acc[j] = __builtin_amdgcn_mfma_f32_16x16x32_bf16(af, bfr, acc[j], 0, 0, 0); \
        } } while (0)

    STAGE96(0, As0, Bs0);
    for (int it = 0; it < NIT; it += 2) {
        asm volatile("s_waitcnt vmcnt(0)" ::: "memory");
        asm volatile("s_barrier" ::: "memory");
        STAGE96((it + 1) * 32, As1, Bs1);
        COMPUTE96(As0, Bs0);
        asm volatile("s_waitcnt vmcnt(0)" ::: "memory");
        asm volatile("s_barrier" ::: "memory");
        if (it + 2 < NIT) STAGE96((it + 2) * 32, As0, Bs0);
        COMPUTE96(As1, Bs1);
    }
#undef STAGE96
#undef COMPUTE96

#pragma unroll
    for (int r = 0; r < 4; ++r) {
        int gm = bm + wave * 16 + quad * 4 + r;
        if (gm >= N_NODES) continue;
#pragma unroll
        for (int j = 0; j < 6; ++j) {
            int col = j * 16 + l16;
            int seg = col >> 5, cl = col & 31;
            float v = acc[j][r];
            if (seg == 0)      fs1[(size_t)gm * HD1 + cl] = v;
            else if (seg == 1) fd1[(size_t)gm * HD1 + cl] = v;
            else               out1[(size_t)gm * HD1 + cl] = v + b1f[cl];
        }
    }
}

// es/ed for gat_inner
__global__ void esed_kernel(const float* __restrict__ z, const void* __restrict__ a2,
                            float* __restrict__ es, float* __restrict__ ed,
                            const int* __restrict__ dflag) {
    int f32 = *dflag;
    int idx = blockIdx.x * 256 + threadIdx.x;   // n*NH + h
    if (idx >= N_NODES * NH) return;
    int hh = idx % NH;
    const float* zp = z + (size_t)idx * D1;
    float s1 = 0.f, s2 = 0.f;
    for (int o = 0; o < D1; ++o) {
        float zv = zp[o];
        s1 += zv * ldin(a2, hh * 2 * D1 + o, f32);
        s2 += zv * ldin(a2, hh * 2 * D1 + D1 + o, f32);
    }
    es[idx] = s1; ed[idx] = s2;
}

// gat_inner fused attention, 8 nodes per 256-block
__global__ __launch_bounds__(256) void att32z_kernel(
        const int* __restrict__ rowptr, const int* __restrict__ csre,
        const int* __restrict__ src, const float* __restrict__ z,
        const float* __restrict__ es, const float* __restrict__ ed,
        float* __restrict__ h3) {
    int n = blockIdx.x * 8 + (threadIdx.x >> 5);
    int lane = threadIdx.x & 31;
    int h = lane >> 3;
    float edn = ed[n * NH + h];
    float den = 0.f, acc = 0.f;
    int start = rowptr[n], end = rowptr[n + 1];
    for (int i = start; i < end; ++i) {
        int s = src[csre[i]];
        float x = es[s * NH + h] + edn;
        x = x > 0.f ? x : 0.2f * x;
        float p = expf(x);
        den += p;
        acc += p * z[(size_t)s * HD1 + lane];
    }
    h3[(size_t)n * HD1 + lane] = acc / fmaxf(den, 1e-9f);
}

// layer-1 fused attention, 8 nodes per 256-block
__global__ __launch_bounds__(256) void att32e_kernel(
        const int* __restrict__ rowptr, const int* __restrict__ csre,
        const int* __restrict__ src, const float* __restrict__ fs1,
        const float* __restrict__ fd1, const void* __restrict__ a1,
        float* __restrict__ out1, const int* __restrict__ dflag) {
    int f32 = *dflag;
    int n = blockIdx.x * 8 + (threadIdx.x >> 5);
    int lane = threadIdx.x & 31;
    float fdn = fd1[(size_t)n * HD1 + lane];
    float a = ldin(a1, lane, f32);            // a1[h][o], lane = h*8+o
    float den = 0.f, acc = 0.f;
    int start = rowptr[n], end = rowptr[n + 1];
    for (int i = start; i < end; ++i) {
        int s = src[csre[i]];
        float fsv = fs1[(size_t)s * HD1 + lane];
        float x = fsv + fdn;
        x = x > 0.f ? x : 0.2f * x;
        float term = x * a;
        term += __shfl_xor(term, 1);
        term += __shfl_xor(term, 2);
        term += __shfl_xor(term, 4);          // head-wide logit (8 lanes/oct)
        float p = expf(term);
        den += p;
        acc += p * fsv;
    }
    out1[(size_t)n * HD1 + lane] += acc / fmaxf(den, 1e-9f);
}

// final: out[n,o] = [h3 | relu(out1)] @ Wlin + blin; dual-dtype store
__global__ void final_kernel(const float* __restrict__ h3, const float* __restrict__ out1,
                             const void* __restrict__ Wlin, const void* __restrict__ blin,
                             void* __restrict__ out, const int* __restrict__ dflag) {
    int f32 = *dflag;
    int idx = blockIdx.x * 256 + threadIdx.x;   // n*OUTF + o
    if (idx >= N_NODES * OUTF) return;
    int n = idx / OUTF, o = idx % OUTF;
    float acc = ldin(blin, o, f32);
    for (int j = 0; j < HD1; ++j)
        acc += h3[(size_t)n * HD1 + j] * ldin(Wlin, j * OUTF + o, f32);
    for (int j = 0; j < HD1; ++j)
        acc += fmaxf(out1[(size_t)n * HD1 + j], 0.f) * ldin(Wlin, (HD1 + j) * OUTF + o, f32);
    if (f32) ((float*)out)[idx] = acc;
    else     ((__hip_bfloat16*)out)[idx] = __float2bfloat16(acc);
}

// ---------------- launch ----------------
extern "C" void kernel_launch(void* const* d_in, const int* in_sizes, int n_in,
                              void* d_out, int out_size, void* d_ws, size_t ws_size,
                              hipStream_t stream) {
    const void* feats = d_in[0];
    const int*  src   = (const int*)d_in[1];
    const int*  dst   = (const int*)d_in[2];
    const void* tm    = d_in[3];
    const void* am    = d_in[4];
    const void* vm    = d_in[5];
    const void* W2    = d_in[6];
    const void* a2    = d_in[7];
    const void* Wl0   = d_in[8];
    const void* Wr0   = d_in[9];
    const void* a0    = d_in[10];
    const void* Wres0 = d_in[11];
    const void* b0    = d_in[12];
    const void* Wl1   = d_in[13];
    const void* Wr1   = d_in[14];
    const void* a1    = d_in[15];
    const void* Wres1 = d_in[16];
    const void* b1    = d_in[17];
    const void* Wlin  = d_in[18];
    const void* blin  = d_in[19];

    float* ws = (float*)d_ws;
    int*   dflag  = (int*)(ws + OFF_FLAG);
    float* colsum = ws + OFF_COLSUM;
    float* maskm  = ws + OFF_MASKM;
    float* z      = ws + OFF_Z;
    float* es     = ws + OFF_ES;
    float* ed     = ws + OFF_ED;
    float* h3     = ws + OFF_H3;
    float* fs1    = ws + OFF_FS1;
    float* fd1    = ws + OFF_FD1;
    float* out1   = ws + OFF_OUT1;
    float* b0f    = ws + OFF_B0F;
    float* b1f    = ws + OFF_B1F;
    int*   deg    = (int*)(ws + OFF_DEG);
    int*   rowptr = (int*)(ws + OFF_ROWPTR);
    int*   cursor = (int*)(ws + OFF_CURSOR);
    int*   csre   = (int*)(ws + OFF_CSRE);
    __hip_bfloat16* out0r = (__hip_bfloat16*)(ws + OFF_OUT0);
    __hip_bfloat16* fs0b = (__hip_bfloat16*)(ws + OFF_FS0B);
    __hip_bfloat16* fd0b = (__hip_bfloat16*)(ws + OFF_FD0B);
    __hip_bfloat16* abf  = (__hip_bfloat16*)(ws + OFF_ABF);
    __hip_bfloat16* bt   = (__hip_bfloat16*)(ws + OFF_BT);
    __hip_bfloat16* bt1  = (__hip_bfloat16*)(ws + OFF_BT1);
    __hip_bfloat16* out0b = fd0b;   // fd0b row n retired after att0 block n reads it

    // zero accumulators + bt pad rows (ws poisoned 0xAA before every call)
    (void)hipMemsetAsync(ws, 0, (16 + 1280) * sizeof(float), stream);
    (void)hipMemsetAsync(deg, 0, N_NODES * sizeof(int), stream);
    (void)hipMemsetAsync(bt + (size_t)(NBIG + HD1) * KPAD, 0,
                         (size_t)(NBIG2 - NBIG - HD1) * KPAD * 2, stream);

    // dtype detection (subset scan)
    detect_kernel<<<64, 256, 0, stream>>>((const unsigned short*)feats, 131072, dflag);

    // CSR build
    deg_kernel<<<(N_EDGES + 255) / 256, 256, 0, stream>>>(dst, deg);
    scan_kernel<<<1, 256, 0, stream>>>(deg, rowptr, cursor);
    scatter_kernel<<<(N_EDGES + 255) / 256, 256, 0, stream>>>(dst, cursor, csre);

    // preprocess
    colsum_kernel<<<dim3(5, 40), 256, 0, stream>>>(feats, colsum, dflag);
    smallprep_kernel<<<5, 256, 0, stream>>>(tm, am, vm, b0, b1, maskm, b0f, b1f, dflag);
    prep_row_kernel<<<MPAD, 256, 0, stream>>>(feats, colsum, maskm, abf, dflag);
    bt_transpose_kernel<<<dim3(32, 40, 3), 256, 0, stream>>>(Wl0, Wr0, Wres0, bt, dflag);
    w2cols_kernel<<<(32 * KPAD + 255) / 256, 256, 0, stream>>>(W2, bt, dflag);
    bt1_kernel<<<(96 * HD0 + 255) / 256, 256, 0, stream>>>(Wl1, Wr1, Wres1, bt1, dflag);

    // big fused projection GEMM (Wl0 | Wr0 | Wres0 | W2-z)
    mfma_gemm<<<2000, 256, 0, stream>>>(
        (const unsigned short*)abf, (const unsigned short*)bt, b0f, fs0b, fd0b, out0r, z);

    // gat_inner (h3)
    esed_kernel<<<(N_NODES * NH + 255) / 256, 256, 0, stream>>>(z, a2, es, ed, dflag);
    att32z_kernel<<<N_NODES / 8, 256, 0, stream>>>(rowptr, csre, src, z, es, ed, h3);

    // GATv2 layer 0: fused single-pass attention
    att0_kernel<<<N_NODES, 256, 0, stream>>>(rowptr, csre, src, fs0b, fd0b, a0,
                                             out0r, out0b, dflag);

    // GATv2 layer 1
    mfma_gemm96<<<(N_NODES + 63) / 64, 256, 0, stream>>>(
        (const unsigned short*)out0b, (const unsigned short*)bt1, b1f, fs1, fd1, out1);
    att32e_kernel<<<N_NODES / 8, 256, 0, stream>>>(rowptr, csre, src, fs1, fd1, a1,
                                                   out1, dflag);

    // final linear (relu(out1) folded in)
    final_kernel<<<(N_NODES * OUTF + 255) / 256, 256, 0, stream>>>(h3, out1, Wlin, blin,
                                                                   d_out, dflag);
}

// Round 13
// 577.241 us; speedup vs baseline: 7.1626x; 1.0412x over previous
//
#include <hip/hip_runtime.h>
#include <hip/hip_bf16.h>

// Problem constants
#define N_NODES 10000
#define N_EDGES 64000
#define IN_F    1247
#define KPAD    1280   // IN_F padded to mult of 32
#define NH      4
#define D0      256
#define D1      8
#define HD0     1024   // NH*D0
#define HD1     32     // NH*D1
#define NBIG    3072   // Wl0 | Wr0 | Wres0
#define NBIG2   3200   // + 32 z cols (from W2) + 96 pad
#define OUTF    6
#define INV_N   (1.0f / 10000.0f)
#define MPAD    10240  // 80 row-tiles (XCD swizzle: 80 = 8 XCD * 10)

typedef __attribute__((ext_vector_type(8))) short bf16x8;
typedef __attribute__((ext_vector_type(4))) float f32x4;
typedef unsigned int u32;

// async 16B global -> LDS (DMA). LDS dest: wave-uniform base + lane*16.
__device__ __forceinline__ void async_copy16(const unsigned short* gsrc,
                                             unsigned short* ldst) {
    __builtin_amdgcn_global_load_lds(
        (const __attribute__((address_space(1))) u32*)(gsrc),
        (__attribute__((address_space(3))) u32*)(ldst), 16, 0, 0);
}

// ---------------- workspace layout (float-slot offsets) ----------------
constexpr size_t OFF_FLAG   = 0;                          // 16
constexpr size_t OFF_COLSUM = 16;                         // 1280
constexpr size_t OFF_MASKM  = 1296;                       // 1280
constexpr size_t OFF_Z      = 2576;                       // N*32
constexpr size_t OFF_H3     = OFF_Z    + 320000;          // N*32
constexpr size_t OFF_OUT0   = OFF_H3   + 320000;          // bf16 N*1024 (res+bias)
constexpr size_t OFF_FS1    = OFF_OUT0 + 10240000;        // N*32
constexpr size_t OFF_FD1    = OFF_FS1  + 320000;          // N*32
constexpr size_t OFF_OUT1   = OFF_FD1  + 320000;          // N*32
constexpr size_t OFF_B0F    = OFF_OUT1 + 320000;          // 1024
constexpr size_t OFF_B1F    = OFF_B0F  + 1024;            // 64
constexpr size_t OFF_DEG    = OFF_B1F  + 64;              // int 10016
constexpr size_t OFF_ROWPTR = OFF_DEG  + 10016;           // int 10016
constexpr size_t OFF_CURSOR = OFF_ROWPTR + 10016;         // int 10016
constexpr size_t OFF_CSRE   = OFF_CURSOR + 10016;         // int 64000
constexpr size_t OFF_FS0B   = OFF_CSRE + 64000;           // bf16 N*1024
constexpr size_t OFF_FD0B   = OFF_FS0B + 5120000;         // bf16 N*1024 (reused as out0b)
constexpr size_t OFF_ABF    = OFF_FD0B + 5120000;         // bf16 MPAD*KPAD
constexpr size_t OFF_BT     = OFF_ABF  + 6553600;         // bf16 NBIG2*KPAD
constexpr size_t OFF_BT1    = OFF_BT   + 2048000;         // bf16 96*1024
constexpr size_t WS_FLOATS  = OFF_BT1  + 49152;

// dual-dtype load: is_f32 ? float : bf16
__device__ __forceinline__ float ldin(const void* p, size_t i, int f32) {
    return f32 ? ((const float*)p)[i]
               : __bfloat162float(((const __hip_bfloat16*)p)[i]);
}
__device__ __forceinline__ float bfu2f(unsigned short u) {
    union { unsigned int i; float f; } x;
    x.i = ((unsigned int)u) << 16;
    return x.f;
}
__device__ __forceinline__ unsigned short f2bu(float v) {
    __hip_bfloat16 h = __float2bfloat16(v);
    unsigned short u;
    __builtin_memcpy(&u, &h, 2);
    return u;
}

// ---------------- kernels ----------------

// fused init: detect dtype (64 blocks) + zero deg (40) + zero bt pad rows (240)
__global__ void init_kernel(const unsigned short* __restrict__ feats_w,
                            int* __restrict__ flag, int* __restrict__ deg,
                            u32* __restrict__ btpad) {
    int b = blockIdx.x, t = threadIdx.x;
    if (b < 64) {
        int found = 0;
        for (int i = b * 256 + t; i < 131072; i += 64 * 256)
            if (((feats_w[i] >> 7) & 0xFF) == 0xFF) found = 1;
        if (found) atomicOr(flag, 1);
    } else if (b < 104) {
        int idx = (b - 64) * 256 + t;
        if (idx < N_NODES + 16) deg[idx] = 0;
    } else {
        int idx = (b - 104) * 256 + t;
        if (idx < 61440) btpad[idx] = 0;   // rows 3104..3199 of bt, as u32
    }
}

// fused: colsum (200 blocks) + deg histogram (250) + smallprep (5)
__global__ void prepA_kernel(const void* __restrict__ feats, const int* __restrict__ dst,
                             const void* __restrict__ tm, const void* __restrict__ am,
                             const void* __restrict__ vm, const void* __restrict__ b0,
                             const void* __restrict__ b1,
                             float* __restrict__ colsum, int* __restrict__ deg,
                             float* __restrict__ maskmul, float* __restrict__ b0f,
                             float* __restrict__ b1f, const int* __restrict__ dflag) {
    int b = blockIdx.x, t = threadIdx.x;
    if (b < 200) {
        int f32 = *dflag;
        int c = (b % 5) * 256 + t;
        if (c >= IN_F) return;
        int r0 = (b / 5) * 250;
        float s = 0.f;
        for (int r = r0; r < r0 + 250; ++r)
            s += ldin(feats, (size_t)r * IN_F + c, f32);
        atomicAdd(&colsum[c], s);
    } else if (b < 450) {
        int e = (b - 200) * 256 + t;
        if (e < N_EDGES) atomicAdd(&deg[dst[e]], 1);
    } else {
        int f32 = *dflag;
        int c = (b - 450) * 256 + t;
        if (c < IN_F) maskmul[c] = ldin(tm, c, f32) + ldin(am, c, f32) + ldin(vm, c, f32);
        if (c < HD0) b0f[c] = ldin(b0, c, f32);
        if (c < HD1) b1f[c] = ldin(b1, c, f32);
    }
}

__global__ __launch_bounds__(256) void scan_kernel(const int* __restrict__ deg,
                                                   int* __restrict__ rowptr,
                                                   int* __restrict__ cursor) {
    __shared__ int sums[256];
    __shared__ int offs[257];
    int t = threadIdx.x;
    int base = t * 40;
    int s = 0;
    for (int i = 0; i < 40; ++i) {
        int idx = base + i;
        if (idx < N_NODES) s += deg[idx];
    }
    sums[t] = s;
    __syncthreads();
    if (t == 0) {
        int run = 0;
        for (int i = 0; i < 256; ++i) { offs[i] = run; run += sums[i]; }
        offs[256] = run;
    }
    __syncthreads();
    int run = offs[t];
    for (int i = 0; i < 40; ++i) {
        int idx = base + i;
        if (idx < N_NODES) {
            rowptr[idx] = run; cursor[idx] = run;
            run += deg[idx];
        }
    }
    if (t == 255) rowptr[N_NODES] = offs[256];
}

__global__ void scatter_kernel(const int* __restrict__ dst, int* __restrict__ cursor,
                               int* __restrict__ csr_eid) {
    int e = blockIdx.x * 256 + threadIdx.x;
    if (e >= N_EDGES) return;
    int pos = atomicAdd(&cursor[dst[e]], 1);
    csr_eid[pos] = e;
}

// fused big prep: prep_row (10240 blocks) + bt transpose (3840) + w2cols (160) + bt1 (384)
__global__ __launch_bounds__(256) void prepB_kernel(
        const void* __restrict__ feats, const float* __restrict__ colsum,
        const float* __restrict__ maskmul, __hip_bfloat16* __restrict__ abf,
        const void* __restrict__ Wl0, const void* __restrict__ Wr0,
        const void* __restrict__ Wres0, const void* __restrict__ W2,
        __hip_bfloat16* __restrict__ bt,
        const void* __restrict__ Wl1, const void* __restrict__ Wr1,
        const void* __restrict__ Wres1, __hip_bfloat16* __restrict__ bt1,
        const int* __restrict__ dflag) {
    __shared__ float smem[1503];
    int b = blockIdx.x, t = threadIdx.x;
    int f32 = *dflag;
    if (b < MPAD) {
        // prep_row: impute + L1 scale + mask -> bf16 A row (pad rows -> 0)
        int n = b;
        if (n >= N_NODES) {
            for (int k = t; k < KPAD; k += 256)
                abf[(size_t)n * KPAD + k] = __float2bfloat16(0.f);
            return;
        }
        float* rowbuf = smem;            // 1247
        float* red    = smem + IN_F;     // 256
        float s = 0.f;
        for (int c = t; c < IN_F; c += 256) {
            float f = ldin(feats, (size_t)n * IN_F + c, f32);
            float v = (f != 0.0f) ? f : 0.5f * colsum[c] * INV_N;   // 0.5*(h+h1)
            rowbuf[c] = v;
            s += fabsf(v);
        }
        red[t] = s;
        __syncthreads();
        for (int st = 128; st > 0; st >>= 1) {
            if (t < st) red[t] += red[t + st];
            __syncthreads();
        }
        float scale = 1.0f / fmaxf(red[0], 1e-12f);
        for (int k = t; k < KPAD; k += 256) {
            float v = (k < IN_F) ? rowbuf[k] * scale * maskmul[k] : 0.f;
            abf[(size_t)n * KPAD + k] = __float2bfloat16(v);
        }
    } else if (b < MPAD + 3840) {
        // LDS-tiled transpose of Wl0/Wr0/Wres0 -> bt rows 0..3071
        int b2 = b - MPAD;
        int bz = b2 / 1280, rem = b2 - bz * 1280;
        int by = rem >> 5, bx = rem & 31;
        float (*tile)[33] = (float(*)[33])smem;
        int n0 = bx * 32, k0 = by * 32;
        const void* W = (bz == 0) ? Wl0 : (bz == 1) ? Wr0 : Wres0;
        int tx = t & 31, ty = t >> 5;
        for (int i = ty; i < 32; i += 8) {
            int k = k0 + i;
            tile[i][tx] = (k < IN_F) ? ldin(W, (size_t)k * HD0 + n0 + tx, f32) : 0.f;
        }
        __syncthreads();
        for (int i = ty; i < 32; i += 8)
            bt[(size_t)(bz * 1024 + n0 + i) * KPAD + k0 + tx] = __float2bfloat16(tile[tx][i]);
    } else if (b < MPAD + 3840 + 160) {
        // W2 z-columns -> bt rows 3072..3103 (coalesced over k)
        int idx = (b - (MPAD + 3840)) * 256 + t;
        if (idx >= 32 * KPAD) return;
        int n = idx / KPAD, k = idx % KPAD;
        int hh = n >> 3, o = n & 7;
        float v = (k < IN_F) ? ldin(W2, ((size_t)hh * IN_F + k) * D1 + o, f32) : 0.f;
        bt[(size_t)(NBIG + n) * KPAD + k] = __float2bfloat16(v);
    } else {
        // bt1 [96][1024], coalesced writes
        int idx = (b - (MPAD + 4000)) * 256 + t;
        if (idx >= 96 * HD0) return;
        int n = idx >> 10, k = idx & 1023;
        int seg = n >> 5, col = n & 31;
        const void* W = (seg == 0) ? Wl1 : (seg == 1) ? Wr1 : Wres1;
        bt1[idx] = __float2bfloat16(ldin(W, (size_t)k * HD1 + col, f32));
    }
}

// MFMA GEMM: C[MPAD x 3200] = abf @ bt^T. BK=64 single-buffer (32KB, 5 blocks/CU):
// 32 MFMAs per barrier pair (half the barrier-drain events of BK=32).
// Fragment-major LDS: group g=(f<<1)|h (f=row16 block, h=k32 half), 512 ushorts each.
// XCD-aware swizzle (flat grid 2000). Epilogue: cols 0..1023 -> fs0b (bf16),
// 1024..2047 -> fd0b (bf16), 2048..3071 -> out0r (bf16, +b0), 3072..3103 -> z.
__global__ __launch_bounds__(256) void mfma_gemm(
        const unsigned short* __restrict__ A, const unsigned short* __restrict__ BT,
        const float* __restrict__ b0f, __hip_bfloat16* __restrict__ fs0b,
        __hip_bfloat16* __restrict__ fd0b, __hip_bfloat16* __restrict__ out0r,
        float* __restrict__ z) {
    __shared__ unsigned short As[16 * 512];   // 16KB
    __shared__ unsigned short Bs[16 * 512];   // 16KB
    const int g = blockIdx.x;
    const int xcd = g & 7, l = g >> 3;
    const int colb = l / 10, rowl = l - colb * 10;
    const int bm = (xcd * 10 + rowl) * 128;
    const int bn = colb * 128;
    const int tid = threadIdx.x;
    const int wave = tid >> 6, lane = tid & 63;
    const int quad = lane >> 4, l16 = lane & 15;
    const int wm = (wave & 1) * 64, wn = (wave >> 1) * 64;
    const int srow = lane & 15;
    const int skc  = (lane >> 4) * 8;
    const int NIT = KPAD / 64;   // 20

    f32x4 acc[4][4];
#pragma unroll
    for (int i = 0; i < 4; ++i)
#pragma unroll
        for (int j = 0; j < 4; ++j) acc[i][j] = (f32x4){0.f, 0.f, 0.f, 0.f};

#define STAGE64(kk) do {                                                         \
        _Pragma("unroll")                                                        \
        for (int tt = 0; tt < 4; ++tt) {                                         \
            int gg = wave + 4 * tt;                                              \
            int fr = gg >> 1, hh = gg & 1;                                       \
            async_copy16(A + (size_t)(bm + fr * 16 + srow) * KPAD + (kk) + hh * 32 + skc, \
                         As + gg * 512);                                         \
            async_copy16(BT + (size_t)(bn + fr * 16 + srow) * KPAD + (kk) + hh * 32 + skc, \
                         Bs + gg * 512);                                         \
        } } while (0)

    STAGE64(0);
    for (int it = 0; it < NIT; ++it) {
        asm volatile("s_waitcnt vmcnt(0)" ::: "memory");
        asm volatile("s_barrier" ::: "memory");   // all deposits of this tile in
#pragma unroll
        for (int h = 0; h < 2; ++h) {
            bf16x8 af[4], bfr[4];
#pragma unroll
            for (int i = 0; i < 4; ++i)
                af[i] = *(const bf16x8*)(As + ((((wave & 1) * 4 + i) << 1) | h) * 512 + lane * 8);
#pragma unroll
            for (int j = 0; j < 4; ++j)
                bfr[j] = *(const bf16x8*)(Bs + ((((wave >> 1) * 4 + j) << 1) | h) * 512 + lane * 8);
#pragma unroll
            for (int i = 0; i < 4; ++i)
#pragma unroll
                for (int j = 0; j < 4; ++j)
                    acc[i][j] = __builtin_amdgcn_mfma_f32_16x16x32_bf16(
                        af[i], bfr[j], acc[i][j], 0, 0, 0);
        }
        asm volatile("s_barrier" ::: "memory");   // reads done; safe to overwrite
        if (it + 1 < NIT) STAGE64((it + 1) * 64);
    }
#undef STAGE64

    const int seg = bn >> 10;
#pragma unroll
    for (int i = 0; i < 4; ++i) {
#pragma unroll
        for (int r = 0; r < 4; ++r) {
            int gm = bm + wm + i * 16 + quad * 4 + r;
            if (gm >= N_NODES) continue;
#pragma unroll
            for (int j = 0; j < 4; ++j) {
                int gnl = (bn & 1023) + wn + j * 16 + l16;
                float v = acc[i][j][r];
                if (seg == 0)      fs0b[(size_t)gm * HD0 + gnl] = __float2bfloat16(v);
                else if (seg == 1) fd0b[(size_t)gm * HD0 + gnl] = __float2bfloat16(v);
                else if (seg == 2) out0r[(size_t)gm * HD0 + gnl] = __float2bfloat16(v + b0f[gnl]);
                else if (gnl < HD1) z[(size_t)gm * HD1 + gnl] = v;
            }
        }
    }
}

// gat_inner fused attention (es/ed computed on the fly), 8 nodes per 256-block:
// h3[n] = (sum_e p*z[src]) / (sum_e p),  p = exp(leaky(es[s][h] + ed[n][h]))
__global__ __launch_bounds__(256) void att32z_kernel(
        const int* __restrict__ rowptr, const int* __restrict__ csre,
        const int* __restrict__ src, const float* __restrict__ z,
        const void* __restrict__ a2, float* __restrict__ h3,
        const int* __restrict__ dflag) {
    int f32 = *dflag;
    int n = blockIdx.x * 8 + (threadIdx.x >> 5);
    int lane = threadIdx.x & 31;
    int h = lane >> 3, o = lane & 7;
    float a2e = ldin(a2, h * 2 * D1 + o, f32);        // es half
    float a2d = ldin(a2, h * 2 * D1 + D1 + o, f32);   // ed half
    float zn = z[(size_t)n * HD1 + lane];
    float edn = zn * a2d;
    edn += __shfl_xor(edn, 1); edn += __shfl_xor(edn, 2); edn += __shfl_xor(edn, 4);
    float den = 0.f, acc = 0.f;
    int start = rowptr[n], end = rowptr[n + 1];
    for (int i = start; i < end; ++i) {
        int s = src[csre[i]];
        float zs = z[(size_t)s * HD1 + lane];
        float esv = zs * a2e;
        esv += __shfl_xor(esv, 1); esv += __shfl_xor(esv, 2); esv += __shfl_xor(esv, 4);
        float x = esv + edn;
        x = x > 0.f ? x : 0.2f * x;
        float p = expf(x);
        den += p;
        acc += p * zs;
    }
    h3[(size_t)n * HD1 + lane] = acc / fmaxf(den, 1e-9f);
}

// fused layer-0 attention, single pass, src indices cached in LDS.
__global__ __launch_bounds__(256) void att0_kernel(
        const int* __restrict__ rowptr, const int* __restrict__ csre,
        const int* __restrict__ src, const __hip_bfloat16* __restrict__ fs,
        const __hip_bfloat16* __restrict__ fd, const void* __restrict__ a0,
        const __hip_bfloat16* __restrict__ out0res, __hip_bfloat16* __restrict__ out0b,
        const int* __restrict__ dflag) {
    int f32 = *dflag;
    int n = blockIdx.x;
    int t = threadIdx.x;
    __shared__ float sfd[HD0];
    __shared__ float sa0[HD0];
    __shared__ int sidx[128];
    int start = rowptr[n], end = rowptr[n + 1];
    int deg = end - start;
    {
        const unsigned short* fdp = (const unsigned short*)fd + (size_t)n * HD0;
        ushort4 u = *(const ushort4*)(fdp + 4 * t);
        sfd[4 * t + 0] = bfu2f(u.x); sfd[4 * t + 1] = bfu2f(u.y);
        sfd[4 * t + 2] = bfu2f(u.z); sfd[4 * t + 3] = bfu2f(u.w);
#pragma unroll
        for (int i = 0; i < 4; ++i) sa0[4 * t + i] = ldin(a0, 4 * t + i, f32);
        if (t < deg && t < 128) sidx[t] = src[csre[start + t]];
    }
    __syncthreads();
    const unsigned short* fsu = (const unsigned short*)fs;
    float den = 0.f;
    float acc[4] = {0.f, 0.f, 0.f, 0.f};
#pragma unroll 2
    for (int i = 0; i < deg; ++i) {
        int s = (i < 128) ? sidx[i] : src[csre[start + i]];
        ushort4 u = *(const ushort4*)(fsu + (size_t)s * HD0 + 4 * t);
        float fv[4], part = 0.f;
#pragma unroll
        for (int j = 0; j < 4; ++j) {
            unsigned short uj = (j == 0) ? u.x : (j == 1) ? u.y : (j == 2) ? u.z : u.w;
            fv[j] = bfu2f(uj);
            float x = fv[j] + sfd[4 * t + j];
            x = x > 0.f ? x : 0.2f * x;
            part += x * sa0[4 * t + j];
        }
        for (int off = 32; off > 0; off >>= 1) part += __shfl_xor(part, off);
        float p = expf(part);
        den += p;   // identical across the wave (= head)
#pragma unroll
        for (int j = 0; j < 4; ++j) acc[j] += p * fv[j];
    }
    float inv = 1.0f / fmaxf(den, 1e-9f);
    ushort4 ub = *(const ushort4*)((const unsigned short*)out0res + (size_t)n * HD0 + 4 * t);
    ushort4 o;
    o.x = f2bu(fmaxf(bfu2f(ub.x) + acc[0] * inv, 0.f));
    o.y = f2bu(fmaxf(bfu2f(ub.y) + acc[1] * inv, 0.f));
    o.z = f2bu(fmaxf(bfu2f(ub.z) + acc[2] * inv, 0.f));
    o.w = f2bu(fmaxf(bfu2f(ub.w) + acc[3] * inv, 0.f));
    *(ushort4*)((unsigned short*)out0b + (size_t)n * HD0 + 4 * t) = o;
}

// layer-1 fused MFMA GEMM: C[10000 x 96] = out0b @ bt1^T, K=1024, 64-row tiles,
// dbuf single-barrier pipeline.
__global__ __launch_bounds__(256) void mfma_gemm96(
        const unsigned short* __restrict__ A, const unsigned short* __restrict__ BT1,
        const float* __restrict__ b1f, float* __restrict__ fs1,
        float* __restrict__ fd1, float* __restrict__ out1) {
    __shared__ unsigned short As0[2048], Bs0[3072], As1[2048], Bs1[3072];  // 20KB
    const int tid = threadIdx.x;
    const int wave = tid >> 6, lane = tid & 63;
    const int quad = lane >> 4, l16 = lane & 15;
    const int bm = blockIdx.x * 64;
    const int srow = lane & 15;
    const int skc  = (lane >> 4) * 8;
    const int NIT = HD0 / 32;   // 32 (even)

    f32x4 acc[6];
#pragma unroll
    for (int j = 0; j < 6; ++j) acc[j] = (f32x4){0.f, 0.f, 0.f, 0.f};

#define STAGE96(kk, Adst, Bdst) do {                                              \
        async_copy16(A + (size_t)(bm + wave * 16 + srow) * HD0 + (kk) + skc,      \
                     (Adst) + wave * 512);                                        \
        async_copy16(BT1 + (size_t)(wave * 16 + srow) * HD0 + (kk) + skc,         \
                     (Bdst) + wave * 512);                                        \
        if (wave < 2)                                                             \
            async_copy16(BT1 + (size_t)((4 + wave) * 16 + srow) * HD0 + (kk) + skc, \
                         (Bdst) + (4 + wave) * 512);                              \
        } while (0)

#define COMPUTE96(Asrc, Bsrc) do {                                                \
        bf16x8 af = *(const bf16x8*)((Asrc) + wave * 512 + lane * 8);             \
        _Pragma("unroll")                                                         \
        for (int j = 0; j < 6; ++j) {                                             \
            bf16x8 bfr = *(const bf16x8*)((Bsrc) + j * 512 + lane * 8);           \
            acc[j] = __builtin_amdgcn_mfma_f32_16x16x32_bf16(af, bfr, acc[j], 0, 0, 0); \
        } } while (0)

    STAGE96(0, As0, Bs0);
    for (int it = 0; it < NIT; it += 2) {
        asm volatile("s_waitcnt vmcnt(0)" ::: "memory");
        asm volatile("s_barrier" ::: "memory");
        STAGE96((it + 1) * 32, As1, Bs1);
        COMPUTE96(As0, Bs0);
        asm volatile("s_waitcnt vmcnt(0)" ::: "memory");
        asm volatile("s_barrier" ::: "memory");
        if (it + 2 < NIT) STAGE96((it + 2) * 32, As0, Bs0);
        COMPUTE96(As1, Bs1);
    }
#undef STAGE96
#undef COMPUTE96

#pragma unroll
    for (int r = 0; r < 4; ++r) {
        int gm = bm + wave * 16 + quad * 4 + r;
        if (gm >= N_NODES) continue;
#pragma unroll
        for (int j = 0; j < 6; ++j) {
            int col = j * 16 + l16;
            int seg = col >> 5, cl = col & 31;
            float v = acc[j][r];
            if (seg == 0)      fs1[(size_t)gm * HD1 + cl] = v;
            else if (seg == 1) fd1[(size_t)gm * HD1 + cl] = v;
            else               out1[(size_t)gm * HD1 + cl] = v + b1f[cl];
        }
    }
}

// layer-1 attention + final linear fused, 8 nodes per 256-block.
// out1v = out1g + attention; out[n] = [h3 | relu(out1v)] @ Wlin + blin.
__global__ __launch_bounds__(256) void att32e_final_kernel(
        const int* __restrict__ rowptr, const int* __restrict__ csre,
        const int* __restrict__ src, const float* __restrict__ fs1,
        const float* __restrict__ fd1, const void* __restrict__ a1,
        const float* __restrict__ out1g, const float* __restrict__ h3,
        const void* __restrict__ Wlin, const void* __restrict__ blin,
        void* __restrict__ out, const int* __restrict__ dflag) {
    int f32 = *dflag;
    int n = blockIdx.x * 8 + (threadIdx.x >> 5);
    int lane = threadIdx.x & 31;
    float fdn = fd1[(size_t)n * HD1 + lane];
    float a = ldin(a1, lane, f32);            // a1[h][o], lane = h*8+o
    float den = 0.f, acc = 0.f;
    int start = rowptr[n], end = rowptr[n + 1];
    for (int i = start; i < end; ++i) {
        int s = src[csre[i]];
        float fsv = fs1[(size_t)s * HD1 + lane];
        float x = fsv + fdn;
        x = x > 0.f ? x : 0.2f * x;
        float term = x * a;
        term += __shfl_xor(term, 1);
        term += __shfl_xor(term, 2);
        term += __shfl_xor(term, 4);          // head-wide logit (8 lanes/oct)
        float p = expf(term);
        den += p;
        acc += p * fsv;
    }
    float out1v = fmaxf(out1g[(size_t)n * HD1 + lane] + acc / fmaxf(den, 1e-9f), 0.f);
    float h3v = h3[(size_t)n * HD1 + lane];
    float partial[OUTF];
#pragma unroll
    for (int o = 0; o < OUTF; ++o)
        partial[o] = h3v * ldin(Wlin, (size_t)lane * OUTF + o, f32)
                   + out1v * ldin(Wlin, (size_t)(HD1 + lane) * OUTF + o, f32);
#pragma unroll
    for (int st = 1; st <= 16; st <<= 1)
#pragma unroll
        for (int o = 0; o < OUTF; ++o) partial[o] += __shfl_xor(partial[o], st);
    if (lane == 0) {
#pragma unroll
        for (int o = 0; o < OUTF; ++o) {
            float v = partial[o] + ldin(blin, o, f32);
            if (f32) ((float*)out)[(size_t)n * OUTF + o] = v;
            else     ((__hip_bfloat16*)out)[(size_t)n * OUTF + o] = __float2bfloat16(v);
        }
    }
}

// ---------------- launch ----------------
extern "C" void kernel_launch(void* const* d_in, const int* in_sizes, int n_in,
                              void* d_out, int out_size, void* d_ws, size_t ws_size,
                              hipStream_t stream) {
    const void* feats = d_in[0];
    const int*  src   = (const int*)d_in[1];
    const int*  dst   = (const int*)d_in[2];
    const void* tm    = d_in[3];
    const void* am    = d_in[4];
    const void* vm    = d_in[5];
    const void* W2    = d_in[6];
    const void* a2    = d_in[7];
    const void* Wl0   = d_in[8];
    const void* Wr0   = d_in[9];
    const void* a0    = d_in[10];
    const void* Wres0 = d_in[11];
    const void* b0    = d_in[12];
    const void* Wl1   = d_in[13];
    const void* Wr1   = d_in[14];
    const void* a1    = d_in[15];
    const void* Wres1 = d_in[16];
    const void* b1    = d_in[17];
    const void* Wlin  = d_in[18];
    const void* blin  = d_in[19];

    float* ws = (float*)d_ws;
    int*   dflag  = (int*)(ws + OFF_FLAG);
    float* colsum = ws + OFF_COLSUM;
    float* maskm  = ws + OFF_MASKM;
    float* z      = ws + OFF_Z;
    float* h3     = ws + OFF_H3;
    float* fs1    = ws + OFF_FS1;
    float* fd1    = ws + OFF_FD1;
    float* out1   = ws + OFF_OUT1;
    float* b0f    = ws + OFF_B0F;
    float* b1f    = ws + OFF_B1F;
    int*   deg    = (int*)(ws + OFF_DEG);
    int*   rowptr = (int*)(ws + OFF_ROWPTR);
    int*   cursor = (int*)(ws + OFF_CURSOR);
    int*   csre   = (int*)(ws + OFF_CSRE);
    __hip_bfloat16* out0r = (__hip_bfloat16*)(ws + OFF_OUT0);
    __hip_bfloat16* fs0b = (__hip_bfloat16*)(ws + OFF_FS0B);
    __hip_bfloat16* fd0b = (__hip_bfloat16*)(ws + OFF_FD0B);
    __hip_bfloat16* abf  = (__hip_bfloat16*)(ws + OFF_ABF);
    __hip_bfloat16* bt   = (__hip_bfloat16*)(ws + OFF_BT);
    __hip_bfloat16* bt1  = (__hip_bfloat16*)(ws + OFF_BT1);
    __hip_bfloat16* out0b = fd0b;   // fd0b row n retired after att0 block n reads it

    // single memset: dflag + colsum (contiguous). Other zeroing in init_kernel.
    (void)hipMemsetAsync(ws, 0, (16 + 1280) * sizeof(float), stream);

    // init: detect + deg-zero + bt-pad-zero
    init_kernel<<<344, 256, 0, stream>>>((const unsigned short*)feats, dflag, deg,
                                         (u32*)(bt + (size_t)(NBIG + HD1) * KPAD));
    // colsum + deg histogram + small preps
    prepA_kernel<<<455, 256, 0, stream>>>(feats, dst, tm, am, vm, b0, b1,
                                          colsum, deg, maskm, b0f, b1f, dflag);
    scan_kernel<<<1, 256, 0, stream>>>(deg, rowptr, cursor);
    scatter_kernel<<<(N_EDGES + 255) / 256, 256, 0, stream>>>(dst, cursor, csre);

    // big prep: A rows + all weight transposes
    prepB_kernel<<<MPAD + 3840 + 160 + 384, 256, 0, stream>>>(
        feats, colsum, maskm, abf, Wl0, Wr0, Wres0, W2, bt, Wl1, Wr1, Wres1, bt1, dflag);

    // big fused projection GEMM (Wl0 | Wr0 | Wres0 | W2-z), BK=64, XCD-swizzled
    mfma_gemm<<<2000, 256, 0, stream>>>(
        (const unsigned short*)abf, (const unsigned short*)bt, b0f, fs0b, fd0b, out0r, z);

    // gat_inner attention (es/ed on the fly)
    att32z_kernel<<<N_NODES / 8, 256, 0, stream>>>(rowptr, csre, src, z, a2, h3, dflag);

    // GATv2 layer 0: fused single-pass attention
    att0_kernel<<<N_NODES, 256, 0, stream>>>(rowptr, csre, src, fs0b, fd0b, a0,
                                             out0r, out0b, dflag);

    // GATv2 layer 1 GEMM
    mfma_gemm96<<<(N_NODES + 63) / 64, 256, 0, stream>>>(
        (const unsigned short*)out0b, (const unsigned short*)bt1, b1f, fs1, fd1, out1);

    // layer-1 attention + final linear fused
    att32e_final_kernel<<<N_NODES / 8, 256, 0, stream>>>(
        rowptr, csre, src, fs1, fd1, a1, out1, h3, Wlin, blin, d_out, dflag);
}